// Round 17
// baseline (339.533 us; speedup 1.0000x reference)
//
#include <hip/hip_runtime.h>
#include <hip/hip_bf16.h>

// Problem constants
#define KN 2048
#define BB 4
#define DM 512
#define NH 8
#define HE 64
#define UP 40
#define NBH 32          // B*H
#define NROWS 8192      // KN*B
#define MiB(x) ((size_t)(x) << 20)

typedef __attribute__((ext_vector_type(8))) short short8;
typedef __attribute__((ext_vector_type(4))) float f32x4;

// bf16 split helpers (RNE)
__device__ __forceinline__ ushort f2bf(float x) {
  unsigned u = __float_as_uint(x);
  unsigned r = (u + 0x7FFFu + ((u >> 16) & 1u)) >> 16;
  return (ushort)r;
}
__device__ __forceinline__ float bf2f(ushort h) {
  return __uint_as_float((unsigned)h << 16);
}

// ---------------------------------------------------------------------------
// Split W (512x512) / A (8192x512) f32 into hi/lo bf16 planes.
// ---------------------------------------------------------------------------
__global__ __launch_bounds__(256) void wsplit_kernel(
    const float* __restrict__ W, ushort* __restrict__ Wh,
    ushort* __restrict__ Wl) {
  int i = (blockIdx.x * 256 + threadIdx.x) * 2;   // 512 blocks
  float2 v = *(const float2*)(W + i);
  ushort h0 = f2bf(v.x), h1 = f2bf(v.y);
  ushort l0 = f2bf(v.x - bf2f(h0)), l1 = f2bf(v.y - bf2f(h1));
  *(ushort2*)(Wh + i) = make_ushort2(h0, h1);
  *(ushort2*)(Wl + i) = make_ushort2(l0, l1);
}

__global__ __launch_bounds__(256) void asplit_kernel(
    const float* __restrict__ A, ushort* __restrict__ Ah,
    ushort* __restrict__ Al) {
  size_t i = ((size_t)blockIdx.x * 256 + threadIdx.x) * 4;  // 4096 blocks
  float4 v = *(const float4*)(A + i);
  ushort h0 = f2bf(v.x), h1 = f2bf(v.y), h2 = f2bf(v.z), h3 = f2bf(v.w);
  ushort l0 = f2bf(v.x - bf2f(h0)), l1 = f2bf(v.y - bf2f(h1));
  ushort l2 = f2bf(v.z - bf2f(h2)), l3 = f2bf(v.w - bf2f(h3));
  *(ushort4*)(Ah + i) = make_ushort4(h0, h1, h2, h3);
  *(ushort4*)(Al + i) = make_ushort4(l0, l1, l2, l3);
}

// ---------------------------------------------------------------------------
// Split-bf16 MFMA GEMM, all-global fragments (no LDS, no barriers).
// C[m,o] = (sum_k A[m,k]*W[o,k] + bias[o]) * scale ; 4-term split.
// Tile 128x64, 512 blocks, XCD decode (R11: FETCH 12MB). Wave w owns rows
// [w*32,+32) x 64 cols. Fragment reads: 16 rows x 64 contiguous B per wave
// (full cache lines, same pattern as the proven W reads).
//   A-frag: lane holds A[16rows: lane%16][(lane/16)*8 +0..7]  (bf16x8 in K)
//   C/D   : col = lane&15, row = (lane>>4)*4 + reg  (m89-verified)
// ---------------------------------------------------------------------------
__global__ __launch_bounds__(256) void gemm_mfma(
    const ushort* __restrict__ Ah, const ushort* __restrict__ Al,
    const ushort* __restrict__ Wh, const ushort* __restrict__ Wl,
    const float* __restrict__ bias, float scale, float* __restrict__ C) {
  const int bid = blockIdx.x;
  const int mt = (bid & 7) * 8 + ((bid >> 3) & 7);  // 0..63
  const int ot = bid >> 6;                          // 0..7
  const int m0 = mt * 128, o0 = ot * 64;
  const int tid = threadIdx.x;
  const int w = tid >> 6, lane = tid & 63;
  const int fr = lane & 15;      // fragment row
  const int kc = lane >> 4;      // k-chunk (8 bf16)

  f32x4 acc[2][4];
#pragma unroll
  for (int i = 0; i < 2; ++i)
#pragma unroll
    for (int j = 0; j < 4; ++j)
#pragma unroll
      for (int r = 0; r < 4; ++r) acc[i][j][r] = 0.f;

  const size_t arow0 = (size_t)(m0 + w * 32 + fr) * 512 + kc * 8;
  const size_t arow1 = arow0 + (size_t)16 * 512;
  const size_t wrow0 = (size_t)(o0 + fr) * 512 + kc * 8;

  for (int k0 = 0; k0 < 512; k0 += 32) {
    short8 ah[2], al[2], bh[4], bl[4];
    ah[0] = *(const short8*)(Ah + arow0 + k0);
    al[0] = *(const short8*)(Al + arow0 + k0);
    ah[1] = *(const short8*)(Ah + arow1 + k0);
    al[1] = *(const short8*)(Al + arow1 + k0);
#pragma unroll
    for (int j = 0; j < 4; ++j) {
      size_t off = wrow0 + (size_t)j * 16 * 512 + k0;
      bh[j] = *(const short8*)(Wh + off);
      bl[j] = *(const short8*)(Wl + off);
    }
#pragma unroll
    for (int i = 0; i < 2; ++i)
#pragma unroll
      for (int j = 0; j < 4; ++j) {
        acc[i][j] = __builtin_amdgcn_mfma_f32_16x16x32_bf16(ah[i], bh[j], acc[i][j], 0, 0, 0);
        acc[i][j] = __builtin_amdgcn_mfma_f32_16x16x32_bf16(ah[i], bl[j], acc[i][j], 0, 0, 0);
        acc[i][j] = __builtin_amdgcn_mfma_f32_16x16x32_bf16(al[i], bh[j], acc[i][j], 0, 0, 0);
        acc[i][j] = __builtin_amdgcn_mfma_f32_16x16x32_bf16(al[i], bl[j], acc[i][j], 0, 0, 0);
      }
  }

#pragma unroll
  for (int i = 0; i < 2; ++i)
#pragma unroll
    for (int j = 0; j < 4; ++j)
#pragma unroll
      for (int r = 0; r < 4; ++r) {
        int m = m0 + w * 32 + i * 16 + (lane >> 4) * 4 + r;
        int o = o0 + j * 16 + fr;
        C[(size_t)m * 512 + o] = (acc[i][j][r] + bias[o]) * scale;
      }
}

// ---------------------------------------------------------------------------
// Transpose K into Kt[bh][e][n] for coalesced attention score reads.
// ---------------------------------------------------------------------------
__global__ __launch_bounds__(256) void transposeK_kernel(
    const float* __restrict__ K, float* __restrict__ Kt) {
  const int bh = blockIdx.x & 31;
  const int nt = blockIdx.x >> 5;       // 0..15
  const int b = bh >> 3, h = bh & 7;
  const int n0 = nt * 128;
  const int tid = threadIdx.x;
  __shared__ float T[128][65];

#pragma unroll
  for (int i = 0; i < 8; ++i) {
    int flat = tid + i * 256;           // 0..2047
    int r = flat >> 4;                  // 0..127
    int c4 = flat & 15;                 // 0..15
    float4 v = *(const float4*)(K + (((size_t)(n0 + r) * 4 + b) * 8 + h) * 64 + c4 * 4);
    T[r][c4 * 4 + 0] = v.x; T[r][c4 * 4 + 1] = v.y;
    T[r][c4 * 4 + 2] = v.z; T[r][c4 * 4 + 3] = v.w;
  }
  __syncthreads();

  const int nl = tid & 127;             // 0..127
  const int eg = tid >> 7;              // 0..1
#pragma unroll
  for (int e = eg * 32; e < eg * 32 + 32; ++e)
    Kt[((size_t)bh * 64 + e) * 2048 + n0 + nl] = T[nl][e];
}

// ---------------------------------------------------------------------------
// M scores, wave-cooperative gather. One wave per (bh, n).
// ---------------------------------------------------------------------------
__global__ __launch_bounds__(256) void mscore_kernel(
    const float* __restrict__ Q, const float* __restrict__ K,
    const int* __restrict__ idx, float* __restrict__ Mout) {
  const int bh = blockIdx.x & 31;
  const int c  = blockIdx.x >> 5;        // 0..511
  const int wv = threadIdx.x >> 6;       // 0..3
  const int lane = threadIdx.x & 63;
  const int n = c * 4 + wv;
  const int b = bh >> 3, h = bh & 7;
  const int g = lane >> 4;               // sample group 0..3
  const int e16 = lane & 15;             // element chunk within row

  const float4 qv = *(const float4*)(Q + (((size_t)n * 4 + b) * 8 + h) * 64 + e16 * 4);

  float mx = -INFINITY, sm = 0.f;
#pragma unroll
  for (int it = 0; it < 10; ++it) {
    const int s = it * 4 + g;
    const int kn = idx[n * UP + s];
    const float4 kv = *(const float4*)(K + (((size_t)kn * 4 + b) * 8 + h) * 64 + e16 * 4);
    float d = qv.x * kv.x + qv.y * kv.y + qv.z * kv.z + qv.w * kv.w;
    d += __shfl_xor(d, 1);
    d += __shfl_xor(d, 2);
    d += __shfl_xor(d, 4);
    d += __shfl_xor(d, 8);
    mx = fmaxf(mx, d);
    sm += d;
  }
  mx = fmaxf(mx, __shfl_xor(mx, 16));
  mx = fmaxf(mx, __shfl_xor(mx, 32));
  sm += __shfl_xor(sm, 16);
  sm += __shfl_xor(sm, 32);
  if (lane == 0) Mout[(size_t)bh * 2048 + n] = mx - sm * (1.0f / (float)KN);
}

// ---------------------------------------------------------------------------
// top-40 per (b,h) via 4-pass byte radix-select (R14, verified).
// ---------------------------------------------------------------------------
__global__ __launch_bounds__(256) void topk_kernel(
    const float* __restrict__ M, int* __restrict__ Mtop) {
  const int bh = blockIdx.x;
  __shared__ unsigned keys[2048];
  __shared__ int hist[256];
  __shared__ int suf[256];
  __shared__ int scal[2];
  __shared__ int ties[128];
  __shared__ int cnts[2];

  const int tid = threadIdx.x;
  const float* Mrow = M + (size_t)bh * 2048;
#pragma unroll
  for (int i = 0; i < 8; ++i) {
    int j = tid + i * 256;
    unsigned u = __float_as_uint(Mrow[j]);
    keys[j] = (u & 0x80000000u) ? ~u : (u | 0x80000000u);  // monotone map
  }
  if (tid < 2) cnts[tid] = 0;

  unsigned prefix = 0, prefmask = 0;
  int rank = UP;
#pragma unroll
  for (int shift = 24; shift >= 0; shift -= 8) {
    hist[tid] = 0;
    __syncthreads();
#pragma unroll
    for (int i = 0; i < 8; ++i) {
      unsigned k = keys[tid + i * 256];
      if ((k & prefmask) == prefix)
        atomicAdd(&hist[(k >> shift) & 0xFFu], 1);
    }
    __syncthreads();
    suf[tid] = hist[tid];
    __syncthreads();
#pragma unroll
    for (int off = 1; off < 256; off <<= 1) {
      int add = (tid + off < 256) ? suf[tid + off] : 0;
      __syncthreads();
      suf[tid] += add;
      __syncthreads();
    }
    {
      int above = suf[tid] - hist[tid];
      if (above < rank && rank <= suf[tid]) {
        scal[0] = tid;
        scal[1] = rank - above;
      }
    }
    __syncthreads();
    prefix |= ((unsigned)scal[0]) << shift;
    prefmask |= 0xFFu << shift;
    rank = scal[1];
    __syncthreads();
  }
  const unsigned T = prefix;

#pragma unroll
  for (int i = 0; i < 8; ++i) {
    int j = tid + i * 256;
    unsigned k = keys[j];
    if (k > T) {
      int p = atomicAdd(&cnts[0], 1);
      Mtop[bh * UP + p] = j;
    } else if (k == T) {
      int p = atomicAdd(&cnts[1], 1);
      if (p < 128) ties[p] = j;
    }
  }
  __syncthreads();
  if (tid == 0) {
    int base = cnts[0];
    int need = UP - base;
    int tc = cnts[1] < 128 ? cnts[1] : 128;
    for (int s = 0; s < need; ++s) {
      int best = 1 << 30, bj = 0;
      for (int j = 0; j < tc; ++j) {
        int v = ties[j];
        if (v < best) { best = v; bj = j; }
      }
      Mtop[bh * UP + base + s] = best;
      ties[bj] = 1 << 30;
    }
  }
}

// ---------------------------------------------------------------------------
// mean of V: two-phase coalesced column-sum (V is a [2048][2048] matrix).
// ---------------------------------------------------------------------------
__global__ __launch_bounds__(256) void meanv_part(
    const float* __restrict__ V, float* __restrict__ part) {
  const int rc = blockIdx.x >> 3;      // 0..31
  const int cc = blockIdx.x & 7;       // 0..7
  const int c = cc * 256 + threadIdx.x;
  const float* p = V + (size_t)rc * 64 * 2048 + c;
  float acc = 0.f;
#pragma unroll 8
  for (int i = 0; i < 64; ++i) acc += p[(size_t)i * 2048];
  part[(size_t)rc * 2048 + c] = acc;
}

__global__ __launch_bounds__(256) void meanv_final(
    const float* __restrict__ part, float* __restrict__ mnV) {
  const int c = blockIdx.x * 256 + threadIdx.x;   // 8 blocks
  float acc = 0.f;
#pragma unroll
  for (int r = 0; r < 32; ++r) acc += part[(size_t)r * 2048 + c];
  mnV[c] = acc * (1.0f / (float)KN);
}

// ---------------------------------------------------------------------------
// Selected-row machinery for the sparse output GEMM.
// ---------------------------------------------------------------------------
__global__ void selbuild_kernel(const int* __restrict__ Mtop,
                                int* __restrict__ flags) {
  const int i = blockIdx.x * 64 + threadIdx.x;   // 0..1279
  const int bh = i / UP;
  const int b = bh >> 3;
  flags[b * 2048 + Mtop[i]] = 1;
}

__global__ void selcompact_kernel(const int* __restrict__ flags,
                                  int* __restrict__ rows,
                                  int* __restrict__ cnt) {
  const int i = blockIdx.x * 256 + threadIdx.x;  // 0..8191
  if (flags[i]) {
    int p = atomicAdd(cnt, 1);
    rows[p] = i;                                  // flat row index b*2048+n
  }
}

// meanout[b][o] = dot(mnV[b*512..], Wo[o]) + bo[o]
__global__ __launch_bounds__(256) void meanout_kernel(
    const float* __restrict__ mnV, const float* __restrict__ Wo,
    const float* __restrict__ bo, float* __restrict__ mo) {
  const int b = blockIdx.x;           // 4 blocks
  for (int o = threadIdx.x; o < 512; o += 256) {
    const float* m = mnV + b * 512;
    const float* w = Wo + (size_t)o * 512;
    float acc = 0.f;
#pragma unroll 8
    for (int k = 0; k < 512; ++k) acc = fmaf(m[k], w[k], acc);
    mo[b * 512 + o] = acc + bo[o];
  }
}

// out broadcast fill (float4)
__global__ void fillout_kernel(const float* __restrict__ mo,
                               float* __restrict__ out) {
  size_t i = ((size_t)blockIdx.x * 256 + threadIdx.x) * 4;
  int d = (int)(i & 511);
  int b = (int)(i >> 20);
  float4 v = *(const float4*)(mo + (b << 9) + d);
  *(float4*)(out + i) = v;
}

// ---------------------------------------------------------------------------
// Sparse output GEMM over selected rows only (<=1280 of 8192).
// ---------------------------------------------------------------------------
__global__ __launch_bounds__(256) void gemm_rows(
    const float* __restrict__ ctx, const float* __restrict__ W,
    const float* __restrict__ bias, const int* __restrict__ rows,
    const int* __restrict__ cnt, float* __restrict__ out) {
  __shared__ float As[32][68];
  __shared__ float Ws[32][68];
  __shared__ int rsel[64];
  const int rt = blockIdx.x >> 3;      // 0..19
  const int ot = blockIdx.x & 7;       // 0..7
  const int o0 = ot * 64;
  const int tid = threadIdx.x;
  const int tx = tid & 15;
  const int ty = tid >> 4;
  const int n = *cnt;

  if (rt * 64 >= n) return;

  if (tid < 64) {
    int g = rt * 64 + tid;
    rsel[tid] = (g < n) ? rows[g] : rows[0];
  }
  __syncthreads();

  float acc[4][4] = {};
  for (int k0 = 0; k0 < 512; k0 += 32) {
#pragma unroll
    for (int i = 0; i < 2; ++i) {
      int flat = tid + i * 256;        // 0..511
      int r = flat >> 3;               // 0..63
      int c4 = flat & 7;
      float4 av = *(const float4*)(ctx + (size_t)rsel[r] * 512 + k0 + c4 * 4);
      float4 wv = *(const float4*)(W + (size_t)(o0 + r) * 512 + k0 + c4 * 4);
      As[c4 * 4 + 0][r] = av.x; As[c4 * 4 + 1][r] = av.y;
      As[c4 * 4 + 2][r] = av.z; As[c4 * 4 + 3][r] = av.w;
      Ws[c4 * 4 + 0][r] = wv.x; Ws[c4 * 4 + 1][r] = wv.y;
      Ws[c4 * 4 + 2][r] = wv.z; Ws[c4 * 4 + 3][r] = wv.w;
    }
    __syncthreads();
#pragma unroll
    for (int kk = 0; kk < 32; ++kk) {
      float a_[4], w_[4];
#pragma unroll
      for (int i = 0; i < 4; ++i) a_[i] = As[kk][ty * 4 + i];
#pragma unroll
      for (int j = 0; j < 4; ++j) w_[j] = Ws[kk][tx * 4 + j];
#pragma unroll
      for (int i = 0; i < 4; ++i)
#pragma unroll
        for (int j = 0; j < 4; ++j)
          acc[i][j] = fmaf(a_[i], w_[j], acc[i][j]);
    }
    __syncthreads();
  }

#pragma unroll
  for (int i = 0; i < 4; ++i) {
    int g = rt * 64 + ty * 4 + i;
    if (g < n) {
      int m = rsel[ty * 4 + i];
#pragma unroll
      for (int j = 0; j < 4; ++j) {
        int o = o0 + tx * 4 + j;
        out[(size_t)m * 512 + o] = acc[i][j] + bias[o];
      }
    }
  }
}

// ---------------------------------------------------------------------------
// Flash-split attention (R15, verified): grid 1024, bid%8 == bh%8.
// ---------------------------------------------------------------------------
#define QG 5   // queries per block
#define NC 4   // n-chunks
__global__ __launch_bounds__(256) void attn_part(
    const float* __restrict__ Q, const float* __restrict__ Kt,
    const float* __restrict__ V, const int* __restrict__ Mtop,
    float* __restrict__ pmax, float* __restrict__ psum,
    float* __restrict__ pvp) {
  const int bh = blockIdx.x & 31;
  const int t  = blockIdx.x >> 5;       // 0..31
  const int g  = t & 7;                 // query group
  const int ch = t >> 3;                // n-chunk
  const int b = bh >> 3, h = bh & 7;
  const int tid = threadIdx.x;
  const int wv = tid >> 6, lane = tid & 63;
  const int n0 = ch * 512;

  __shared__ float qs[QG][64];
  __shared__ float p[QG][512];
  __shared__ float redm[QG][4];
  __shared__ float reds[QG][4];
  __shared__ float pvs[4][QG][64];

  for (int i = tid; i < QG * 64; i += 256) {
    int q = i >> 6, e = i & 63;
    int nq = Mtop[bh * UP + g * QG + q];
    qs[q][e] = Q[(((size_t)nq * 4 + b) * 8 + h) * 64 + e];
  }
  __syncthreads();

  const float* ktb = Kt + (size_t)bh * 64 * 2048;
  float d0[QG] = {}, d1[QG] = {};
  const int nb = n0 + tid * 2;
  for (int e = 0; e < 64; ++e) {
    float2 kv = *(const float2*)(ktb + (size_t)e * 2048 + nb);
#pragma unroll
    for (int q = 0; q < QG; ++q) {
      float qe = qs[q][e];
      d0[q] = fmaf(qe, kv.x, d0[q]);
      d1[q] = fmaf(qe, kv.y, d1[q]);
    }
  }

#pragma unroll
  for (int q = 0; q < QG; ++q) {
    float m_ = fmaxf(d0[q], d1[q]);
#pragma unroll
    for (int off = 1; off < 64; off <<= 1)
      m_ = fmaxf(m_, __shfl_xor(m_, off));
    if (lane == 0) redm[q][wv] = m_;
  }
  __syncthreads();
  float gm[QG];
#pragma unroll
  for (int q = 0; q < QG; ++q)
    gm[q] = fmaxf(fmaxf(redm[q][0], redm[q][1]),
                  fmaxf(redm[q][2], redm[q][3]));

  float ls[QG];
#pragma unroll
  for (int q = 0; q < QG; ++q) {
    float e0 = __expf(d0[q] - gm[q]);
    float e1 = __expf(d1[q] - gm[q]);
    p[q][tid * 2] = e0;
    p[q][tid * 2 + 1] = e1;
    ls[q] = e0 + e1;
  }
#pragma unroll
  for (int q = 0; q < QG; ++q) {
    float s_ = ls[q];
#pragma unroll
    for (int off = 1; off < 64; off <<= 1)
      s_ += __shfl_xor(s_, off);
    if (lane == 0) reds[q][wv] = s_;
  }
  __syncthreads();
  float den[QG];
#pragma unroll
  for (int q = 0; q < QG; ++q)
    den[q] = reds[q][0] + reds[q][1] + reds[q][2] + reds[q][3];

  float acc[QG] = {};
  for (int nn = wv * 128; nn < wv * 128 + 128; ++nn) {
    float v = V[(((size_t)(n0 + nn) * 4 + b) * 8 + h) * 64 + lane];
#pragma unroll
    for (int q = 0; q < QG; ++q) acc[q] = fmaf(p[q][nn], v, acc[q]);
  }
#pragma unroll
  for (int q = 0; q < QG; ++q) pvs[wv][q][lane] = acc[q];
  __syncthreads();

  for (int i = tid; i < QG * 64; i += 256) {
    int q = i >> 6, e = i & 63;
    int slot = bh * UP + g * QG + q;
    float pv = pvs[0][q][e] + pvs[1][q][e] + pvs[2][q][e] + pvs[3][q][e];
    pvp[((size_t)slot * NC + ch) * 64 + e] = pv;
    if (e == 0) {
      pmax[slot * NC + ch] = gm[q];
      psum[slot * NC + ch] = den[q];
    }
  }
}

__global__ __launch_bounds__(64) void attn_combine(
    const float* __restrict__ pmax, const float* __restrict__ psum,
    const float* __restrict__ pvp, float* __restrict__ upd) {
  const int slot = blockIdx.x;     // 0..1279
  const int e = threadIdx.x;
  float m = -INFINITY;
#pragma unroll
  for (int ch = 0; ch < NC; ++ch) m = fmaxf(m, pmax[slot * NC + ch]);
  float den = 0.f, num = 0.f;
#pragma unroll
  for (int ch = 0; ch < NC; ++ch) {
    float w = __expf(pmax[slot * NC + ch] - m);
    den = fmaf(w, psum[slot * NC + ch], den);
    num = fmaf(w, pvp[((size_t)slot * NC + ch) * 64 + e], num);
  }
  upd[(size_t)slot * 64 + e] = num / den;
}

// ---------------------------------------------------------------------------
// ctx fill + scatter
// ---------------------------------------------------------------------------
__global__ void fillctx_kernel(const float* __restrict__ meanV,
                               float* __restrict__ ctx) {
  size_t i = ((size_t)blockIdx.x * 256 + threadIdx.x) * 4;
  int d = (int)(i & 511);
  int b = (int)(i >> 20);
  float4 v = *(const float4*)(meanV + (b << 9) + d);
  *(float4*)(ctx + i) = v;
}

__global__ void scatter_kernel(const float* __restrict__ upd,
                               const int* __restrict__ Mtop,
                               float* __restrict__ ctx) {
  const int blk = blockIdx.x;   // bh*40 + s
  const int bh = blk / UP;
  const int b = bh >> 3, h = bh & 7;
  const int n = Mtop[blk];
  ctx[((size_t)(b * 2048 + n)) * 512 + h * 64 + threadIdx.x] =
      upd[(size_t)blk * 64 + threadIdx.x];
}

// ---------------------------------------------------------------------------
// Workspace layout (~86 MiB used; ws >= 113 MiB proven in R4):
//   [0, 256K) Mbuf | [256K,576K) upd | [589824,598016) mnV
//   [598016,603136) Mtop | [634880,897024) vpart | [903168,935936) flags
//   [935936,935940) cnt | [936192,941312) rows | [941312,949504) mo
//   [1M,17M) Q(ctx alias) [17M,33M) K [33M,49M) V [49M,65M) Kt
//   [65M..68M) Wh/Wl x3 | [68M..68M+64K) pmax/psum | [..~69.4M) pvp
//   [70M,78M) Ah | [78M,86M) Al   (shared across the 3 GEMMs, serialized)
// ---------------------------------------------------------------------------
extern "C" void kernel_launch(void* const* d_in, const int* in_sizes, int n_in,
                              void* d_out, int out_size, void* d_ws,
                              size_t ws_size, hipStream_t stream) {
  const float* query = (const float*)d_in[0];
  const float* key   = (const float*)d_in[1];
  const float* value = (const float*)d_in[2];
  const int*   idxs  = (const int*)d_in[3];
  const float* Wq = (const float*)d_in[4];
  const float* bq = (const float*)d_in[5];
  const float* Wk = (const float*)d_in[6];
  const float* bk = (const float*)d_in[7];
  const float* Wv = (const float*)d_in[8];
  const float* bv = (const float*)d_in[9];
  const float* Wo = (const float*)d_in[10];
  const float* bo = (const float*)d_in[11];
  float* out = (float*)d_out;    // reference output dtype is float32

  char* ws = (char*)d_ws;
  float*  Mbuf  = (float*)(ws + 0);
  float*  upd   = (float*)(ws + 262144);
  float*  mnV   = (float*)(ws + 589824);
  int*    Mtop  = (int*)  (ws + 598016);
  float*  vpart = (float*)(ws + 634880);
  int*    flags = (int*)  (ws + 903168);
  int*    cnt   = (int*)  (ws + 935936);
  int*    rows  = (int*)  (ws + 936192);
  float*  mo    = (float*)(ws + 941312);
  float*  Q     = (float*)(ws + MiB(1));
  float*  K     = (float*)(ws + MiB(17));
  float*  V     = (float*)(ws + MiB(33));
  float*  Kt    = (float*)(ws + MiB(49));
  ushort* Whq   = (ushort*)(ws + MiB(65));
  ushort* Wlq   = (ushort*)(ws + MiB(65) + 524288);
  ushort* Whk   = (ushort*)(ws + MiB(66));
  ushort* Wlk   = (ushort*)(ws + MiB(66) + 524288);
  ushort* Whv   = (ushort*)(ws + MiB(67));
  ushort* Wlv   = (ushort*)(ws + MiB(67) + 524288);
  float*  pmax  = (float*)(ws + MiB(68));
  float*  psum  = (float*)(ws + MiB(68) + 32768);
  float*  pvp   = (float*)(ws + MiB(68) + 65536);
  ushort* Ahb   = (ushort*)(ws + MiB(70));
  ushort* Alb   = (ushort*)(ws + MiB(78));
  float*  ctx   = Q;   // Q dead after attn; ctx written afterwards

  // zero flags + cnt (contiguous region)
  hipMemsetAsync(flags, 0, 32768 + 4, stream);

  wsplit_kernel<<<512, 256, 0, stream>>>(Wq, Whq, Wlq);
  wsplit_kernel<<<512, 256, 0, stream>>>(Wk, Whk, Wlk);
  wsplit_kernel<<<512, 256, 0, stream>>>(Wv, Whv, Wlv);

  asplit_kernel<<<4096, 256, 0, stream>>>(query, Ahb, Alb);
  gemm_mfma<<<512, 256, 0, stream>>>(Ahb, Alb, Whq, Wlq, bq, 0.125f, Q);
  asplit_kernel<<<4096, 256, 0, stream>>>(key, Ahb, Alb);
  gemm_mfma<<<512, 256, 0, stream>>>(Ahb, Alb, Whk, Wlk, bk, 1.0f, K);
  asplit_kernel<<<4096, 256, 0, stream>>>(value, Ahb, Alb);
  gemm_mfma<<<512, 256, 0, stream>>>(Ahb, Alb, Whv, Wlv, bv, 1.0f, V);

  transposeK_kernel<<<512, 256, 0, stream>>>(K, Kt);

  mscore_kernel<<<16384, 256, 0, stream>>>(Q, K, idxs, Mbuf);
  topk_kernel<<<NBH, 256, 0, stream>>>(Mbuf, Mtop);
  selbuild_kernel<<<20, 64, 0, stream>>>(Mtop, flags);
  selcompact_kernel<<<32, 256, 0, stream>>>(flags, rows, cnt);

  meanv_part<<<256, 256, 0, stream>>>(V, vpart);
  meanv_final<<<8, 256, 0, stream>>>(vpart, mnV);

  attn_part<<<NBH * 32, 256, 0, stream>>>(Q, Kt, V, Mtop, pmax, psum, pvp);
  attn_combine<<<NBH * UP, 64, 0, stream>>>(pmax, psum, pvp, upd);

  fillctx_kernel<<<4096, 256, 0, stream>>>(mnV, ctx);
  scatter_kernel<<<NBH * UP, 64, 0, stream>>>(upd, Mtop, ctx);

  meanout_kernel<<<4, 256, 0, stream>>>(mnV, Wo, bo, mo);
  fillout_kernel<<<4096, 256, 0, stream>>>(mo, out);
  gemm_rows<<<160, 256, 0, stream>>>(ctx, Wo, bo, rows, cnt, out);
}

// Round 18
// 321.349 us; speedup vs baseline: 1.0566x; 1.0566x over previous
//
#include <hip/hip_runtime.h>
#include <hip/hip_bf16.h>

// Problem constants
#define KN 2048
#define BB 4
#define DM 512
#define NH 8
#define HE 64
#define UP 40
#define NBH 32          // B*H
#define NROWS 8192      // KN*B
#define MiB(x) ((size_t)(x) << 20)

typedef __attribute__((ext_vector_type(8))) short short8;
typedef __attribute__((ext_vector_type(4))) float f32x4;

// bf16 split helpers (RNE)
__device__ __forceinline__ ushort f2bf(float x) {
  unsigned u = __float_as_uint(x);
  unsigned r = (u + 0x7FFFu + ((u >> 16) & 1u)) >> 16;
  return (ushort)r;
}
__device__ __forceinline__ float bf2f(ushort h) {
  return __uint_as_float((unsigned)h << 16);
}

// ---------------------------------------------------------------------------
// Fused split of the 3 weight matrices into hi/lo bf16 planes.
// grid 1536: which = bid>>9
// ---------------------------------------------------------------------------
__global__ __launch_bounds__(256) void wsplit3_kernel(
    const float* __restrict__ W0, const float* __restrict__ W1,
    const float* __restrict__ W2, ushort* __restrict__ Wh,
    ushort* __restrict__ Wl) {
  const int which = blockIdx.x >> 9;
  const float* W = (which == 0) ? W0 : (which == 1) ? W1 : W2;
  size_t base = (size_t)which * 262144;
  int i = ((blockIdx.x & 511) * 256 + threadIdx.x) * 2;
  float2 v = *(const float2*)(W + i);
  ushort h0 = f2bf(v.x), h1 = f2bf(v.y);
  ushort l0 = f2bf(v.x - bf2f(h0)), l1 = f2bf(v.y - bf2f(h1));
  *(ushort2*)(Wh + base + i) = make_ushort2(h0, h1);
  *(ushort2*)(Wl + base + i) = make_ushort2(l0, l1);
}

// ---------------------------------------------------------------------------
// Fused split of the 3 activation matrices (8192x512 each).
// grid 12288: which = bid>>12. Dest pointers differ per input (disjoint ws).
// ---------------------------------------------------------------------------
__global__ __launch_bounds__(256) void asplit3_kernel(
    const float* __restrict__ A0, const float* __restrict__ A1,
    const float* __restrict__ A2, ushort* __restrict__ Ah0,
    ushort* __restrict__ Al0, ushort* __restrict__ Ah1,
    ushort* __restrict__ Al1, ushort* __restrict__ Ah2,
    ushort* __restrict__ Al2) {
  const int which = blockIdx.x >> 12;
  const float* A = (which == 0) ? A0 : (which == 1) ? A1 : A2;
  ushort* Ah = (which == 0) ? Ah0 : (which == 1) ? Ah1 : Ah2;
  ushort* Al = (which == 0) ? Al0 : (which == 1) ? Al1 : Al2;
  size_t i = ((size_t)(blockIdx.x & 4095) * 256 + threadIdx.x) * 4;
  float4 v = *(const float4*)(A + i);
  ushort h0 = f2bf(v.x), h1 = f2bf(v.y), h2 = f2bf(v.z), h3 = f2bf(v.w);
  ushort l0 = f2bf(v.x - bf2f(h0)), l1 = f2bf(v.y - bf2f(h1));
  ushort l2 = f2bf(v.z - bf2f(h2)), l3 = f2bf(v.w - bf2f(h3));
  *(ushort4*)(Ah + i) = make_ushort4(h0, h1, h2, h3);
  *(ushort4*)(Al + i) = make_ushort4(l0, l1, l2, l3);
}

// ---------------------------------------------------------------------------
// Fused 3-GEMM split-bf16 MFMA, all-global fragments, no LDS/barriers.
// grid 1536: which = bid>>9 selects (A,W,bias,scale,C); sub-grid decode as
// R11 (XCD-aware; 512%8==0 so each sub-grid cycles all XCDs).
// 6 blocks/CU -> 24 waves/CU for latency hiding. #pragma unroll 4 k-loop
// gives 4 k-steps of independent loads in flight.
// ---------------------------------------------------------------------------
__global__ __launch_bounds__(256) void gemm3_mfma(
    const ushort* __restrict__ Ahq, const ushort* __restrict__ Alq,
    const ushort* __restrict__ Ahk, const ushort* __restrict__ Alk,
    const ushort* __restrict__ Ahv, const ushort* __restrict__ Alv,
    const ushort* __restrict__ Wh3, const ushort* __restrict__ Wl3,
    const float* __restrict__ bq, const float* __restrict__ bk,
    const float* __restrict__ bv, float* __restrict__ Q,
    float* __restrict__ K, float* __restrict__ V) {
  const int which = blockIdx.x >> 9;
  const int bid = blockIdx.x & 511;
  const ushort* Ah = (which == 0) ? Ahq : (which == 1) ? Ahk : Ahv;
  const ushort* Al = (which == 0) ? Alq : (which == 1) ? Alk : Alv;
  const ushort* Wh = Wh3 + (size_t)which * 262144;
  const ushort* Wl = Wl3 + (size_t)which * 262144;
  const float* bias = (which == 0) ? bq : (which == 1) ? bk : bv;
  float* C = (which == 0) ? Q : (which == 1) ? K : V;
  const float scale = (which == 0) ? 0.125f : 1.0f;

  const int mt = (bid & 7) * 8 + ((bid >> 3) & 7);  // 0..63
  const int ot = bid >> 6;                          // 0..7
  const int m0 = mt * 128, o0 = ot * 64;
  const int tid = threadIdx.x;
  const int w = tid >> 6, lane = tid & 63;
  const int fr = lane & 15;      // fragment row
  const int kc = lane >> 4;      // k-chunk (8 bf16)

  f32x4 acc[2][4];
#pragma unroll
  for (int i = 0; i < 2; ++i)
#pragma unroll
    for (int j = 0; j < 4; ++j)
#pragma unroll
      for (int r = 0; r < 4; ++r) acc[i][j][r] = 0.f;

  const size_t arow0 = (size_t)(m0 + w * 32 + fr) * 512 + kc * 8;
  const size_t arow1 = arow0 + (size_t)16 * 512;
  const size_t wrow0 = (size_t)(o0 + fr) * 512 + kc * 8;

#pragma unroll 4
  for (int k0 = 0; k0 < 512; k0 += 32) {
    short8 ah[2], al[2], bh[4], bl[4];
    ah[0] = *(const short8*)(Ah + arow0 + k0);
    al[0] = *(const short8*)(Al + arow0 + k0);
    ah[1] = *(const short8*)(Ah + arow1 + k0);
    al[1] = *(const short8*)(Al + arow1 + k0);
#pragma unroll
    for (int j = 0; j < 4; ++j) {
      size_t off = wrow0 + (size_t)j * 16 * 512 + k0;
      bh[j] = *(const short8*)(Wh + off);
      bl[j] = *(const short8*)(Wl + off);
    }
#pragma unroll
    for (int i = 0; i < 2; ++i)
#pragma unroll
      for (int j = 0; j < 4; ++j) {
        acc[i][j] = __builtin_amdgcn_mfma_f32_16x16x32_bf16(ah[i], bh[j], acc[i][j], 0, 0, 0);
        acc[i][j] = __builtin_amdgcn_mfma_f32_16x16x32_bf16(ah[i], bl[j], acc[i][j], 0, 0, 0);
        acc[i][j] = __builtin_amdgcn_mfma_f32_16x16x32_bf16(al[i], bh[j], acc[i][j], 0, 0, 0);
        acc[i][j] = __builtin_amdgcn_mfma_f32_16x16x32_bf16(al[i], bl[j], acc[i][j], 0, 0, 0);
      }
  }

#pragma unroll
  for (int i = 0; i < 2; ++i)
#pragma unroll
    for (int j = 0; j < 4; ++j)
#pragma unroll
      for (int r = 0; r < 4; ++r) {
        int m = m0 + w * 32 + i * 16 + (lane >> 4) * 4 + r;
        int o = o0 + j * 16 + fr;
        C[(size_t)m * 512 + o] = (acc[i][j][r] + bias[o]) * scale;
      }
}

// ---------------------------------------------------------------------------
// Transpose K into Kt[bh][e][n] for coalesced attention score reads.
// ---------------------------------------------------------------------------
__global__ __launch_bounds__(256) void transposeK_kernel(
    const float* __restrict__ K, float* __restrict__ Kt) {
  const int bh = blockIdx.x & 31;
  const int nt = blockIdx.x >> 5;       // 0..15
  const int b = bh >> 3, h = bh & 7;
  const int n0 = nt * 128;
  const int tid = threadIdx.x;
  __shared__ float T[128][65];

#pragma unroll
  for (int i = 0; i < 8; ++i) {
    int flat = tid + i * 256;           // 0..2047
    int r = flat >> 4;                  // 0..127
    int c4 = flat & 15;                 // 0..15
    float4 v = *(const float4*)(K + (((size_t)(n0 + r) * 4 + b) * 8 + h) * 64 + c4 * 4);
    T[r][c4 * 4 + 0] = v.x; T[r][c4 * 4 + 1] = v.y;
    T[r][c4 * 4 + 2] = v.z; T[r][c4 * 4 + 3] = v.w;
  }
  __syncthreads();

  const int nl = tid & 127;             // 0..127
  const int eg = tid >> 7;              // 0..1
#pragma unroll
  for (int e = eg * 32; e < eg * 32 + 32; ++e)
    Kt[((size_t)bh * 64 + e) * 2048 + n0 + nl] = T[nl][e];
}

// ---------------------------------------------------------------------------
// M scores, wave-cooperative gather. One wave per (bh, n).
// ---------------------------------------------------------------------------
__global__ __launch_bounds__(256) void mscore_kernel(
    const float* __restrict__ Q, const float* __restrict__ K,
    const int* __restrict__ idx, float* __restrict__ Mout) {
  const int bh = blockIdx.x & 31;
  const int c  = blockIdx.x >> 5;        // 0..511
  const int wv = threadIdx.x >> 6;       // 0..3
  const int lane = threadIdx.x & 63;
  const int n = c * 4 + wv;
  const int b = bh >> 3, h = bh & 7;
  const int g = lane >> 4;               // sample group 0..3
  const int e16 = lane & 15;             // element chunk within row

  const float4 qv = *(const float4*)(Q + (((size_t)n * 4 + b) * 8 + h) * 64 + e16 * 4);

  float mx = -INFINITY, sm = 0.f;
#pragma unroll
  for (int it = 0; it < 10; ++it) {
    const int s = it * 4 + g;
    const int kn = idx[n * UP + s];
    const float4 kv = *(const float4*)(K + (((size_t)kn * 4 + b) * 8 + h) * 64 + e16 * 4);
    float d = qv.x * kv.x + qv.y * kv.y + qv.z * kv.z + qv.w * kv.w;
    d += __shfl_xor(d, 1);
    d += __shfl_xor(d, 2);
    d += __shfl_xor(d, 4);
    d += __shfl_xor(d, 8);
    mx = fmaxf(mx, d);
    sm += d;
  }
  mx = fmaxf(mx, __shfl_xor(mx, 16));
  mx = fmaxf(mx, __shfl_xor(mx, 32));
  sm += __shfl_xor(sm, 16);
  sm += __shfl_xor(sm, 32);
  if (lane == 0) Mout[(size_t)bh * 2048 + n] = mx - sm * (1.0f / (float)KN);
}

// ---------------------------------------------------------------------------
// top-40 per (b,h) via 4-pass byte radix-select (R14, verified).
// ---------------------------------------------------------------------------
__global__ __launch_bounds__(256) void topk_kernel(
    const float* __restrict__ M, int* __restrict__ Mtop) {
  const int bh = blockIdx.x;
  __shared__ unsigned keys[2048];
  __shared__ int hist[256];
  __shared__ int suf[256];
  __shared__ int scal[2];
  __shared__ int ties[128];
  __shared__ int cnts[2];

  const int tid = threadIdx.x;
  const float* Mrow = M + (size_t)bh * 2048;
#pragma unroll
  for (int i = 0; i < 8; ++i) {
    int j = tid + i * 256;
    unsigned u = __float_as_uint(Mrow[j]);
    keys[j] = (u & 0x80000000u) ? ~u : (u | 0x80000000u);  // monotone map
  }
  if (tid < 2) cnts[tid] = 0;

  unsigned prefix = 0, prefmask = 0;
  int rank = UP;
#pragma unroll
  for (int shift = 24; shift >= 0; shift -= 8) {
    hist[tid] = 0;
    __syncthreads();
#pragma unroll
    for (int i = 0; i < 8; ++i) {
      unsigned k = keys[tid + i * 256];
      if ((k & prefmask) == prefix)
        atomicAdd(&hist[(k >> shift) & 0xFFu], 1);
    }
    __syncthreads();
    suf[tid] = hist[tid];
    __syncthreads();
#pragma unroll
    for (int off = 1; off < 256; off <<= 1) {
      int add = (tid + off < 256) ? suf[tid + off] : 0;
      __syncthreads();
      suf[tid] += add;
      __syncthreads();
    }
    {
      int above = suf[tid] - hist[tid];
      if (above < rank && rank <= suf[tid]) {
        scal[0] = tid;
        scal[1] = rank - above;
      }
    }
    __syncthreads();
    prefix |= ((unsigned)scal[0]) << shift;
    prefmask |= 0xFFu << shift;
    rank = scal[1];
    __syncthreads();
  }
  const unsigned T = prefix;

#pragma unroll
  for (int i = 0; i < 8; ++i) {
    int j = tid + i * 256;
    unsigned k = keys[j];
    if (k > T) {
      int p = atomicAdd(&cnts[0], 1);
      Mtop[bh * UP + p] = j;
    } else if (k == T) {
      int p = atomicAdd(&cnts[1], 1);
      if (p < 128) ties[p] = j;
    }
  }
  __syncthreads();
  if (tid == 0) {
    int base = cnts[0];
    int need = UP - base;
    int tc = cnts[1] < 128 ? cnts[1] : 128;
    for (int s = 0; s < need; ++s) {
      int best = 1 << 30, bj = 0;
      for (int j = 0; j < tc; ++j) {
        int v = ties[j];
        if (v < best) { best = v; bj = j; }
      }
      Mtop[bh * UP + base + s] = best;
      ties[bj] = 1 << 30;
    }
  }
}

// ---------------------------------------------------------------------------
// mean of V: two-phase coalesced column-sum (V is a [2048][2048] matrix).
// ---------------------------------------------------------------------------
__global__ __launch_bounds__(256) void meanv_part(
    const float* __restrict__ V, float* __restrict__ part) {
  const int rc = blockIdx.x >> 3;      // 0..31
  const int cc = blockIdx.x & 7;       // 0..7
  const int c = cc * 256 + threadIdx.x;
  const float* p = V + (size_t)rc * 64 * 2048 + c;
  float acc = 0.f;
#pragma unroll 8
  for (int i = 0; i < 64; ++i) acc += p[(size_t)i * 2048];
  part[(size_t)rc * 2048 + c] = acc;
}

__global__ __launch_bounds__(256) void meanv_final(
    const float* __restrict__ part, float* __restrict__ mnV) {
  const int c = blockIdx.x * 256 + threadIdx.x;   // 8 blocks
  float acc = 0.f;
#pragma unroll
  for (int r = 0; r < 32; ++r) acc += part[(size_t)r * 2048 + c];
  mnV[c] = acc * (1.0f / (float)KN);
}

// ---------------------------------------------------------------------------
// Selected-row machinery for the sparse output GEMM.
// ---------------------------------------------------------------------------
__global__ void selbuild_kernel(const int* __restrict__ Mtop,
                                int* __restrict__ flags) {
  const int i = blockIdx.x * 64 + threadIdx.x;   // 0..1279
  const int bh = i / UP;
  const int b = bh >> 3;
  flags[b * 2048 + Mtop[i]] = 1;
}

__global__ void selcompact_kernel(const int* __restrict__ flags,
                                  int* __restrict__ rows,
                                  int* __restrict__ cnt) {
  const int i = blockIdx.x * 256 + threadIdx.x;  // 0..8191
  if (flags[i]) {
    int p = atomicAdd(cnt, 1);
    rows[p] = i;                                  // flat row index b*2048+n
  }
}

// meanout[b][o] = dot(mnV[b*512..], Wo[o]) + bo[o]
__global__ __launch_bounds__(256) void meanout_kernel(
    const float* __restrict__ mnV, const float* __restrict__ Wo,
    const float* __restrict__ bo, float* __restrict__ mo) {
  const int b = blockIdx.x;           // 4 blocks
  for (int o = threadIdx.x; o < 512; o += 256) {
    const float* m = mnV + b * 512;
    const float* w = Wo + (size_t)o * 512;
    float acc = 0.f;
#pragma unroll 8
    for (int k = 0; k < 512; ++k) acc = fmaf(m[k], w[k], acc);
    mo[b * 512 + o] = acc + bo[o];
  }
}

// out broadcast fill (float4)
__global__ void fillout_kernel(const float* __restrict__ mo,
                               float* __restrict__ out) {
  size_t i = ((size_t)blockIdx.x * 256 + threadIdx.x) * 4;
  int d = (int)(i & 511);
  int b = (int)(i >> 20);
  float4 v = *(const float4*)(mo + (b << 9) + d);
  *(float4*)(out + i) = v;
}

// ---------------------------------------------------------------------------
// Sparse output GEMM over selected rows only (<=1280 of 8192).
// ---------------------------------------------------------------------------
__global__ __launch_bounds__(256) void gemm_rows(
    const float* __restrict__ ctx, const float* __restrict__ W,
    const float* __restrict__ bias, const int* __restrict__ rows,
    const int* __restrict__ cnt, float* __restrict__ out) {
  __shared__ float As[32][68];
  __shared__ float Ws[32][68];
  __shared__ int rsel[64];
  const int rt = blockIdx.x >> 3;      // 0..19
  const int ot = blockIdx.x & 7;       // 0..7
  const int o0 = ot * 64;
  const int tid = threadIdx.x;
  const int tx = tid & 15;
  const int ty = tid >> 4;
  const int n = *cnt;

  if (rt * 64 >= n) return;

  if (tid < 64) {
    int g = rt * 64 + tid;
    rsel[tid] = (g < n) ? rows[g] : rows[0];
  }
  __syncthreads();

  float acc[4][4] = {};
  for (int k0 = 0; k0 < 512; k0 += 32) {
#pragma unroll
    for (int i = 0; i < 2; ++i) {
      int flat = tid + i * 256;        // 0..511
      int r = flat >> 3;               // 0..63
      int c4 = flat & 7;
      float4 av = *(const float4*)(ctx + (size_t)rsel[r] * 512 + k0 + c4 * 4);
      float4 wv = *(const float4*)(W + (size_t)(o0 + r) * 512 + k0 + c4 * 4);
      As[c4 * 4 + 0][r] = av.x; As[c4 * 4 + 1][r] = av.y;
      As[c4 * 4 + 2][r] = av.z; As[c4 * 4 + 3][r] = av.w;
      Ws[c4 * 4 + 0][r] = wv.x; Ws[c4 * 4 + 1][r] = wv.y;
      Ws[c4 * 4 + 2][r] = wv.z; Ws[c4 * 4 + 3][r] = wv.w;
    }
    __syncthreads();
#pragma unroll
    for (int kk = 0; kk < 32; ++kk) {
      float a_[4], w_[4];
#pragma unroll
      for (int i = 0; i < 4; ++i) a_[i] = As[kk][ty * 4 + i];
#pragma unroll
      for (int j = 0; j < 4; ++j) w_[j] = Ws[kk][tx * 4 + j];
#pragma unroll
      for (int i = 0; i < 4; ++i)
#pragma unroll
        for (int j = 0; j < 4; ++j)
          acc[i][j] = fmaf(a_[i], w_[j], acc[i][j]);
    }
    __syncthreads();
  }

#pragma unroll
  for (int i = 0; i < 4; ++i) {
    int g = rt * 64 + ty * 4 + i;
    if (g < n) {
      int m = rsel[ty * 4 + i];
#pragma unroll
      for (int j = 0; j < 4; ++j) {
        int o = o0 + tx * 4 + j;
        out[(size_t)m * 512 + o] = acc[i][j] + bias[o];
      }
    }
  }
}

// ---------------------------------------------------------------------------
// Flash-split attention (R15, verified): grid 1024, bid%8 == bh%8.
// ---------------------------------------------------------------------------
#define QG 5   // queries per block
#define NC 4   // n-chunks
__global__ __launch_bounds__(256) void attn_part(
    const float* __restrict__ Q, const float* __restrict__ Kt,
    const float* __restrict__ V, const int* __restrict__ Mtop,
    float* __restrict__ pmax, float* __restrict__ psum,
    float* __restrict__ pvp) {
  const int bh = blockIdx.x & 31;
  const int t  = blockIdx.x >> 5;       // 0..31
  const int g  = t & 7;                 // query group
  const int ch = t >> 3;                // n-chunk
  const int b = bh >> 3, h = bh & 7;
  const int tid = threadIdx.x;
  const int wv = tid >> 6, lane = tid & 63;
  const int n0 = ch * 512;

  __shared__ float qs[QG][64];
  __shared__ float p[QG][512];
  __shared__ float redm[QG][4];
  __shared__ float reds[QG][4];
  __shared__ float pvs[4][QG][64];

  for (int i = tid; i < QG * 64; i += 256) {
    int q = i >> 6, e = i & 63;
    int nq = Mtop[bh * UP + g * QG + q];
    qs[q][e] = Q[(((size_t)nq * 4 + b) * 8 + h) * 64 + e];
  }
  __syncthreads();

  const float* ktb = Kt + (size_t)bh * 64 * 2048;
  float d0[QG] = {}, d1[QG] = {};
  const int nb = n0 + tid * 2;
  for (int e = 0; e < 64; ++e) {
    float2 kv = *(const float2*)(ktb + (size_t)e * 2048 + nb);
#pragma unroll
    for (int q = 0; q < QG; ++q) {
      float qe = qs[q][e];
      d0[q] = fmaf(qe, kv.x, d0[q]);
      d1[q] = fmaf(qe, kv.y, d1[q]);
    }
  }

#pragma unroll
  for (int q = 0; q < QG; ++q) {
    float m_ = fmaxf(d0[q], d1[q]);
#pragma unroll
    for (int off = 1; off < 64; off <<= 1)
      m_ = fmaxf(m_, __shfl_xor(m_, off));
    if (lane == 0) redm[q][wv] = m_;
  }
  __syncthreads();
  float gm[QG];
#pragma unroll
  for (int q = 0; q < QG; ++q)
    gm[q] = fmaxf(fmaxf(redm[q][0], redm[q][1]),
                  fmaxf(redm[q][2], redm[q][3]));

  float ls[QG];
#pragma unroll
  for (int q = 0; q < QG; ++q) {
    float e0 = __expf(d0[q] - gm[q]);
    float e1 = __expf(d1[q] - gm[q]);
    p[q][tid * 2] = e0;
    p[q][tid * 2 + 1] = e1;
    ls[q] = e0 + e1;
  }
#pragma unroll
  for (int q = 0; q < QG; ++q) {
    float s_ = ls[q];
#pragma unroll
    for (int off = 1; off < 64; off <<= 1)
      s_ += __shfl_xor(s_, off);
    if (lane == 0) reds[q][wv] = s_;
  }
  __syncthreads();
  float den[QG];
#pragma unroll
  for (int q = 0; q < QG; ++q)
    den[q] = reds[q][0] + reds[q][1] + reds[q][2] + reds[q][3];

  float acc[QG] = {};
  for (int nn = wv * 128; nn < wv * 128 + 128; ++nn) {
    float v = V[(((size_t)(n0 + nn) * 4 + b) * 8 + h) * 64 + lane];
#pragma unroll
    for (int q = 0; q < QG; ++q) acc[q] = fmaf(p[q][nn], v, acc[q]);
  }
#pragma unroll
  for (int q = 0; q < QG; ++q) pvs[wv][q][lane] = acc[q];
  __syncthreads();

  for (int i = tid; i < QG * 64; i += 256) {
    int q = i >> 6, e = i & 63;
    int slot = bh * UP + g * QG + q;
    float pv = pvs[0][q][e] + pvs[1][q][e] + pvs[2][q][e] + pvs[3][q][e];
    pvp[((size_t)slot * NC + ch) * 64 + e] = pv;
    if (e == 0) {
      pmax[slot * NC + ch] = gm[q];
      psum[slot * NC + ch] = den[q];
    }
  }
}

__global__ __launch_bounds__(64) void attn_combine(
    const float* __restrict__ pmax, const float* __restrict__ psum,
    const float* __restrict__ pvp, float* __restrict__ upd) {
  const int slot = blockIdx.x;     // 0..1279
  const int e = threadIdx.x;
  float m = -INFINITY;
#pragma unroll
  for (int ch = 0; ch < NC; ++ch) m = fmaxf(m, pmax[slot * NC + ch]);
  float den = 0.f, num = 0.f;
#pragma unroll
  for (int ch = 0; ch < NC; ++ch) {
    float w = __expf(pmax[slot * NC + ch] - m);
    den = fmaf(w, psum[slot * NC + ch], den);
    num = fmaf(w, pvp[((size_t)slot * NC + ch) * 64 + e], num);
  }
  upd[(size_t)slot * 64 + e] = num / den;
}

// ---------------------------------------------------------------------------
// ctx fill + scatter
// ---------------------------------------------------------------------------
__global__ void fillctx_kernel(const float* __restrict__ meanV,
                               float* __restrict__ ctx) {
  size_t i = ((size_t)blockIdx.x * 256 + threadIdx.x) * 4;
  int d = (int)(i & 511);
  int b = (int)(i >> 20);
  float4 v = *(const float4*)(meanV + (b << 9) + d);
  *(float4*)(ctx + i) = v;
}

__global__ void scatter_kernel(const float* __restrict__ upd,
                               const int* __restrict__ Mtop,
                               float* __restrict__ ctx) {
  const int blk = blockIdx.x;   // bh*40 + s
  const int bh = blk / UP;
  const int b = bh >> 3, h = bh & 7;
  const int n = Mtop[blk];
  ctx[((size_t)(b * 2048 + n)) * 512 + h * 64 + threadIdx.x] =
      upd[(size_t)blk * 64 + threadIdx.x];
}

// ---------------------------------------------------------------------------
// Workspace layout (~102 MiB used; ws >= 113 MiB proven in R4):
//   [0, 256K) Mbuf | [256K,576K) upd | [589824,598016) mnV
//   [598016,603136) Mtop | [634880,897024) vpart | [903168,935936) flags
//   [935936,935940) cnt | [936192,941312) rows | [941312,949504) mo
//   [1M,17M) Q(ctx alias) [17M,33M) K [33M,49M) V
//   [49M,57M) Ahv / [57M,65M) Alv   (dead after GEMM; Kt overwrites)
//   [49M,65M) Kt (written by transposeK after GEMMs)
//   [65M..66.5M) Wh3 | [66.5M..68M) Wl3 (3 x 512KB planes each)
//   [68M..68M+64K) pmax/psum | [..~69.4M) pvp
//   [70M,78M) Ahq | [78M,86M) Alq | [86M,94M) Ahk | [94M,102M) Alk
// ---------------------------------------------------------------------------
extern "C" void kernel_launch(void* const* d_in, const int* in_sizes, int n_in,
                              void* d_out, int out_size, void* d_ws,
                              size_t ws_size, hipStream_t stream) {
  const float* query = (const float*)d_in[0];
  const float* key   = (const float*)d_in[1];
  const float* value = (const float*)d_in[2];
  const int*   idxs  = (const int*)d_in[3];
  const float* Wq = (const float*)d_in[4];
  const float* bq = (const float*)d_in[5];
  const float* Wk = (const float*)d_in[6];
  const float* bk = (const float*)d_in[7];
  const float* Wv = (const float*)d_in[8];
  const float* bv = (const float*)d_in[9];
  const float* Wo = (const float*)d_in[10];
  const float* bo = (const float*)d_in[11];
  float* out = (float*)d_out;    // reference output dtype is float32

  char* ws = (char*)d_ws;
  float*  Mbuf  = (float*)(ws + 0);
  float*  upd   = (float*)(ws + 262144);
  float*  mnV   = (float*)(ws + 589824);
  int*    Mtop  = (int*)  (ws + 598016);
  float*  vpart = (float*)(ws + 634880);
  int*    flags = (int*)  (ws + 903168);
  int*    cnt   = (int*)  (ws + 935936);
  int*    rows  = (int*)  (ws + 936192);
  float*  mo    = (float*)(ws + 941312);
  float*  Q     = (float*)(ws + MiB(1));
  float*  K     = (float*)(ws + MiB(17));
  float*  V     = (float*)(ws + MiB(33));
  float*  Kt    = (float*)(ws + MiB(49));
  ushort* Ahv   = (ushort*)(ws + MiB(49));           // dead before Kt write
  ushort* Alv   = (ushort*)(ws + MiB(57));
  ushort* Wh3   = (ushort*)(ws + MiB(65));           // 3 x 512KB
  ushort* Wl3   = (ushort*)(ws + MiB(65) + 1572864);
  float*  pmax  = (float*)(ws + MiB(68));
  float*  psum  = (float*)(ws + MiB(68) + 32768);
  float*  pvp   = (float*)(ws + MiB(68) + 65536);
  ushort* Ahq   = (ushort*)(ws + MiB(70));
  ushort* Alq   = (ushort*)(ws + MiB(78));
  ushort* Ahk   = (ushort*)(ws + MiB(86));
  ushort* Alk   = (ushort*)(ws + MiB(94));
  float*  ctx   = Q;   // Q dead after attn; ctx written afterwards

  // zero flags + cnt (contiguous region)
  hipMemsetAsync(flags, 0, 32768 + 4, stream);

  wsplit3_kernel<<<1536, 256, 0, stream>>>(Wq, Wk, Wv, Wh3, Wl3);
  asplit3_kernel<<<12288, 256, 0, stream>>>(query, key, value,
                                            Ahq, Alq, Ahk, Alk, Ahv, Alv);
  gemm3_mfma<<<1536, 256, 0, stream>>>(Ahq, Alq, Ahk, Alk, Ahv, Alv,
                                       Wh3, Wl3, bq, bk, bv, Q, K, V);

  transposeK_kernel<<<512, 256, 0, stream>>>(K, Kt);

  mscore_kernel<<<16384, 256, 0, stream>>>(Q, K, idxs, Mbuf);
  topk_kernel<<<NBH, 256, 0, stream>>>(Mbuf, Mtop);
  selbuild_kernel<<<20, 64, 0, stream>>>(Mtop, flags);
  selcompact_kernel<<<32, 256, 0, stream>>>(flags, rows, cnt);

  meanv_part<<<256, 256, 0, stream>>>(V, vpart);
  meanv_final<<<8, 256, 0, stream>>>(vpart, mnV);

  attn_part<<<NBH * 32, 256, 0, stream>>>(Q, Kt, V, Mtop, pmax, psum, pvp);
  attn_combine<<<NBH * UP, 64, 0, stream>>>(pmax, psum, pvp, upd);

  fillctx_kernel<<<4096, 256, 0, stream>>>(mnV, ctx);
  scatter_kernel<<<NBH * UP, 64, 0, stream>>>(upd, Mtop, ctx);

  meanout_kernel<<<4, 256, 0, stream>>>(mnV, Wo, bo, mo);
  fillout_kernel<<<4096, 256, 0, stream>>>(mo, out);
  gemm_rows<<<160, 256, 0, stream>>>(ctx, Wo, bo, rows, cnt, out);
}

// Round 19
// 320.028 us; speedup vs baseline: 1.0609x; 1.0041x over previous
//
#include <hip/hip_runtime.h>
#include <hip/hip_bf16.h>

// Problem constants
#define KN 2048
#define BB 4
#define DM 512
#define NH 8
#define HE 64
#define UP 40
#define NBH 32          // B*H
#define NROWS 8192      // KN*B
#define MiB(x) ((size_t)(x) << 20)

typedef __attribute__((ext_vector_type(8))) short short8;
typedef __attribute__((ext_vector_type(4))) float f32x4;

// bf16 split helpers (RNE)
__device__ __forceinline__ ushort f2bf(float x) {
  unsigned u = __float_as_uint(x);
  unsigned r = (u + 0x7FFFu + ((u >> 16) & 1u)) >> 16;
  return (ushort)r;
}
__device__ __forceinline__ float bf2f(ushort h) {
  return __uint_as_float((unsigned)h << 16);
}

// ---------------------------------------------------------------------------
// Fused split of the 3 weight matrices into hi/lo bf16 planes.
// ---------------------------------------------------------------------------
__global__ __launch_bounds__(256) void wsplit3_kernel(
    const float* __restrict__ W0, const float* __restrict__ W1,
    const float* __restrict__ W2, ushort* __restrict__ Wh,
    ushort* __restrict__ Wl) {
  const int which = blockIdx.x >> 9;
  const float* W = (which == 0) ? W0 : (which == 1) ? W1 : W2;
  size_t base = (size_t)which * 262144;
  int i = ((blockIdx.x & 511) * 256 + threadIdx.x) * 2;
  float2 v = *(const float2*)(W + i);
  ushort h0 = f2bf(v.x), h1 = f2bf(v.y);
  ushort l0 = f2bf(v.x - bf2f(h0)), l1 = f2bf(v.y - bf2f(h1));
  *(ushort2*)(Wh + base + i) = make_ushort2(h0, h1);
  *(ushort2*)(Wl + base + i) = make_ushort2(l0, l1);
}

// ---------------------------------------------------------------------------
// Fused split of the 3 activation matrices (8192x512 each).
// ---------------------------------------------------------------------------
__global__ __launch_bounds__(256) void asplit3_kernel(
    const float* __restrict__ A0, const float* __restrict__ A1,
    const float* __restrict__ A2, ushort* __restrict__ Ah0,
    ushort* __restrict__ Al0, ushort* __restrict__ Ah1,
    ushort* __restrict__ Al1, ushort* __restrict__ Ah2,
    ushort* __restrict__ Al2) {
  const int which = blockIdx.x >> 12;
  const float* A = (which == 0) ? A0 : (which == 1) ? A1 : A2;
  ushort* Ah = (which == 0) ? Ah0 : (which == 1) ? Ah1 : Ah2;
  ushort* Al = (which == 0) ? Al0 : (which == 1) ? Al1 : Al2;
  size_t i = ((size_t)(blockIdx.x & 4095) * 256 + threadIdx.x) * 4;
  float4 v = *(const float4*)(A + i);
  ushort h0 = f2bf(v.x), h1 = f2bf(v.y), h2 = f2bf(v.z), h3 = f2bf(v.w);
  ushort l0 = f2bf(v.x - bf2f(h0)), l1 = f2bf(v.y - bf2f(h1));
  ushort l2 = f2bf(v.z - bf2f(h2)), l3 = f2bf(v.w - bf2f(h3));
  *(ushort4*)(Ah + i) = make_ushort4(h0, h1, h2, h3);
  *(ushort4*)(Al + i) = make_ushort4(l0, l1, l2, l3);
}

// ---------------------------------------------------------------------------
// Fused 3-GEMM split-bf16 MFMA, all-global fragments, no LDS/barriers,
// HAND SOFTWARE-PIPELINED: double-buffered fragment registers so the next
// k-step's 12 loads are issued BEFORE the current k-step's 128 MFMAs
// (~640 cyc) -> L2 latency (~300 cyc) fully covered. All buffer indices are
// compile-time (rule #20); expect VGPR ~140-160 = pipeline accepted.
// ---------------------------------------------------------------------------
#define LOAD_FRAGS(B, K0)                                                  \
  do {                                                                     \
    pah##B##0 = *(const short8*)(Ah + arow0 + (K0));                       \
    pal##B##0 = *(const short8*)(Al + arow0 + (K0));                       \
    pah##B##1 = *(const short8*)(Ah + arow1 + (K0));                       \
    pal##B##1 = *(const short8*)(Al + arow1 + (K0));                       \
    pbh##B##0 = *(const short8*)(Wh + wrow0 + 0 * 8192 + (K0));            \
    pbl##B##0 = *(const short8*)(Wl + wrow0 + 0 * 8192 + (K0));            \
    pbh##B##1 = *(const short8*)(Wh + wrow0 + 1 * 8192 + (K0));            \
    pbl##B##1 = *(const short8*)(Wl + wrow0 + 1 * 8192 + (K0));            \
    pbh##B##2 = *(const short8*)(Wh + wrow0 + 2 * 8192 + (K0));            \
    pbl##B##2 = *(const short8*)(Wl + wrow0 + 2 * 8192 + (K0));            \
    pbh##B##3 = *(const short8*)(Wh + wrow0 + 3 * 8192 + (K0));            \
    pbl##B##3 = *(const short8*)(Wl + wrow0 + 3 * 8192 + (K0));            \
  } while (0)

#define MFMA_ONE(B, I, J)                                                    \
  do {                                                                      \
    acc[I][J] = __builtin_amdgcn_mfma_f32_16x16x32_bf16(pah##B##I, pbh##B##J, acc[I][J], 0, 0, 0); \
    acc[I][J] = __builtin_amdgcn_mfma_f32_16x16x32_bf16(pah##B##I, pbl##B##J, acc[I][J], 0, 0, 0); \
    acc[I][J] = __builtin_amdgcn_mfma_f32_16x16x32_bf16(pal##B##I, pbh##B##J, acc[I][J], 0, 0, 0); \
    acc[I][J] = __builtin_amdgcn_mfma_f32_16x16x32_bf16(pal##B##I, pbl##B##J, acc[I][J], 0, 0, 0); \
  } while (0)

#define MFMA_STEP(B)                                                       \
  do {                                                                     \
    MFMA_ONE(B, 0, 0); MFMA_ONE(B, 0, 1); MFMA_ONE(B, 0, 2);               \
    MFMA_ONE(B, 0, 3); MFMA_ONE(B, 1, 0); MFMA_ONE(B, 1, 1);               \
    MFMA_ONE(B, 1, 2); MFMA_ONE(B, 1, 3);                                  \
  } while (0)

__global__ __launch_bounds__(256) void gemm3_mfma(
    const ushort* __restrict__ Ahq, const ushort* __restrict__ Alq,
    const ushort* __restrict__ Ahk, const ushort* __restrict__ Alk,
    const ushort* __restrict__ Ahv, const ushort* __restrict__ Alv,
    const ushort* __restrict__ Wh3, const ushort* __restrict__ Wl3,
    const float* __restrict__ bq, const float* __restrict__ bk,
    const float* __restrict__ bv, float* __restrict__ Q,
    float* __restrict__ K, float* __restrict__ V) {
  const int which = blockIdx.x >> 9;
  const int bid = blockIdx.x & 511;
  const ushort* Ah = (which == 0) ? Ahq : (which == 1) ? Ahk : Ahv;
  const ushort* Al = (which == 0) ? Alq : (which == 1) ? Alk : Alv;
  const ushort* Wh = Wh3 + (size_t)which * 262144;
  const ushort* Wl = Wl3 + (size_t)which * 262144;
  const float* bias = (which == 0) ? bq : (which == 1) ? bk : bv;
  float* C = (which == 0) ? Q : (which == 1) ? K : V;
  const float scale = (which == 0) ? 0.125f : 1.0f;

  const int mt = (bid & 7) * 8 + ((bid >> 3) & 7);  // 0..63
  const int ot = bid >> 6;                          // 0..7
  const int m0 = mt * 128, o0 = ot * 64;
  const int tid = threadIdx.x;
  const int w = tid >> 6, lane = tid & 63;
  const int fr = lane & 15;      // fragment row
  const int kc = lane >> 4;      // k-chunk (8 bf16)

  f32x4 acc[2][4];
#pragma unroll
  for (int i = 0; i < 2; ++i)
#pragma unroll
    for (int j = 0; j < 4; ++j)
#pragma unroll
      for (int r = 0; r < 4; ++r) acc[i][j][r] = 0.f;

  const size_t arow0 = (size_t)(m0 + w * 32 + fr) * 512 + kc * 8;
  const size_t arow1 = arow0 + (size_t)16 * 512;
  const size_t wrow0 = (size_t)(o0 + fr) * 512 + kc * 8;

  short8 pah00, pal00, pah01, pal01, pbh00, pbl00, pbh01, pbl01,
         pbh02, pbl02, pbh03, pbl03;
  short8 pah10, pal10, pah11, pal11, pbh10, pbl10, pbh11, pbl11,
         pbh12, pbl12, pbh13, pbl13;

  LOAD_FRAGS(0, 0);
#pragma unroll
  for (int k0 = 0; k0 < 512; k0 += 64) {
    LOAD_FRAGS(1, k0 + 32);
    MFMA_STEP(0);
    if (k0 + 64 < 512) LOAD_FRAGS(0, k0 + 64);
    MFMA_STEP(1);
  }

#pragma unroll
  for (int i = 0; i < 2; ++i)
#pragma unroll
    for (int j = 0; j < 4; ++j)
#pragma unroll
      for (int r = 0; r < 4; ++r) {
        int m = m0 + w * 32 + i * 16 + (lane >> 4) * 4 + r;
        int o = o0 + j * 16 + fr;
        C[(size_t)m * 512 + o] = (acc[i][j][r] + bias[o]) * scale;
      }
}

// ---------------------------------------------------------------------------
// Transpose K into Kt[bh][e][n] for coalesced attention score reads.
// ---------------------------------------------------------------------------
__global__ __launch_bounds__(256) void transposeK_kernel(
    const float* __restrict__ K, float* __restrict__ Kt) {
  const int bh = blockIdx.x & 31;
  const int nt = blockIdx.x >> 5;       // 0..15
  const int b = bh >> 3, h = bh & 7;
  const int n0 = nt * 128;
  const int tid = threadIdx.x;
  __shared__ float T[128][65];

#pragma unroll
  for (int i = 0; i < 8; ++i) {
    int flat = tid + i * 256;           // 0..2047
    int r = flat >> 4;                  // 0..127
    int c4 = flat & 15;                 // 0..15
    float4 v = *(const float4*)(K + (((size_t)(n0 + r) * 4 + b) * 8 + h) * 64 + c4 * 4);
    T[r][c4 * 4 + 0] = v.x; T[r][c4 * 4 + 1] = v.y;
    T[r][c4 * 4 + 2] = v.z; T[r][c4 * 4 + 3] = v.w;
  }
  __syncthreads();

  const int nl = tid & 127;             // 0..127
  const int eg = tid >> 7;              // 0..1
#pragma unroll
  for (int e = eg * 32; e < eg * 32 + 32; ++e)
    Kt[((size_t)bh * 64 + e) * 2048 + n0 + nl] = T[nl][e];
}

// ---------------------------------------------------------------------------
// M scores, wave-cooperative gather. One wave per (bh, n).
// ---------------------------------------------------------------------------
__global__ __launch_bounds__(256) void mscore_kernel(
    const float* __restrict__ Q, const float* __restrict__ K,
    const int* __restrict__ idx, float* __restrict__ Mout) {
  const int bh = blockIdx.x & 31;
  const int c  = blockIdx.x >> 5;        // 0..511
  const int wv = threadIdx.x >> 6;       // 0..3
  const int lane = threadIdx.x & 63;
  const int n = c * 4 + wv;
  const int b = bh >> 3, h = bh & 7;
  const int g = lane >> 4;               // sample group 0..3
  const int e16 = lane & 15;             // element chunk within row

  const float4 qv = *(const float4*)(Q + (((size_t)n * 4 + b) * 8 + h) * 64 + e16 * 4);

  float mx = -INFINITY, sm = 0.f;
#pragma unroll
  for (int it = 0; it < 10; ++it) {
    const int s = it * 4 + g;
    const int kn = idx[n * UP + s];
    const float4 kv = *(const float4*)(K + (((size_t)kn * 4 + b) * 8 + h) * 64 + e16 * 4);
    float d = qv.x * kv.x + qv.y * kv.y + qv.z * kv.z + qv.w * kv.w;
    d += __shfl_xor(d, 1);
    d += __shfl_xor(d, 2);
    d += __shfl_xor(d, 4);
    d += __shfl_xor(d, 8);
    mx = fmaxf(mx, d);
    sm += d;
  }
  mx = fmaxf(mx, __shfl_xor(mx, 16));
  mx = fmaxf(mx, __shfl_xor(mx, 32));
  sm += __shfl_xor(sm, 16);
  sm += __shfl_xor(sm, 32);
  if (lane == 0) Mout[(size_t)bh * 2048 + n] = mx - sm * (1.0f / (float)KN);
}

// ---------------------------------------------------------------------------
// top-40 per (b,h) via 4-pass byte radix-select (R14, verified).
// ---------------------------------------------------------------------------
__global__ __launch_bounds__(256) void topk_kernel(
    const float* __restrict__ M, int* __restrict__ Mtop) {
  const int bh = blockIdx.x;
  __shared__ unsigned keys[2048];
  __shared__ int hist[256];
  __shared__ int suf[256];
  __shared__ int scal[2];
  __shared__ int ties[128];
  __shared__ int cnts[2];

  const int tid = threadIdx.x;
  const float* Mrow = M + (size_t)bh * 2048;
#pragma unroll
  for (int i = 0; i < 8; ++i) {
    int j = tid + i * 256;
    unsigned u = __float_as_uint(Mrow[j]);
    keys[j] = (u & 0x80000000u) ? ~u : (u | 0x80000000u);  // monotone map
  }
  if (tid < 2) cnts[tid] = 0;

  unsigned prefix = 0, prefmask = 0;
  int rank = UP;
#pragma unroll
  for (int shift = 24; shift >= 0; shift -= 8) {
    hist[tid] = 0;
    __syncthreads();
#pragma unroll
    for (int i = 0; i < 8; ++i) {
      unsigned k = keys[tid + i * 256];
      if ((k & prefmask) == prefix)
        atomicAdd(&hist[(k >> shift) & 0xFFu], 1);
    }
    __syncthreads();
    suf[tid] = hist[tid];
    __syncthreads();
#pragma unroll
    for (int off = 1; off < 256; off <<= 1) {
      int add = (tid + off < 256) ? suf[tid + off] : 0;
      __syncthreads();
      suf[tid] += add;
      __syncthreads();
    }
    {
      int above = suf[tid] - hist[tid];
      if (above < rank && rank <= suf[tid]) {
        scal[0] = tid;
        scal[1] = rank - above;
      }
    }
    __syncthreads();
    prefix |= ((unsigned)scal[0]) << shift;
    prefmask |= 0xFFu << shift;
    rank = scal[1];
    __syncthreads();
  }
  const unsigned T = prefix;

#pragma unroll
  for (int i = 0; i < 8; ++i) {
    int j = tid + i * 256;
    unsigned k = keys[j];
    if (k > T) {
      int p = atomicAdd(&cnts[0], 1);
      Mtop[bh * UP + p] = j;
    } else if (k == T) {
      int p = atomicAdd(&cnts[1], 1);
      if (p < 128) ties[p] = j;
    }
  }
  __syncthreads();
  if (tid == 0) {
    int base = cnts[0];
    int need = UP - base;
    int tc = cnts[1] < 128 ? cnts[1] : 128;
    for (int s = 0; s < need; ++s) {
      int best = 1 << 30, bj = 0;
      for (int j = 0; j < tc; ++j) {
        int v = ties[j];
        if (v < best) { best = v; bj = j; }
      }
      Mtop[bh * UP + base + s] = best;
      ties[bj] = 1 << 30;
    }
  }
}

// ---------------------------------------------------------------------------
// mean of V: two-phase coalesced column-sum (V is a [2048][2048] matrix).
// ---------------------------------------------------------------------------
__global__ __launch_bounds__(256) void meanv_part(
    const float* __restrict__ V, float* __restrict__ part) {
  const int rc = blockIdx.x >> 3;      // 0..31
  const int cc = blockIdx.x & 7;       // 0..7
  const int c = cc * 256 + threadIdx.x;
  const float* p = V + (size_t)rc * 64 * 2048 + c;
  float acc = 0.f;
#pragma unroll 8
  for (int i = 0; i < 64; ++i) acc += p[(size_t)i * 2048];
  part[(size_t)rc * 2048 + c] = acc;
}

__global__ __launch_bounds__(256) void meanv_final(
    const float* __restrict__ part, float* __restrict__ mnV) {
  const int c = blockIdx.x * 256 + threadIdx.x;   // 8 blocks
  float acc = 0.f;
#pragma unroll
  for (int r = 0; r < 32; ++r) acc += part[(size_t)r * 2048 + c];
  mnV[c] = acc * (1.0f / (float)KN);
}

// ---------------------------------------------------------------------------
// Selected-row machinery for the sparse output GEMM.
// ---------------------------------------------------------------------------
__global__ void selbuild_kernel(const int* __restrict__ Mtop,
                                int* __restrict__ flags) {
  const int i = blockIdx.x * 64 + threadIdx.x;   // 0..1279
  const int bh = i / UP;
  const int b = bh >> 3;
  flags[b * 2048 + Mtop[i]] = 1;
}

__global__ void selcompact_kernel(const int* __restrict__ flags,
                                  int* __restrict__ rows,
                                  int* __restrict__ cnt) {
  const int i = blockIdx.x * 256 + threadIdx.x;  // 0..8191
  if (flags[i]) {
    int p = atomicAdd(cnt, 1);
    rows[p] = i;                                  // flat row index b*2048+n
  }
}

// meanout[b][o] = dot(mnV[b*512..], Wo[o]) + bo[o]
__global__ __launch_bounds__(256) void meanout_kernel(
    const float* __restrict__ mnV, const float* __restrict__ Wo,
    const float* __restrict__ bo, float* __restrict__ mo) {
  const int b = blockIdx.x;           // 4 blocks
  for (int o = threadIdx.x; o < 512; o += 256) {
    const float* m = mnV + b * 512;
    const float* w = Wo + (size_t)o * 512;
    float acc = 0.f;
#pragma unroll 8
    for (int k = 0; k < 512; ++k) acc = fmaf(m[k], w[k], acc);
    mo[b * 512 + o] = acc + bo[o];
  }
}

// out broadcast fill (float4)
__global__ void fillout_kernel(const float* __restrict__ mo,
                               float* __restrict__ out) {
  size_t i = ((size_t)blockIdx.x * 256 + threadIdx.x) * 4;
  int d = (int)(i & 511);
  int b = (int)(i >> 20);
  float4 v = *(const float4*)(mo + (b << 9) + d);
  *(float4*)(out + i) = v;
}

// ---------------------------------------------------------------------------
// Sparse output GEMM over selected rows only (<=1280 of 8192).
// ---------------------------------------------------------------------------
__global__ __launch_bounds__(256) void gemm_rows(
    const float* __restrict__ ctx, const float* __restrict__ W,
    const float* __restrict__ bias, const int* __restrict__ rows,
    const int* __restrict__ cnt, float* __restrict__ out) {
  __shared__ float As[32][68];
  __shared__ float Ws[32][68];
  __shared__ int rsel[64];
  const int rt = blockIdx.x >> 3;      // 0..19
  const int ot = blockIdx.x & 7;       // 0..7
  const int o0 = ot * 64;
  const int tid = threadIdx.x;
  const int tx = tid & 15;
  const int ty = tid >> 4;
  const int n = *cnt;

  if (rt * 64 >= n) return;

  if (tid < 64) {
    int g = rt * 64 + tid;
    rsel[tid] = (g < n) ? rows[g] : rows[0];
  }
  __syncthreads();

  float acc[4][4] = {};
  for (int k0 = 0; k0 < 512; k0 += 32) {
#pragma unroll
    for (int i = 0; i < 2; ++i) {
      int flat = tid + i * 256;        // 0..511
      int r = flat >> 3;               // 0..63
      int c4 = flat & 7;
      float4 av = *(const float4*)(ctx + (size_t)rsel[r] * 512 + k0 + c4 * 4);
      float4 wv = *(const float4*)(W + (size_t)(o0 + r) * 512 + k0 + c4 * 4);
      As[c4 * 4 + 0][r] = av.x; As[c4 * 4 + 1][r] = av.y;
      As[c4 * 4 + 2][r] = av.z; As[c4 * 4 + 3][r] = av.w;
      Ws[c4 * 4 + 0][r] = wv.x; Ws[c4 * 4 + 1][r] = wv.y;
      Ws[c4 * 4 + 2][r] = wv.z; Ws[c4 * 4 + 3][r] = wv.w;
    }
    __syncthreads();
#pragma unroll
    for (int kk = 0; kk < 32; ++kk) {
      float a_[4], w_[4];
#pragma unroll
      for (int i = 0; i < 4; ++i) a_[i] = As[kk][ty * 4 + i];
#pragma unroll
      for (int j = 0; j < 4; ++j) w_[j] = Ws[kk][tx * 4 + j];
#pragma unroll
      for (int i = 0; i < 4; ++i)
#pragma unroll
        for (int j = 0; j < 4; ++j)
          acc[i][j] = fmaf(a_[i], w_[j], acc[i][j]);
    }
    __syncthreads();
  }

#pragma unroll
  for (int i = 0; i < 4; ++i) {
    int g = rt * 64 + ty * 4 + i;
    if (g < n) {
      int m = rsel[ty * 4 + i];
#pragma unroll
      for (int j = 0; j < 4; ++j) {
        int o = o0 + tx * 4 + j;
        out[(size_t)m * 512 + o] = acc[i][j] + bias[o];
      }
    }
  }
}

// ---------------------------------------------------------------------------
// Flash-split attention (R15, verified): grid 1024, bid%8 == bh%8.
// ---------------------------------------------------------------------------
#define QG 5   // queries per block
#define NC 4   // n-chunks
__global__ __launch_bounds__(256) void attn_part(
    const float* __restrict__ Q, const float* __restrict__ Kt,
    const float* __restrict__ V, const int* __restrict__ Mtop,
    float* __restrict__ pmax, float* __restrict__ psum,
    float* __restrict__ pvp) {
  const int bh = blockIdx.x & 31;
  const int t  = blockIdx.x >> 5;       // 0..31
  const int g  = t & 7;                 // query group
  const int ch = t >> 3;                // n-chunk
  const int b = bh >> 3, h = bh & 7;
  const int tid = threadIdx.x;
  const int wv = tid >> 6, lane = tid & 63;
  const int n0 = ch * 512;

  __shared__ float qs[QG][64];
  __shared__ float p[QG][512];
  __shared__ float redm[QG][4];
  __shared__ float reds[QG][4];
  __shared__ float pvs[4][QG][64];

  for (int i = tid; i < QG * 64; i += 256) {
    int q = i >> 6, e = i & 63;
    int nq = Mtop[bh * UP + g * QG + q];
    qs[q][e] = Q[(((size_t)nq * 4 + b) * 8 + h) * 64 + e];
  }
  __syncthreads();

  const float* ktb = Kt + (size_t)bh * 64 * 2048;
  float d0[QG] = {}, d1[QG] = {};
  const int nb = n0 + tid * 2;
  for (int e = 0; e < 64; ++e) {
    float2 kv = *(const float2*)(ktb + (size_t)e * 2048 + nb);
#pragma unroll
    for (int q = 0; q < QG; ++q) {
      float qe = qs[q][e];
      d0[q] = fmaf(qe, kv.x, d0[q]);
      d1[q] = fmaf(qe, kv.y, d1[q]);
    }
  }

#pragma unroll
  for (int q = 0; q < QG; ++q) {
    float m_ = fmaxf(d0[q], d1[q]);
#pragma unroll
    for (int off = 1; off < 64; off <<= 1)
      m_ = fmaxf(m_, __shfl_xor(m_, off));
    if (lane == 0) redm[q][wv] = m_;
  }
  __syncthreads();
  float gm[QG];
#pragma unroll
  for (int q = 0; q < QG; ++q)
    gm[q] = fmaxf(fmaxf(redm[q][0], redm[q][1]),
                  fmaxf(redm[q][2], redm[q][3]));

  float ls[QG];
#pragma unroll
  for (int q = 0; q < QG; ++q) {
    float e0 = __expf(d0[q] - gm[q]);
    float e1 = __expf(d1[q] - gm[q]);
    p[q][tid * 2] = e0;
    p[q][tid * 2 + 1] = e1;
    ls[q] = e0 + e1;
  }
#pragma unroll
  for (int q = 0; q < QG; ++q) {
    float s_ = ls[q];
#pragma unroll
    for (int off = 1; off < 64; off <<= 1)
      s_ += __shfl_xor(s_, off);
    if (lane == 0) reds[q][wv] = s_;
  }
  __syncthreads();
  float den[QG];
#pragma unroll
  for (int q = 0; q < QG; ++q)
    den[q] = reds[q][0] + reds[q][1] + reds[q][2] + reds[q][3];

  float acc[QG] = {};
  for (int nn = wv * 128; nn < wv * 128 + 128; ++nn) {
    float v = V[(((size_t)(n0 + nn) * 4 + b) * 8 + h) * 64 + lane];
#pragma unroll
    for (int q = 0; q < QG; ++q) acc[q] = fmaf(p[q][nn], v, acc[q]);
  }
#pragma unroll
  for (int q = 0; q < QG; ++q) pvs[wv][q][lane] = acc[q];
  __syncthreads();

  for (int i = tid; i < QG * 64; i += 256) {
    int q = i >> 6, e = i & 63;
    int slot = bh * UP + g * QG + q;
    float pv = pvs[0][q][e] + pvs[1][q][e] + pvs[2][q][e] + pvs[3][q][e];
    pvp[((size_t)slot * NC + ch) * 64 + e] = pv;
    if (e == 0) {
      pmax[slot * NC + ch] = gm[q];
      psum[slot * NC + ch] = den[q];
    }
  }
}

__global__ __launch_bounds__(64) void attn_combine(
    const float* __restrict__ pmax, const float* __restrict__ psum,
    const float* __restrict__ pvp, float* __restrict__ upd) {
  const int slot = blockIdx.x;     // 0..1279
  const int e = threadIdx.x;
  float m = -INFINITY;
#pragma unroll
  for (int ch = 0; ch < NC; ++ch) m = fmaxf(m, pmax[slot * NC + ch]);
  float den = 0.f, num = 0.f;
#pragma unroll
  for (int ch = 0; ch < NC; ++ch) {
    float w = __expf(pmax[slot * NC + ch] - m);
    den = fmaf(w, psum[slot * NC + ch], den);
    num = fmaf(w, pvp[((size_t)slot * NC + ch) * 64 + e], num);
  }
  upd[(size_t)slot * 64 + e] = num / den;
}

// ---------------------------------------------------------------------------
// ctx fill + scatter
// ---------------------------------------------------------------------------
__global__ void fillctx_kernel(const float* __restrict__ meanV,
                               float* __restrict__ ctx) {
  size_t i = ((size_t)blockIdx.x * 256 + threadIdx.x) * 4;
  int d = (int)(i & 511);
  int b = (int)(i >> 20);
  float4 v = *(const float4*)(meanV + (b << 9) + d);
  *(float4*)(ctx + i) = v;
}

__global__ void scatter_kernel(const float* __restrict__ upd,
                               const int* __restrict__ Mtop,
                               float* __restrict__ ctx) {
  const int blk = blockIdx.x;   // bh*40 + s
  const int bh = blk / UP;
  const int b = bh >> 3, h = bh & 7;
  const int n = Mtop[blk];
  ctx[((size_t)(b * 2048 + n)) * 512 + h * 64 + threadIdx.x] =
      upd[(size_t)blk * 64 + threadIdx.x];
}

// ---------------------------------------------------------------------------
// Workspace layout (~102 MiB used; ws >= 113 MiB proven in R4):
//   [0, 256K) Mbuf | [256K,576K) upd | [589824,598016) mnV
//   [598016,603136) Mtop | [634880,897024) vpart | [903168,935936) flags
//   [935936,935940) cnt | [936192,941312) rows | [941312,949504) mo
//   [1M,17M) Q(ctx alias) [17M,33M) K [33M,49M) V
//   [49M,57M) Ahv / [57M,65M) Alv   (dead after GEMM; Kt overwrites)
//   [49M,65M) Kt (written by transposeK after GEMMs)
//   [65M..66.5M) Wh3 | [66.5M..68M) Wl3 (3 x 512KB planes each)
//   [68M..68M+64K) pmax/psum | [..~69.4M) pvp
//   [70M,78M) Ahq | [78M,86M) Alq | [86M,94M) Ahk | [94M,102M) Alk
// ---------------------------------------------------------------------------
extern "C" void kernel_launch(void* const* d_in, const int* in_sizes, int n_in,
                              void* d_out, int out_size, void* d_ws,
                              size_t ws_size, hipStream_t stream) {
  const float* query = (const float*)d_in[0];
  const float* key   = (const float*)d_in[1];
  const float* value = (const float*)d_in[2];
  const int*   idxs  = (const int*)d_in[3];
  const float* Wq = (const float*)d_in[4];
  const float* bq = (const float*)d_in[5];
  const float* Wk = (const float*)d_in[6];
  const float* bk = (const float*)d_in[7];
  const float* Wv = (const float*)d_in[8];
  const float* bv = (const float*)d_in[9];
  const float* Wo = (const float*)d_in[10];
  const float* bo = (const float*)d_in[11];
  float* out = (float*)d_out;    // reference output dtype is float32

  char* ws = (char*)d_ws;
  float*  Mbuf  = (float*)(ws + 0);
  float*  upd   = (float*)(ws + 262144);
  float*  mnV   = (float*)(ws + 589824);
  int*    Mtop  = (int*)  (ws + 598016);
  float*  vpart = (float*)(ws + 634880);
  int*    flags = (int*)  (ws + 903168);
  int*    cnt   = (int*)  (ws + 935936);
  int*    rows  = (int*)  (ws + 936192);
  float*  mo    = (float*)(ws + 941312);
  float*  Q     = (float*)(ws + MiB(1));
  float*  K     = (float*)(ws + MiB(17));
  float*  V     = (float*)(ws + MiB(33));
  float*  Kt    = (float*)(ws + MiB(49));
  ushort* Ahv   = (ushort*)(ws + MiB(49));           // dead before Kt write
  ushort* Alv   = (ushort*)(ws + MiB(57));
  ushort* Wh3   = (ushort*)(ws + MiB(65));           // 3 x 512KB
  ushort* Wl3   = (ushort*)(ws + MiB(65) + 1572864);
  float*  pmax  = (float*)(ws + MiB(68));
  float*  psum  = (float*)(ws + MiB(68) + 32768);
  float*  pvp   = (float*)(ws + MiB(68) + 65536);
  ushort* Ahq   = (ushort*)(ws + MiB(70));
  ushort* Alq   = (ushort*)(ws + MiB(78));
  ushort* Ahk   = (ushort*)(ws + MiB(86));
  ushort* Alk   = (ushort*)(ws + MiB(94));
  float*  ctx   = Q;   // Q dead after attn; ctx written afterwards

  // zero flags + cnt (contiguous region)
  hipMemsetAsync(flags, 0, 32768 + 4, stream);

  wsplit3_kernel<<<1536, 256, 0, stream>>>(Wq, Wk, Wv, Wh3, Wl3);
  asplit3_kernel<<<12288, 256, 0, stream>>>(query, key, value,
                                            Ahq, Alq, Ahk, Alk, Ahv, Alv);
  gemm3_mfma<<<1536, 256, 0, stream>>>(Ahq, Alq, Ahk, Alk, Ahv, Alv,
                                       Wh3, Wl3, bq, bk, bv, Q, K, V);

  transposeK_kernel<<<512, 256, 0, stream>>>(K, Kt);

  mscore_kernel<<<16384, 256, 0, stream>>>(Q, K, idxs, Mbuf);
  topk_kernel<<<NBH, 256, 0, stream>>>(Mbuf, Mtop);
  selbuild_kernel<<<20, 64, 0, stream>>>(Mtop, flags);
  selcompact_kernel<<<32, 256, 0, stream>>>(flags, rows, cnt);

  meanv_part<<<256, 256, 0, stream>>>(V, vpart);
  meanv_final<<<8, 256, 0, stream>>>(vpart, mnV);

  attn_part<<<NBH * 32, 256, 0, stream>>>(Q, Kt, V, Mtop, pmax, psum, pvp);
  attn_combine<<<NBH * UP, 64, 0, stream>>>(pmax, psum, pvp, upd);

  fillctx_kernel<<<4096, 256, 0, stream>>>(mnV, ctx);
  scatter_kernel<<<NBH * UP, 64, 0, stream>>>(upd, Mtop, ctx);

  meanout_kernel<<<4, 256, 0, stream>>>(mnV, Wo, bo, mo);
  fillout_kernel<<<4096, 256, 0, stream>>>(mo, out);
  gemm_rows<<<160, 256, 0, stream>>>(ctx, Wo, bo, rows, cnt, out);
}

// Round 20
// 239.219 us; speedup vs baseline: 1.4193x; 1.3378x over previous
//
#include <hip/hip_runtime.h>
#include <hip/hip_bf16.h>

// Problem constants
#define KN 2048
#define BB 4
#define DM 512
#define NH 8
#define HE 64
#define UP 40
#define NBH 32          // B*H
#define NROWS 8192      // KN*B
#define MiB(x) ((size_t)(x) << 20)

typedef __attribute__((ext_vector_type(8))) short short8;
typedef __attribute__((ext_vector_type(4))) float f32x4;

// bf16 split helpers (RNE)
__device__ __forceinline__ ushort f2bf(float x) {
  unsigned u = __float_as_uint(x);
  unsigned r = (u + 0x7FFFu + ((u >> 16) & 1u)) >> 16;
  return (ushort)r;
}
__device__ __forceinline__ float bf2f(ushort h) {
  return __uint_as_float((unsigned)h << 16);
}

// ---------------------------------------------------------------------------
// Fused split of the 3 weight matrices into hi/lo bf16 planes (stacked).
// ---------------------------------------------------------------------------
__global__ __launch_bounds__(256) void wsplit3_kernel(
    const float* __restrict__ W0, const float* __restrict__ W1,
    const float* __restrict__ W2, ushort* __restrict__ Wh,
    ushort* __restrict__ Wl) {
  const int which = blockIdx.x >> 9;
  const float* W = (which == 0) ? W0 : (which == 1) ? W1 : W2;
  size_t base = (size_t)which * 262144;
  int i = ((blockIdx.x & 511) * 256 + threadIdx.x) * 2;
  float2 v = *(const float2*)(W + i);
  ushort h0 = f2bf(v.x), h1 = f2bf(v.y);
  ushort l0 = f2bf(v.x - bf2f(h0)), l1 = f2bf(v.y - bf2f(h1));
  *(ushort2*)(Wh + base + i) = make_ushort2(h0, h1);
  *(ushort2*)(Wl + base + i) = make_ushort2(l0, l1);
}

// ---------------------------------------------------------------------------
// Fused split of the 3 activation matrices into STACKED hi/lo planes:
// Ah3/Al3 are 24576x512 (q rows 0-8191, k 8192-16383, v 16384-24575).
// ---------------------------------------------------------------------------
__global__ __launch_bounds__(256) void asplit3_kernel(
    const float* __restrict__ A0, const float* __restrict__ A1,
    const float* __restrict__ A2, ushort* __restrict__ Ah3,
    ushort* __restrict__ Al3) {
  const int which = blockIdx.x >> 12;
  const float* A = (which == 0) ? A0 : (which == 1) ? A1 : A2;
  const size_t base = (size_t)which * 8192 * 512;
  size_t i = ((size_t)(blockIdx.x & 4095) * 256 + threadIdx.x) * 4;
  float4 v = *(const float4*)(A + i);
  ushort h0 = f2bf(v.x), h1 = f2bf(v.y), h2 = f2bf(v.z), h3 = f2bf(v.w);
  ushort l0 = f2bf(v.x - bf2f(h0)), l1 = f2bf(v.y - bf2f(h1));
  ushort l2 = f2bf(v.z - bf2f(h2)), l3 = f2bf(v.w - bf2f(h3));
  *(ushort4*)(Ah3 + base + i) = make_ushort4(h0, h1, h2, h3);
  *(ushort4*)(Al3 + base + i) = make_ushort4(l0, l1, l2, l3);
}

// ---------------------------------------------------------------------------
// Fused 3-GEMM, m97-style: 128x128 tile, BK=32, LDS-staged A and W hi/lo
// planes (padded 40-ushort rows: staging writes & ds_read_b128 both 2-way =
// free), 3-term split (AhWh+AhWl+AlWh; AlWl ~2^-18 rel, below proven-safe
// f32 noise band). grid 768 = 3 x 256; which = bid>>8; sub-grid XCD decode
// per R11. 48 MFMA vs 20 ds_read_b128 per k-step per wave - balanced.
// ---------------------------------------------------------------------------
#define APAD 40
__global__ __launch_bounds__(256) void gemm3_mfma(
    const ushort* __restrict__ Ah3, const ushort* __restrict__ Al3,
    const ushort* __restrict__ Wh3, const ushort* __restrict__ Wl3,
    const float* __restrict__ bq, const float* __restrict__ bk,
    const float* __restrict__ bv, float* __restrict__ QKV) {
  __shared__ ushort AsH[128 * APAD];
  __shared__ ushort AsL[128 * APAD];
  __shared__ ushort WsH[128 * APAD];
  __shared__ ushort WsL[128 * APAD];

  const int which = blockIdx.x >> 8;
  const int local = blockIdx.x & 255;
  const int mt = (local & 7) * 8 + ((local >> 3) & 7);  // 0..63
  const int ot = local >> 6;                            // 0..3
  const int m0 = mt * 128, o0 = ot * 128;

  const ushort* Ah = Ah3 + (size_t)which * 8192 * 512;
  const ushort* Al = Al3 + (size_t)which * 8192 * 512;
  const ushort* Wh = Wh3 + (size_t)which * 262144;
  const ushort* Wl = Wl3 + (size_t)which * 262144;
  const float* bias = (which == 0) ? bq : (which == 1) ? bk : bv;
  float* C = QKV + (size_t)which * 8192 * 512;
  const float scale = (which == 0) ? 0.125f : 1.0f;

  const int tid = threadIdx.x;
  const int w = tid >> 6, lane = tid & 63;
  const int fr = lane & 15;      // fragment row
  const int kc = lane >> 4;      // k-chunk (8 bf16)

  f32x4 acc[2][8];
#pragma unroll
  for (int i = 0; i < 2; ++i)
#pragma unroll
    for (int j = 0; j < 8; ++j)
#pragma unroll
      for (int r = 0; r < 4; ++r) acc[i][j][r] = 0.f;

  // staging decode: chunk c in [0,512): row = c>>2, kq = c&3
  const int r0 = tid >> 2, kq0 = (tid & 3) * 8;
  const int r1 = (tid + 256) >> 2, kq1 = ((tid + 256) & 3) * 8;
  const int lo0 = r0 * APAD + kq0, lo1 = r1 * APAD + kq1;

  for (int k0 = 0; k0 < 512; k0 += 32) {
    {
      size_t ga0 = (size_t)(m0 + r0) * 512 + k0 + kq0;
      size_t ga1 = (size_t)(m0 + r1) * 512 + k0 + kq1;
      size_t gw0 = (size_t)(o0 + r0) * 512 + k0 + kq0;
      size_t gw1 = (size_t)(o0 + r1) * 512 + k0 + kq1;
      *(short8*)(AsH + lo0) = *(const short8*)(Ah + ga0);
      *(short8*)(AsL + lo0) = *(const short8*)(Al + ga0);
      *(short8*)(WsH + lo0) = *(const short8*)(Wh + gw0);
      *(short8*)(WsL + lo0) = *(const short8*)(Wl + gw0);
      *(short8*)(AsH + lo1) = *(const short8*)(Ah + ga1);
      *(short8*)(AsL + lo1) = *(const short8*)(Al + ga1);
      *(short8*)(WsH + lo1) = *(const short8*)(Wh + gw1);
      *(short8*)(WsL + lo1) = *(const short8*)(Wl + gw1);
    }
    __syncthreads();

    short8 ah[2], al[2];
#pragma unroll
    for (int i = 0; i < 2; ++i) {
      int off = (w * 32 + i * 16 + fr) * APAD + kc * 8;
      ah[i] = *(const short8*)(AsH + off);
      al[i] = *(const short8*)(AsL + off);
    }
#pragma unroll
    for (int jj = 0; jj < 2; ++jj) {
      short8 bh[4], bl[4];
#pragma unroll
      for (int j = 0; j < 4; ++j) {
        int off = ((jj * 4 + j) * 16 + fr) * APAD + kc * 8;
        bh[j] = *(const short8*)(WsH + off);
        bl[j] = *(const short8*)(WsL + off);
      }
#pragma unroll
      for (int i = 0; i < 2; ++i)
#pragma unroll
        for (int j = 0; j < 4; ++j) {
          acc[i][jj * 4 + j] = __builtin_amdgcn_mfma_f32_16x16x32_bf16(
              ah[i], bh[j], acc[i][jj * 4 + j], 0, 0, 0);
          acc[i][jj * 4 + j] = __builtin_amdgcn_mfma_f32_16x16x32_bf16(
              ah[i], bl[j], acc[i][jj * 4 + j], 0, 0, 0);
          acc[i][jj * 4 + j] = __builtin_amdgcn_mfma_f32_16x16x32_bf16(
              al[i], bh[j], acc[i][jj * 4 + j], 0, 0, 0);
        }
    }
    __syncthreads();
  }

#pragma unroll
  for (int i = 0; i < 2; ++i)
#pragma unroll
    for (int j = 0; j < 8; ++j)
#pragma unroll
      for (int r = 0; r < 4; ++r) {
        int m = m0 + w * 32 + i * 16 + (lane >> 4) * 4 + r;
        int o = o0 + j * 16 + fr;
        C[(size_t)m * 512 + o] = (acc[i][j][r] + bias[o]) * scale;
      }
}

// ---------------------------------------------------------------------------
// Transpose K into Kt[bh][e][n] for coalesced attention score reads.
// ---------------------------------------------------------------------------
__global__ __launch_bounds__(256) void transposeK_kernel(
    const float* __restrict__ K, float* __restrict__ Kt) {
  const int bh = blockIdx.x & 31;
  const int nt = blockIdx.x >> 5;       // 0..15
  const int b = bh >> 3, h = bh & 7;
  const int n0 = nt * 128;
  const int tid = threadIdx.x;
  __shared__ float T[128][65];

#pragma unroll
  for (int i = 0; i < 8; ++i) {
    int flat = tid + i * 256;           // 0..2047
    int r = flat >> 4;                  // 0..127
    int c4 = flat & 15;                 // 0..15
    float4 v = *(const float4*)(K + (((size_t)(n0 + r) * 4 + b) * 8 + h) * 64 + c4 * 4);
    T[r][c4 * 4 + 0] = v.x; T[r][c4 * 4 + 1] = v.y;
    T[r][c4 * 4 + 2] = v.z; T[r][c4 * 4 + 3] = v.w;
  }
  __syncthreads();

  const int nl = tid & 127;             // 0..127
  const int eg = tid >> 7;              // 0..1
#pragma unroll
  for (int e = eg * 32; e < eg * 32 + 32; ++e)
    Kt[((size_t)bh * 64 + e) * 2048 + n0 + nl] = T[nl][e];
}

// ---------------------------------------------------------------------------
// M scores, wave-cooperative gather. One wave per (bh, n).
// ---------------------------------------------------------------------------
__global__ __launch_bounds__(256) void mscore_kernel(
    const float* __restrict__ Q, const float* __restrict__ K,
    const int* __restrict__ idx, float* __restrict__ Mout) {
  const int bh = blockIdx.x & 31;
  const int c  = blockIdx.x >> 5;        // 0..511
  const int wv = threadIdx.x >> 6;       // 0..3
  const int lane = threadIdx.x & 63;
  const int n = c * 4 + wv;
  const int b = bh >> 3, h = bh & 7;
  const int g = lane >> 4;               // sample group 0..3
  const int e16 = lane & 15;             // element chunk within row

  const float4 qv = *(const float4*)(Q + (((size_t)n * 4 + b) * 8 + h) * 64 + e16 * 4);

  float mx = -INFINITY, sm = 0.f;
#pragma unroll
  for (int it = 0; it < 10; ++it) {
    const int s = it * 4 + g;
    const int kn = idx[n * UP + s];
    const float4 kv = *(const float4*)(K + (((size_t)kn * 4 + b) * 8 + h) * 64 + e16 * 4);
    float d = qv.x * kv.x + qv.y * kv.y + qv.z * kv.z + qv.w * kv.w;
    d += __shfl_xor(d, 1);
    d += __shfl_xor(d, 2);
    d += __shfl_xor(d, 4);
    d += __shfl_xor(d, 8);
    mx = fmaxf(mx, d);
    sm += d;
  }
  mx = fmaxf(mx, __shfl_xor(mx, 16));
  mx = fmaxf(mx, __shfl_xor(mx, 32));
  sm += __shfl_xor(sm, 16);
  sm += __shfl_xor(sm, 32);
  if (lane == 0) Mout[(size_t)bh * 2048 + n] = mx - sm * (1.0f / (float)KN);
}

// ---------------------------------------------------------------------------
// top-40 per (b,h) via 4-pass byte radix-select (R14, verified).
// ---------------------------------------------------------------------------
__global__ __launch_bounds__(256) void topk_kernel(
    const float* __restrict__ M, int* __restrict__ Mtop) {
  const int bh = blockIdx.x;
  __shared__ unsigned keys[2048];
  __shared__ int hist[256];
  __shared__ int suf[256];
  __shared__ int scal[2];
  __shared__ int ties[128];
  __shared__ int cnts[2];

  const int tid = threadIdx.x;
  const float* Mrow = M + (size_t)bh * 2048;
#pragma unroll
  for (int i = 0; i < 8; ++i) {
    int j = tid + i * 256;
    unsigned u = __float_as_uint(Mrow[j]);
    keys[j] = (u & 0x80000000u) ? ~u : (u | 0x80000000u);  // monotone map
  }
  if (tid < 2) cnts[tid] = 0;

  unsigned prefix = 0, prefmask = 0;
  int rank = UP;
#pragma unroll
  for (int shift = 24; shift >= 0; shift -= 8) {
    hist[tid] = 0;
    __syncthreads();
#pragma unroll
    for (int i = 0; i < 8; ++i) {
      unsigned k = keys[tid + i * 256];
      if ((k & prefmask) == prefix)
        atomicAdd(&hist[(k >> shift) & 0xFFu], 1);
    }
    __syncthreads();
    suf[tid] = hist[tid];
    __syncthreads();
#pragma unroll
    for (int off = 1; off < 256; off <<= 1) {
      int add = (tid + off < 256) ? suf[tid + off] : 0;
      __syncthreads();
      suf[tid] += add;
      __syncthreads();
    }
    {
      int above = suf[tid] - hist[tid];
      if (above < rank && rank <= suf[tid]) {
        scal[0] = tid;
        scal[1] = rank - above;
      }
    }
    __syncthreads();
    prefix |= ((unsigned)scal[0]) << shift;
    prefmask |= 0xFFu << shift;
    rank = scal[1];
    __syncthreads();
  }
  const unsigned T = prefix;

#pragma unroll
  for (int i = 0; i < 8; ++i) {
    int j = tid + i * 256;
    unsigned k = keys[j];
    if (k > T) {
      int p = atomicAdd(&cnts[0], 1);
      Mtop[bh * UP + p] = j;
    } else if (k == T) {
      int p = atomicAdd(&cnts[1], 1);
      if (p < 128) ties[p] = j;
    }
  }
  __syncthreads();
  if (tid == 0) {
    int base = cnts[0];
    int need = UP - base;
    int tc = cnts[1] < 128 ? cnts[1] : 128;
    for (int s = 0; s < need; ++s) {
      int best = 1 << 30, bj = 0;
      for (int j = 0; j < tc; ++j) {
        int v = ties[j];
        if (v < best) { best = v; bj = j; }
      }
      Mtop[bh * UP + base + s] = best;
      ties[bj] = 1 << 30;
    }
  }
}

// ---------------------------------------------------------------------------
// mean of V: two-phase coalesced column-sum (V is a [2048][2048] matrix).
// ---------------------------------------------------------------------------
__global__ __launch_bounds__(256) void meanv_part(
    const float* __restrict__ V, float* __restrict__ part) {
  const int rc = blockIdx.x >> 3;      // 0..31
  const int cc = blockIdx.x & 7;       // 0..7
  const int c = cc * 256 + threadIdx.x;
  const float* p = V + (size_t)rc * 64 * 2048 + c;
  float acc = 0.f;
#pragma unroll 8
  for (int i = 0; i < 64; ++i) acc += p[(size_t)i * 2048];
  part[(size_t)rc * 2048 + c] = acc;
}

__global__ __launch_bounds__(256) void meanv_final(
    const float* __restrict__ part, float* __restrict__ mnV) {
  const int c = blockIdx.x * 256 + threadIdx.x;   // 8 blocks
  float acc = 0.f;
#pragma unroll
  for (int r = 0; r < 32; ++r) acc += part[(size_t)r * 2048 + c];
  mnV[c] = acc * (1.0f / (float)KN);
}

// ---------------------------------------------------------------------------
// Selected-row machinery for the sparse output GEMM.
// ---------------------------------------------------------------------------
__global__ void selbuild_kernel(const int* __restrict__ Mtop,
                                int* __restrict__ flags) {
  const int i = blockIdx.x * 64 + threadIdx.x;   // 0..1279
  const int bh = i / UP;
  const int b = bh >> 3;
  flags[b * 2048 + Mtop[i]] = 1;
}

__global__ void selcompact_kernel(const int* __restrict__ flags,
                                  int* __restrict__ rows,
                                  int* __restrict__ cnt) {
  const int i = blockIdx.x * 256 + threadIdx.x;  // 0..8191
  if (flags[i]) {
    int p = atomicAdd(cnt, 1);
    rows[p] = i;                                  // flat row index b*2048+n
  }
}

// meanout[b][o] = dot(mnV[b*512..], Wo[o]) + bo[o]
__global__ __launch_bounds__(256) void meanout_kernel(
    const float* __restrict__ mnV, const float* __restrict__ Wo,
    const float* __restrict__ bo, float* __restrict__ mo) {
  const int b = blockIdx.x;           // 4 blocks
  for (int o = threadIdx.x; o < 512; o += 256) {
    const float* m = mnV + b * 512;
    const float* w = Wo + (size_t)o * 512;
    float acc = 0.f;
#pragma unroll 8
    for (int k = 0; k < 512; ++k) acc = fmaf(m[k], w[k], acc);
    mo[b * 512 + o] = acc + bo[o];
  }
}

// out broadcast fill (float4)
__global__ void fillout_kernel(const float* __restrict__ mo,
                               float* __restrict__ out) {
  size_t i = ((size_t)blockIdx.x * 256 + threadIdx.x) * 4;
  int d = (int)(i & 511);
  int b = (int)(i >> 20);
  float4 v = *(const float4*)(mo + (b << 9) + d);
  *(float4*)(out + i) = v;
}

// ---------------------------------------------------------------------------
// Sparse output GEMM over selected rows only (<=1280 of 8192).
// ---------------------------------------------------------------------------
__global__ __launch_bounds__(256) void gemm_rows(
    const float* __restrict__ ctx, const float* __restrict__ W,
    const float* __restrict__ bias, const int* __restrict__ rows,
    const int* __restrict__ cnt, float* __restrict__ out) {
  __shared__ float As[32][68];
  __shared__ float Ws[32][68];
  __shared__ int rsel[64];
  const int rt = blockIdx.x >> 3;      // 0..19
  const int ot = blockIdx.x & 7;       // 0..7
  const int o0 = ot * 64;
  const int tid = threadIdx.x;
  const int tx = tid & 15;
  const int ty = tid >> 4;
  const int n = *cnt;

  if (rt * 64 >= n) return;

  if (tid < 64) {
    int g = rt * 64 + tid;
    rsel[tid] = (g < n) ? rows[g] : rows[0];
  }
  __syncthreads();

  float acc[4][4] = {};
  for (int k0 = 0; k0 < 512; k0 += 32) {
#pragma unroll
    for (int i = 0; i < 2; ++i) {
      int flat = tid + i * 256;        // 0..511
      int r = flat >> 3;               // 0..63
      int c4 = flat & 7;
      float4 av = *(const float4*)(ctx + (size_t)rsel[r] * 512 + k0 + c4 * 4);
      float4 wv = *(const float4*)(W + (size_t)(o0 + r) * 512 + k0 + c4 * 4);
      As[c4 * 4 + 0][r] = av.x; As[c4 * 4 + 1][r] = av.y;
      As[c4 * 4 + 2][r] = av.z; As[c4 * 4 + 3][r] = av.w;
      Ws[c4 * 4 + 0][r] = wv.x; Ws[c4 * 4 + 1][r] = wv.y;
      Ws[c4 * 4 + 2][r] = wv.z; Ws[c4 * 4 + 3][r] = wv.w;
    }
    __syncthreads();
#pragma unroll
    for (int kk = 0; kk < 32; ++kk) {
      float a_[4], w_[4];
#pragma unroll
      for (int i = 0; i < 4; ++i) a_[i] = As[kk][ty * 4 + i];
#pragma unroll
      for (int j = 0; j < 4; ++j) w_[j] = Ws[kk][tx * 4 + j];
#pragma unroll
      for (int i = 0; i < 4; ++i)
#pragma unroll
        for (int j = 0; j < 4; ++j)
          acc[i][j] = fmaf(a_[i], w_[j], acc[i][j]);
    }
    __syncthreads();
  }

#pragma unroll
  for (int i = 0; i < 4; ++i) {
    int g = rt * 64 + ty * 4 + i;
    if (g < n) {
      int m = rsel[ty * 4 + i];
#pragma unroll
      for (int j = 0; j < 4; ++j) {
        int o = o0 + tx * 4 + j;
        out[(size_t)m * 512 + o] = acc[i][j] + bias[o];
      }
    }
  }
}

// ---------------------------------------------------------------------------
// Flash-split attention (R15, verified): grid 1024, bid%8 == bh%8.
// ---------------------------------------------------------------------------
#define QG 5   // queries per block
#define NC 4   // n-chunks
__global__ __launch_bounds__(256) void attn_part(
    const float* __restrict__ Q, const float* __restrict__ Kt,
    const float* __restrict__ V, const int* __restrict__ Mtop,
    float* __restrict__ pmax, float* __restrict__ psum,
    float* __restrict__ pvp) {
  const int bh = blockIdx.x & 31;
  const int t  = blockIdx.x >> 5;       // 0..31
  const int g  = t & 7;                 // query group
  const int ch = t >> 3;                // n-chunk
  const int b = bh >> 3, h = bh & 7;
  const int tid = threadIdx.x;
  const int wv = tid >> 6, lane = tid & 63;
  const int n0 = ch * 512;

  __shared__ float qs[QG][64];
  __shared__ float p[QG][512];
  __shared__ float redm[QG][4];
  __shared__ float reds[QG][4];
  __shared__ float pvs[4][QG][64];

  for (int i = tid; i < QG * 64; i += 256) {
    int q = i >> 6, e = i & 63;
    int nq = Mtop[bh * UP + g * QG + q];
    qs[q][e] = Q[(((size_t)nq * 4 + b) * 8 + h) * 64 + e];
  }
  __syncthreads();

  const float* ktb = Kt + (size_t)bh * 64 * 2048;
  float d0[QG] = {}, d1[QG] = {};
  const int nb = n0 + tid * 2;
  for (int e = 0; e < 64; ++e) {
    float2 kv = *(const float2*)(ktb + (size_t)e * 2048 + nb);
#pragma unroll
    for (int q = 0; q < QG; ++q) {
      float qe = qs[q][e];
      d0[q] = fmaf(qe, kv.x, d0[q]);
      d1[q] = fmaf(qe, kv.y, d1[q]);
    }
  }

#pragma unroll
  for (int q = 0; q < QG; ++q) {
    float m_ = fmaxf(d0[q], d1[q]);
#pragma unroll
    for (int off = 1; off < 64; off <<= 1)
      m_ = fmaxf(m_, __shfl_xor(m_, off));
    if (lane == 0) redm[q][wv] = m_;
  }
  __syncthreads();
  float gm[QG];
#pragma unroll
  for (int q = 0; q < QG; ++q)
    gm[q] = fmaxf(fmaxf(redm[q][0], redm[q][1]),
                  fmaxf(redm[q][2], redm[q][3]));

  float ls[QG];
#pragma unroll
  for (int q = 0; q < QG; ++q) {
    float e0 = __expf(d0[q] - gm[q]);
    float e1 = __expf(d1[q] - gm[q]);
    p[q][tid * 2] = e0;
    p[q][tid * 2 + 1] = e1;
    ls[q] = e0 + e1;
  }
#pragma unroll
  for (int q = 0; q < QG; ++q) {
    float s_ = ls[q];
#pragma unroll
    for (int off = 1; off < 64; off <<= 1)
      s_ += __shfl_xor(s_, off);
    if (lane == 0) reds[q][wv] = s_;
  }
  __syncthreads();
  float den[QG];
#pragma unroll
  for (int q = 0; q < QG; ++q)
    den[q] = reds[q][0] + reds[q][1] + reds[q][2] + reds[q][3];

  float acc[QG] = {};
  for (int nn = wv * 128; nn < wv * 128 + 128; ++nn) {
    float v = V[(((size_t)(n0 + nn) * 4 + b) * 8 + h) * 64 + lane];
#pragma unroll
    for (int q = 0; q < QG; ++q) acc[q] = fmaf(p[q][nn], v, acc[q]);
  }
#pragma unroll
  for (int q = 0; q < QG; ++q) pvs[wv][q][lane] = acc[q];
  __syncthreads();

  for (int i = tid; i < QG * 64; i += 256) {
    int q = i >> 6, e = i & 63;
    int slot = bh * UP + g * QG + q;
    float pv = pvs[0][q][e] + pvs[1][q][e] + pvs[2][q][e] + pvs[3][q][e];
    pvp[((size_t)slot * NC + ch) * 64 + e] = pv;
    if (e == 0) {
      pmax[slot * NC + ch] = gm[q];
      psum[slot * NC + ch] = den[q];
    }
  }
}

__global__ __launch_bounds__(64) void attn_combine(
    const float* __restrict__ pmax, const float* __restrict__ psum,
    const float* __restrict__ pvp, float* __restrict__ upd) {
  const int slot = blockIdx.x;     // 0..1279
  const int e = threadIdx.x;
  float m = -INFINITY;
#pragma unroll
  for (int ch = 0; ch < NC; ++ch) m = fmaxf(m, pmax[slot * NC + ch]);
  float den = 0.f, num = 0.f;
#pragma unroll
  for (int ch = 0; ch < NC; ++ch) {
    float w = __expf(pmax[slot * NC + ch] - m);
    den = fmaf(w, psum[slot * NC + ch], den);
    num = fmaf(w, pvp[((size_t)slot * NC + ch) * 64 + e], num);
  }
  upd[(size_t)slot * 64 + e] = num / den;
}

// ---------------------------------------------------------------------------
// ctx fill + scatter
// ---------------------------------------------------------------------------
__global__ void fillctx_kernel(const float* __restrict__ meanV,
                               float* __restrict__ ctx) {
  size_t i = ((size_t)blockIdx.x * 256 + threadIdx.x) * 4;
  int d = (int)(i & 511);
  int b = (int)(i >> 20);
  float4 v = *(const float4*)(meanV + (b << 9) + d);
  *(float4*)(ctx + i) = v;
}

__global__ void scatter_kernel(const float* __restrict__ upd,
                               const int* __restrict__ Mtop,
                               float* __restrict__ ctx) {
  const int blk = blockIdx.x;   // bh*40 + s
  const int bh = blk / UP;
  const int b = bh >> 3, h = bh & 7;
  const int n = Mtop[blk];
  ctx[((size_t)(b * 2048 + n)) * 512 + h * 64 + threadIdx.x] =
      upd[(size_t)blk * 64 + threadIdx.x];
}

// ---------------------------------------------------------------------------
// Workspace layout (~100 MiB used; ws >= 113 MiB proven in R4):
//   [0, 256K) Mbuf | [256K,576K) upd | [589824,598016) mnV
//   [598016,603136) Mtop | [634880,897024) vpart | [903168,935936) flags
//   [935936,935940) cnt | [936192,941312) rows | [941312,949504) mo
//   [1M,49M) QKV stacked (Q 1-17M = ctx alias, K 17-33M, V 33-49M)
//   [49M,73M) Ah3 / [73M,97M) Al3  (24576x512 stacked; dead after gemm3)
//   [49M,65M) Kt (written AFTER gemm3 over dead Ah3)
//   [68M..68M+64K) pmax/psum | [..~69.4M) pvp  (written after gemm3)
//   [97M,98.5M) Wh3 | [98.5M,100M) Wl3
// ---------------------------------------------------------------------------
extern "C" void kernel_launch(void* const* d_in, const int* in_sizes, int n_in,
                              void* d_out, int out_size, void* d_ws,
                              size_t ws_size, hipStream_t stream) {
  const float* query = (const float*)d_in[0];
  const float* key   = (const float*)d_in[1];
  const float* value = (const float*)d_in[2];
  const int*   idxs  = (const int*)d_in[3];
  const float* Wq = (const float*)d_in[4];
  const float* bq = (const float*)d_in[5];
  const float* Wk = (const float*)d_in[6];
  const float* bk = (const float*)d_in[7];
  const float* Wv = (const float*)d_in[8];
  const float* bv = (const float*)d_in[9];
  const float* Wo = (const float*)d_in[10];
  const float* bo = (const float*)d_in[11];
  float* out = (float*)d_out;    // reference output dtype is float32

  char* ws = (char*)d_ws;
  float*  Mbuf  = (float*)(ws + 0);
  float*  upd   = (float*)(ws + 262144);
  float*  mnV   = (float*)(ws + 589824);
  int*    Mtop  = (int*)  (ws + 598016);
  float*  vpart = (float*)(ws + 634880);
  int*    flags = (int*)  (ws + 903168);
  int*    cnt   = (int*)  (ws + 935936);
  int*    rows  = (int*)  (ws + 936192);
  float*  mo    = (float*)(ws + 941312);
  float*  QKV   = (float*)(ws + MiB(1));   // Q | K | V stacked
  float*  Q     = QKV;
  float*  K     = (float*)(ws + MiB(17));
  float*  V     = (float*)(ws + MiB(33));
  float*  Kt    = (float*)(ws + MiB(49));            // after gemm3
  ushort* Ah3   = (ushort*)(ws + MiB(49));           // dead after gemm3
  ushort* Al3   = (ushort*)(ws + MiB(73));
  float*  pmax  = (float*)(ws + MiB(68));            // after gemm3
  float*  psum  = (float*)(ws + MiB(68) + 32768);
  float*  pvp   = (float*)(ws + MiB(68) + 65536);
  ushort* Wh3   = (ushort*)(ws + MiB(97));
  ushort* Wl3   = (ushort*)(ws + MiB(97) + 1572864);
  float*  ctx   = Q;   // Q dead after attn; ctx written afterwards

  // zero flags + cnt (contiguous region)
  hipMemsetAsync(flags, 0, 32768 + 4, stream);

  wsplit3_kernel<<<1536, 256, 0, stream>>>(Wq, Wk, Wv, Wh3, Wl3);
  asplit3_kernel<<<12288, 256, 0, stream>>>(query, key, value, Ah3, Al3);
  gemm3_mfma<<<768, 256, 0, stream>>>(Ah3, Al3, Wh3, Wl3, bq, bk, bv, QKV);

  transposeK_kernel<<<512, 256, 0, stream>>>(K, Kt);

  mscore_kernel<<<16384, 256, 0, stream>>>(Q, K, idxs, Mbuf);
  topk_kernel<<<NBH, 256, 0, stream>>>(Mbuf, Mtop);
  selbuild_kernel<<<20, 64, 0, stream>>>(Mtop, flags);
  selcompact_kernel<<<32, 256, 0, stream>>>(flags, rows, cnt);

  meanv_part<<<256, 256, 0, stream>>>(V, vpart);
  meanv_final<<<8, 256, 0, stream>>>(vpart, mnV);

  attn_part<<<NBH * 32, 256, 0, stream>>>(Q, Kt, V, Mtop, pmax, psum, pvp);
  attn_combine<<<NBH * UP, 64, 0, stream>>>(pmax, psum, pvp, upd);

  fillctx_kernel<<<4096, 256, 0, stream>>>(mnV, ctx);
  scatter_kernel<<<NBH * UP, 64, 0, stream>>>(upd, Mtop, ctx);

  meanout_kernel<<<4, 256, 0, stream>>>(mnV, Wo, bo, mo);
  fillout_kernel<<<4096, 256, 0, stream>>>(mo, out);
  gemm_rows<<<160, 256, 0, stream>>>(ctx, Wo, bo, rows, cnt, out);
}

// Round 21
// 234.987 us; speedup vs baseline: 1.4449x; 1.0180x over previous
//
#include <hip/hip_runtime.h>
#include <hip/hip_bf16.h>

// Problem constants
#define KN 2048
#define BB 4
#define DM 512
#define NH 8
#define HE 64
#define UP 40
#define NBH 32          // B*H
#define NROWS 8192      // KN*B
#define MiB(x) ((size_t)(x) << 20)

typedef __attribute__((ext_vector_type(8))) short short8;
typedef __attribute__((ext_vector_type(4))) float f32x4;

// bf16 split helpers (RNE)
__device__ __forceinline__ ushort f2bf(float x) {
  unsigned u = __float_as_uint(x);
  unsigned r = (u + 0x7FFFu + ((u >> 16) & 1u)) >> 16;
  return (ushort)r;
}
__device__ __forceinline__ float bf2f(ushort h) {
  return __uint_as_float((unsigned)h << 16);
}

// ---------------------------------------------------------------------------
// Fused split of the 3 weight matrices into hi/lo bf16 planes (stacked).
// ---------------------------------------------------------------------------
__global__ __launch_bounds__(256) void wsplit3_kernel(
    const float* __restrict__ W0, const float* __restrict__ W1,
    const float* __restrict__ W2, ushort* __restrict__ Wh,
    ushort* __restrict__ Wl) {
  const int which = blockIdx.x >> 9;
  const float* W = (which == 0) ? W0 : (which == 1) ? W1 : W2;
  size_t base = (size_t)which * 262144;
  int i = ((blockIdx.x & 511) * 256 + threadIdx.x) * 2;
  float2 v = *(const float2*)(W + i);
  ushort h0 = f2bf(v.x), h1 = f2bf(v.y);
  ushort l0 = f2bf(v.x - bf2f(h0)), l1 = f2bf(v.y - bf2f(h1));
  *(ushort2*)(Wh + base + i) = make_ushort2(h0, h1);
  *(ushort2*)(Wl + base + i) = make_ushort2(l0, l1);
}

// ---------------------------------------------------------------------------
// Fused split of the 3 activation matrices into STACKED hi/lo planes:
// Ah3/Al3 are 24576x512 (q rows 0-8191, k 8192-16383, v 16384-24575).
// ---------------------------------------------------------------------------
__global__ __launch_bounds__(256) void asplit3_kernel(
    const float* __restrict__ A0, const float* __restrict__ A1,
    const float* __restrict__ A2, ushort* __restrict__ Ah3,
    ushort* __restrict__ Al3) {
  const int which = blockIdx.x >> 12;
  const float* A = (which == 0) ? A0 : (which == 1) ? A1 : A2;
  const size_t base = (size_t)which * 8192 * 512;
  size_t i = ((size_t)(blockIdx.x & 4095) * 256 + threadIdx.x) * 4;
  float4 v = *(const float4*)(A + i);
  ushort h0 = f2bf(v.x), h1 = f2bf(v.y), h2 = f2bf(v.z), h3 = f2bf(v.w);
  ushort l0 = f2bf(v.x - bf2f(h0)), l1 = f2bf(v.y - bf2f(h1));
  ushort l2 = f2bf(v.z - bf2f(h2)), l3 = f2bf(v.w - bf2f(h3));
  *(ushort4*)(Ah3 + base + i) = make_ushort4(h0, h1, h2, h3);
  *(ushort4*)(Al3 + base + i) = make_ushort4(l0, l1, l2, l3);
}

// ---------------------------------------------------------------------------
// Fused 3-GEMM, m97-style LDS staging, SQUARE 64x64 wave tiles (4x4 frags):
// per wave per k-step 16 ds_read_b128 (was 20) for the same 48 MFMAs ->
// LDS traffic -20%, A-frag reuse 4x. 3-term split (AhWh+AhWl+AlWh).
// grid 768 = 3 x 256; which = bid>>8; sub-grid XCD decode per R11.
// Waves arranged 2x2 over the 128x128 tile.
// ---------------------------------------------------------------------------
#define APAD 40
__global__ __launch_bounds__(256) void gemm3_mfma(
    const ushort* __restrict__ Ah3, const ushort* __restrict__ Al3,
    const ushort* __restrict__ Wh3, const ushort* __restrict__ Wl3,
    const float* __restrict__ bq, const float* __restrict__ bk,
    const float* __restrict__ bv, float* __restrict__ QKV) {
  __shared__ ushort AsH[128 * APAD];
  __shared__ ushort AsL[128 * APAD];
  __shared__ ushort WsH[128 * APAD];
  __shared__ ushort WsL[128 * APAD];

  const int which = blockIdx.x >> 8;
  const int local = blockIdx.x & 255;
  const int mt = (local & 7) * 8 + ((local >> 3) & 7);  // 0..63
  const int ot = local >> 6;                            // 0..3
  const int m0 = mt * 128, o0 = ot * 128;

  const ushort* Ah = Ah3 + (size_t)which * 8192 * 512;
  const ushort* Al = Al3 + (size_t)which * 8192 * 512;
  const ushort* Wh = Wh3 + (size_t)which * 262144;
  const ushort* Wl = Wl3 + (size_t)which * 262144;
  const float* bias = (which == 0) ? bq : (which == 1) ? bk : bv;
  float* C = QKV + (size_t)which * 8192 * 512;
  const float scale = (which == 0) ? 0.125f : 1.0f;

  const int tid = threadIdx.x;
  const int w = tid >> 6, lane = tid & 63;
  const int wr = w >> 1, wc = w & 1;   // 2x2 wave grid
  const int fr = lane & 15;            // fragment row
  const int kc = lane >> 4;            // k-chunk (8 bf16)

  f32x4 acc[4][4];
#pragma unroll
  for (int i = 0; i < 4; ++i)
#pragma unroll
    for (int j = 0; j < 4; ++j)
#pragma unroll
      for (int r = 0; r < 4; ++r) acc[i][j][r] = 0.f;

  // staging decode: chunk c in [0,512): row = c>>2, kq = c&3
  const int r0 = tid >> 2, kq0 = (tid & 3) * 8;
  const int r1 = (tid + 256) >> 2, kq1 = ((tid + 256) & 3) * 8;
  const int lo0 = r0 * APAD + kq0, lo1 = r1 * APAD + kq1;

  for (int k0 = 0; k0 < 512; k0 += 32) {
    {
      size_t ga0 = (size_t)(m0 + r0) * 512 + k0 + kq0;
      size_t ga1 = (size_t)(m0 + r1) * 512 + k0 + kq1;
      size_t gw0 = (size_t)(o0 + r0) * 512 + k0 + kq0;
      size_t gw1 = (size_t)(o0 + r1) * 512 + k0 + kq1;
      *(short8*)(AsH + lo0) = *(const short8*)(Ah + ga0);
      *(short8*)(AsL + lo0) = *(const short8*)(Al + ga0);
      *(short8*)(WsH + lo0) = *(const short8*)(Wh + gw0);
      *(short8*)(WsL + lo0) = *(const short8*)(Wl + gw0);
      *(short8*)(AsH + lo1) = *(const short8*)(Ah + ga1);
      *(short8*)(AsL + lo1) = *(const short8*)(Al + ga1);
      *(short8*)(WsH + lo1) = *(const short8*)(Wh + gw1);
      *(short8*)(WsL + lo1) = *(const short8*)(Wl + gw1);
    }
    __syncthreads();

    short8 ah[4], al[4], bh[4], bl[4];
#pragma unroll
    for (int i = 0; i < 4; ++i) {
      int off = (wr * 64 + i * 16 + fr) * APAD + kc * 8;
      ah[i] = *(const short8*)(AsH + off);
      al[i] = *(const short8*)(AsL + off);
    }
#pragma unroll
    for (int j = 0; j < 4; ++j) {
      int off = (wc * 64 + j * 16 + fr) * APAD + kc * 8;
      bh[j] = *(const short8*)(WsH + off);
      bl[j] = *(const short8*)(WsL + off);
    }
#pragma unroll
    for (int i = 0; i < 4; ++i)
#pragma unroll
      for (int j = 0; j < 4; ++j) {
        acc[i][j] = __builtin_amdgcn_mfma_f32_16x16x32_bf16(
            ah[i], bh[j], acc[i][j], 0, 0, 0);
        acc[i][j] = __builtin_amdgcn_mfma_f32_16x16x32_bf16(
            ah[i], bl[j], acc[i][j], 0, 0, 0);
        acc[i][j] = __builtin_amdgcn_mfma_f32_16x16x32_bf16(
            al[i], bh[j], acc[i][j], 0, 0, 0);
      }
    __syncthreads();
  }

#pragma unroll
  for (int i = 0; i < 4; ++i)
#pragma unroll
    for (int j = 0; j < 4; ++j)
#pragma unroll
      for (int r = 0; r < 4; ++r) {
        int m = m0 + wr * 64 + i * 16 + (lane >> 4) * 4 + r;
        int o = o0 + wc * 64 + j * 16 + fr;
        C[(size_t)m * 512 + o] = (acc[i][j][r] + bias[o]) * scale;
      }
}

// ---------------------------------------------------------------------------
// Transpose K into Kt[bh][e][n] for coalesced attention score reads.
// ---------------------------------------------------------------------------
__global__ __launch_bounds__(256) void transposeK_kernel(
    const float* __restrict__ K, float* __restrict__ Kt) {
  const int bh = blockIdx.x & 31;
  const int nt = blockIdx.x >> 5;       // 0..15
  const int b = bh >> 3, h = bh & 7;
  const int n0 = nt * 128;
  const int tid = threadIdx.x;
  __shared__ float T[128][65];

#pragma unroll
  for (int i = 0; i < 8; ++i) {
    int flat = tid + i * 256;           // 0..2047
    int r = flat >> 4;                  // 0..127
    int c4 = flat & 15;                 // 0..15
    float4 v = *(const float4*)(K + (((size_t)(n0 + r) * 4 + b) * 8 + h) * 64 + c4 * 4);
    T[r][c4 * 4 + 0] = v.x; T[r][c4 * 4 + 1] = v.y;
    T[r][c4 * 4 + 2] = v.z; T[r][c4 * 4 + 3] = v.w;
  }
  __syncthreads();

  const int nl = tid & 127;             // 0..127
  const int eg = tid >> 7;              // 0..1
#pragma unroll
  for (int e = eg * 32; e < eg * 32 + 32; ++e)
    Kt[((size_t)bh * 64 + e) * 2048 + n0 + nl] = T[nl][e];
}

// ---------------------------------------------------------------------------
// M scores, wave-cooperative gather. One wave per (bh, n).
// ---------------------------------------------------------------------------
__global__ __launch_bounds__(256) void mscore_kernel(
    const float* __restrict__ Q, const float* __restrict__ K,
    const int* __restrict__ idx, float* __restrict__ Mout) {
  const int bh = blockIdx.x & 31;
  const int c  = blockIdx.x >> 5;        // 0..511
  const int wv = threadIdx.x >> 6;       // 0..3
  const int lane = threadIdx.x & 63;
  const int n = c * 4 + wv;
  const int b = bh >> 3, h = bh & 7;
  const int g = lane >> 4;               // sample group 0..3
  const int e16 = lane & 15;             // element chunk within row

  const float4 qv = *(const float4*)(Q + (((size_t)n * 4 + b) * 8 + h) * 64 + e16 * 4);

  float mx = -INFINITY, sm = 0.f;
#pragma unroll
  for (int it = 0; it < 10; ++it) {
    const int s = it * 4 + g;
    const int kn = idx[n * UP + s];
    const float4 kv = *(const float4*)(K + (((size_t)kn * 4 + b) * 8 + h) * 64 + e16 * 4);
    float d = qv.x * kv.x + qv.y * kv.y + qv.z * kv.z + qv.w * kv.w;
    d += __shfl_xor(d, 1);
    d += __shfl_xor(d, 2);
    d += __shfl_xor(d, 4);
    d += __shfl_xor(d, 8);
    mx = fmaxf(mx, d);
    sm += d;
  }
  mx = fmaxf(mx, __shfl_xor(mx, 16));
  mx = fmaxf(mx, __shfl_xor(mx, 32));
  sm += __shfl_xor(sm, 16);
  sm += __shfl_xor(sm, 32);
  if (lane == 0) Mout[(size_t)bh * 2048 + n] = mx - sm * (1.0f / (float)KN);
}

// ---------------------------------------------------------------------------
// top-40 per (b,h) via 4-pass byte radix-select (R14, verified).
// ---------------------------------------------------------------------------
__global__ __launch_bounds__(256) void topk_kernel(
    const float* __restrict__ M, int* __restrict__ Mtop) {
  const int bh = blockIdx.x;
  __shared__ unsigned keys[2048];
  __shared__ int hist[256];
  __shared__ int suf[256];
  __shared__ int scal[2];
  __shared__ int ties[128];
  __shared__ int cnts[2];

  const int tid = threadIdx.x;
  const float* Mrow = M + (size_t)bh * 2048;
#pragma unroll
  for (int i = 0; i < 8; ++i) {
    int j = tid + i * 256;
    unsigned u = __float_as_uint(Mrow[j]);
    keys[j] = (u & 0x80000000u) ? ~u : (u | 0x80000000u);  // monotone map
  }
  if (tid < 2) cnts[tid] = 0;

  unsigned prefix = 0, prefmask = 0;
  int rank = UP;
#pragma unroll
  for (int shift = 24; shift >= 0; shift -= 8) {
    hist[tid] = 0;
    __syncthreads();
#pragma unroll
    for (int i = 0; i < 8; ++i) {
      unsigned k = keys[tid + i * 256];
      if ((k & prefmask) == prefix)
        atomicAdd(&hist[(k >> shift) & 0xFFu], 1);
    }
    __syncthreads();
    suf[tid] = hist[tid];
    __syncthreads();
#pragma unroll
    for (int off = 1; off < 256; off <<= 1) {
      int add = (tid + off < 256) ? suf[tid + off] : 0;
      __syncthreads();
      suf[tid] += add;
      __syncthreads();
    }
    {
      int above = suf[tid] - hist[tid];
      if (above < rank && rank <= suf[tid]) {
        scal[0] = tid;
        scal[1] = rank - above;
      }
    }
    __syncthreads();
    prefix |= ((unsigned)scal[0]) << shift;
    prefmask |= 0xFFu << shift;
    rank = scal[1];
    __syncthreads();
  }
  const unsigned T = prefix;

#pragma unroll
  for (int i = 0; i < 8; ++i) {
    int j = tid + i * 256;
    unsigned k = keys[j];
    if (k > T) {
      int p = atomicAdd(&cnts[0], 1);
      Mtop[bh * UP + p] = j;
    } else if (k == T) {
      int p = atomicAdd(&cnts[1], 1);
      if (p < 128) ties[p] = j;
    }
  }
  __syncthreads();
  if (tid == 0) {
    int base = cnts[0];
    int need = UP - base;
    int tc = cnts[1] < 128 ? cnts[1] : 128;
    for (int s = 0; s < need; ++s) {
      int best = 1 << 30, bj = 0;
      for (int j = 0; j < tc; ++j) {
        int v = ties[j];
        if (v < best) { best = v; bj = j; }
      }
      Mtop[bh * UP + base + s] = best;
      ties[bj] = 1 << 30;
    }
  }
}

// ---------------------------------------------------------------------------
// mean of V: two-phase coalesced column-sum (V is a [2048][2048] matrix).
// ---------------------------------------------------------------------------
__global__ __launch_bounds__(256) void meanv_part(
    const float* __restrict__ V, float* __restrict__ part) {
  const int rc = blockIdx.x >> 3;      // 0..31
  const int cc = blockIdx.x & 7;       // 0..7
  const int c = cc * 256 + threadIdx.x;
  const float* p = V + (size_t)rc * 64 * 2048 + c;
  float acc = 0.f;
#pragma unroll 8
  for (int i = 0; i < 64; ++i) acc += p[(size_t)i * 2048];
  part[(size_t)rc * 2048 + c] = acc;
}

__global__ __launch_bounds__(256) void meanv_final(
    const float* __restrict__ part, float* __restrict__ mnV) {
  const int c = blockIdx.x * 256 + threadIdx.x;   // 8 blocks
  float acc = 0.f;
#pragma unroll
  for (int r = 0; r < 32; ++r) acc += part[(size_t)r * 2048 + c];
  mnV[c] = acc * (1.0f / (float)KN);
}

// ---------------------------------------------------------------------------
// Selected-row machinery for the sparse output GEMM.
// ---------------------------------------------------------------------------
__global__ void selbuild_kernel(const int* __restrict__ Mtop,
                                int* __restrict__ flags) {
  const int i = blockIdx.x * 64 + threadIdx.x;   // 0..1279
  const int bh = i / UP;
  const int b = bh >> 3;
  flags[b * 2048 + Mtop[i]] = 1;
}

__global__ void selcompact_kernel(const int* __restrict__ flags,
                                  int* __restrict__ rows,
                                  int* __restrict__ cnt) {
  const int i = blockIdx.x * 256 + threadIdx.x;  // 0..8191
  if (flags[i]) {
    int p = atomicAdd(cnt, 1);
    rows[p] = i;                                  // flat row index b*2048+n
  }
}

// meanout[b][o] = dot(mnV[b*512..], Wo[o]) + bo[o]
__global__ __launch_bounds__(256) void meanout_kernel(
    const float* __restrict__ mnV, const float* __restrict__ Wo,
    const float* __restrict__ bo, float* __restrict__ mo) {
  const int b = blockIdx.x;           // 4 blocks
  for (int o = threadIdx.x; o < 512; o += 256) {
    const float* m = mnV + b * 512;
    const float* w = Wo + (size_t)o * 512;
    float acc = 0.f;
#pragma unroll 8
    for (int k = 0; k < 512; ++k) acc = fmaf(m[k], w[k], acc);
    mo[b * 512 + o] = acc + bo[o];
  }
}

// out broadcast fill (float4)
__global__ void fillout_kernel(const float* __restrict__ mo,
                               float* __restrict__ out) {
  size_t i = ((size_t)blockIdx.x * 256 + threadIdx.x) * 4;
  int d = (int)(i & 511);
  int b = (int)(i >> 20);
  float4 v = *(const float4*)(mo + (b << 9) + d);
  *(float4*)(out + i) = v;
}

// ---------------------------------------------------------------------------
// Seed ONLY the selected ctx rows with the per-batch mean row (the rest of
// ctx is never read: gemm_rows touches selected rows only, and non-selected
// output rows come from fillout's mean broadcast).
// ---------------------------------------------------------------------------
__global__ __launch_bounds__(128) void fillsel_kernel(
    const float* __restrict__ mnV, const int* __restrict__ rows,
    const int* __restrict__ cnt, float* __restrict__ ctx) {
  const int bid = blockIdx.x;          // 0..1279
  if (bid >= *cnt) return;
  const int row = rows[bid];           // b*2048 + n
  const int b = row >> 11;
  float4 v = *(const float4*)(mnV + b * 512 + threadIdx.x * 4);
  *(float4*)(ctx + (size_t)row * 512 + threadIdx.x * 4) = v;
}

// ---------------------------------------------------------------------------
// Sparse output GEMM over selected rows only (<=1280 of 8192).
// ---------------------------------------------------------------------------
__global__ __launch_bounds__(256) void gemm_rows(
    const float* __restrict__ ctx, const float* __restrict__ W,
    const float* __restrict__ bias, const int* __restrict__ rows,
    const int* __restrict__ cnt, float* __restrict__ out) {
  __shared__ float As[32][68];
  __shared__ float Ws[32][68];
  __shared__ int rsel[64];
  const int rt = blockIdx.x >> 3;      // 0..19
  const int ot = blockIdx.x & 7;       // 0..7
  const int o0 = ot * 64;
  const int tid = threadIdx.x;
  const int tx = tid & 15;
  const int ty = tid >> 4;
  const int n = *cnt;

  if (rt * 64 >= n) return;

  if (tid < 64) {
    int g = rt * 64 + tid;
    rsel[tid] = (g < n) ? rows[g] : rows[0];
  }
  __syncthreads();

  float acc[4][4] = {};
  for (int k0 = 0; k0 < 512; k0 += 32) {
#pragma unroll
    for (int i = 0; i < 2; ++i) {
      int flat = tid + i * 256;        // 0..511
      int r = flat >> 3;               // 0..63
      int c4 = flat & 7;
      float4 av = *(const float4*)(ctx + (size_t)rsel[r] * 512 + k0 + c4 * 4);
      float4 wv = *(const float4*)(W + (size_t)(o0 + r) * 512 + k0 + c4 * 4);
      As[c4 * 4 + 0][r] = av.x; As[c4 * 4 + 1][r] = av.y;
      As[c4 * 4 + 2][r] = av.z; As[c4 * 4 + 3][r] = av.w;
      Ws[c4 * 4 + 0][r] = wv.x; Ws[c4 * 4 + 1][r] = wv.y;
      Ws[c4 * 4 + 2][r] = wv.z; Ws[c4 * 4 + 3][r] = wv.w;
    }
    __syncthreads();
#pragma unroll
    for (int kk = 0; kk < 32; ++kk) {
      float a_[4], w_[4];
#pragma unroll
      for (int i = 0; i < 4; ++i) a_[i] = As[kk][ty * 4 + i];
#pragma unroll
      for (int j = 0; j < 4; ++j) w_[j] = Ws[kk][tx * 4 + j];
#pragma unroll
      for (int i = 0; i < 4; ++i)
#pragma unroll
        for (int j = 0; j < 4; ++j)
          acc[i][j] = fmaf(a_[i], w_[j], acc[i][j]);
    }
    __syncthreads();
  }

#pragma unroll
  for (int i = 0; i < 4; ++i) {
    int g = rt * 64 + ty * 4 + i;
    if (g < n) {
      int m = rsel[ty * 4 + i];
#pragma unroll
      for (int j = 0; j < 4; ++j) {
        int o = o0 + tx * 4 + j;
        out[(size_t)m * 512 + o] = acc[i][j] + bias[o];
      }
    }
  }
}

// ---------------------------------------------------------------------------
// Flash-split attention (R15, verified): grid 1024, bid%8 == bh%8.
// ---------------------------------------------------------------------------
#define QG 5   // queries per block
#define NC 4   // n-chunks
__global__ __launch_bounds__(256) void attn_part(
    const float* __restrict__ Q, const float* __restrict__ Kt,
    const float* __restrict__ V, const int* __restrict__ Mtop,
    float* __restrict__ pmax, float* __restrict__ psum,
    float* __restrict__ pvp) {
  const int bh = blockIdx.x & 31;
  const int t  = blockIdx.x >> 5;       // 0..31
  const int g  = t & 7;                 // query group
  const int ch = t >> 3;                // n-chunk
  const int b = bh >> 3, h = bh & 7;
  const int tid = threadIdx.x;
  const int wv = tid >> 6, lane = tid & 63;
  const int n0 = ch * 512;

  __shared__ float qs[QG][64];
  __shared__ float p[QG][512];
  __shared__ float redm[QG][4];
  __shared__ float reds[QG][4];
  __shared__ float pvs[4][QG][64];

  for (int i = tid; i < QG * 64; i += 256) {
    int q = i >> 6, e = i & 63;
    int nq = Mtop[bh * UP + g * QG + q];
    qs[q][e] = Q[(((size_t)nq * 4 + b) * 8 + h) * 64 + e];
  }
  __syncthreads();

  const float* ktb = Kt + (size_t)bh * 64 * 2048;
  float d0[QG] = {}, d1[QG] = {};
  const int nb = n0 + tid * 2;
  for (int e = 0; e < 64; ++e) {
    float2 kv = *(const float2*)(ktb + (size_t)e * 2048 + nb);
#pragma unroll
    for (int q = 0; q < QG; ++q) {
      float qe = qs[q][e];
      d0[q] = fmaf(qe, kv.x, d0[q]);
      d1[q] = fmaf(qe, kv.y, d1[q]);
    }
  }

#pragma unroll
  for (int q = 0; q < QG; ++q) {
    float m_ = fmaxf(d0[q], d1[q]);
#pragma unroll
    for (int off = 1; off < 64; off <<= 1)
      m_ = fmaxf(m_, __shfl_xor(m_, off));
    if (lane == 0) redm[q][wv] = m_;
  }
  __syncthreads();
  float gm[QG];
#pragma unroll
  for (int q = 0; q < QG; ++q)
    gm[q] = fmaxf(fmaxf(redm[q][0], redm[q][1]),
                  fmaxf(redm[q][2], redm[q][3]));

  float ls[QG];
#pragma unroll
  for (int q = 0; q < QG; ++q) {
    float e0 = __expf(d0[q] - gm[q]);
    float e1 = __expf(d1[q] - gm[q]);
    p[q][tid * 2] = e0;
    p[q][tid * 2 + 1] = e1;
    ls[q] = e0 + e1;
  }
#pragma unroll
  for (int q = 0; q < QG; ++q) {
    float s_ = ls[q];
#pragma unroll
    for (int off = 1; off < 64; off <<= 1)
      s_ += __shfl_xor(s_, off);
    if (lane == 0) reds[q][wv] = s_;
  }
  __syncthreads();
  float den[QG];
#pragma unroll
  for (int q = 0; q < QG; ++q)
    den[q] = reds[q][0] + reds[q][1] + reds[q][2] + reds[q][3];

  float acc[QG] = {};
  for (int nn = wv * 128; nn < wv * 128 + 128; ++nn) {
    float v = V[(((size_t)(n0 + nn) * 4 + b) * 8 + h) * 64 + lane];
#pragma unroll
    for (int q = 0; q < QG; ++q) acc[q] = fmaf(p[q][nn], v, acc[q]);
  }
#pragma unroll
  for (int q = 0; q < QG; ++q) pvs[wv][q][lane] = acc[q];
  __syncthreads();

  for (int i = tid; i < QG * 64; i += 256) {
    int q = i >> 6, e = i & 63;
    int slot = bh * UP + g * QG + q;
    float pv = pvs[0][q][e] + pvs[1][q][e] + pvs[2][q][e] + pvs[3][q][e];
    pvp[((size_t)slot * NC + ch) * 64 + e] = pv;
    if (e == 0) {
      pmax[slot * NC + ch] = gm[q];
      psum[slot * NC + ch] = den[q];
    }
  }
}

__global__ __launch_bounds__(64) void attn_combine(
    const float* __restrict__ pmax, const float* __restrict__ psum,
    const float* __restrict__ pvp, float* __restrict__ upd) {
  const int slot = blockIdx.x;     // 0..1279
  const int e = threadIdx.x;
  float m = -INFINITY;
#pragma unroll
  for (int ch = 0; ch < NC; ++ch) m = fmaxf(m, pmax[slot * NC + ch]);
  float den = 0.f, num = 0.f;
#pragma unroll
  for (int ch = 0; ch < NC; ++ch) {
    float w = __expf(pmax[slot * NC + ch] - m);
    den = fmaf(w, psum[slot * NC + ch], den);
    num = fmaf(w, pvp[((size_t)slot * NC + ch) * 64 + e], num);
  }
  upd[(size_t)slot * 64 + e] = num / den;
}

// ---------------------------------------------------------------------------
// scatter selected rows
// ---------------------------------------------------------------------------
__global__ void scatter_kernel(const float* __restrict__ upd,
                               const int* __restrict__ Mtop,
                               float* __restrict__ ctx) {
  const int blk = blockIdx.x;   // bh*40 + s
  const int bh = blk / UP;
  const int b = bh >> 3, h = bh & 7;
  const int n = Mtop[blk];
  ctx[((size_t)(b * 2048 + n)) * 512 + h * 64 + threadIdx.x] =
      upd[(size_t)blk * 64 + threadIdx.x];
}

// ---------------------------------------------------------------------------
// Workspace layout (~100 MiB used; ws >= 113 MiB proven in R4):
//   [0, 256K) Mbuf | [256K,576K) upd | [589824,598016) mnV
//   [598016,603136) Mtop | [634880,897024) vpart | [903168,935936) flags
//   [935936,935940) cnt | [936192,941312) rows | [941312,949504) mo
//   [1M,49M) QKV stacked (Q 1-17M = ctx alias, K 17-33M, V 33-49M)
//   [49M,73M) Ah3 / [73M,97M) Al3  (24576x512 stacked; dead after gemm3)
//   [49M,65M) Kt (written AFTER gemm3 over dead Ah3)
//   [68M..68M+64K) pmax/psum | [..~69.4M) pvp  (written after gemm3)
//   [97M,98.5M) Wh3 | [98.5M,100M) Wl3
// ---------------------------------------------------------------------------
extern "C" void kernel_launch(void* const* d_in, const int* in_sizes, int n_in,
                              void* d_out, int out_size, void* d_ws,
                              size_t ws_size, hipStream_t stream) {
  const float* query = (const float*)d_in[0];
  const float* key   = (const float*)d_in[1];
  const float* value = (const float*)d_in[2];
  const int*   idxs  = (const int*)d_in[3];
  const float* Wq = (const float*)d_in[4];
  const float* bq = (const float*)d_in[5];
  const float* Wk = (const float*)d_in[6];
  const float* bk = (const float*)d_in[7];
  const float* Wv = (const float*)d_in[8];
  const float* bv = (const float*)d_in[9];
  const float* Wo = (const float*)d_in[10];
  const float* bo = (const float*)d_in[11];
  float* out = (float*)d_out;    // reference output dtype is float32

  char* ws = (char*)d_ws;
  float*  Mbuf  = (float*)(ws + 0);
  float*  upd   = (float*)(ws + 262144);
  float*  mnV   = (float*)(ws + 589824);
  int*    Mtop  = (int*)  (ws + 598016);
  float*  vpart = (float*)(ws + 634880);
  int*    flags = (int*)  (ws + 903168);
  int*    cnt   = (int*)  (ws + 935936);
  int*    rows  = (int*)  (ws + 936192);
  float*  mo    = (float*)(ws + 941312);
  float*  QKV   = (float*)(ws + MiB(1));   // Q | K | V stacked
  float*  Q     = QKV;
  float*  K     = (float*)(ws + MiB(17));
  float*  V     = (float*)(ws + MiB(33));
  float*  Kt    = (float*)(ws + MiB(49));            // after gemm3
  ushort* Ah3   = (ushort*)(ws + MiB(49));           // dead after gemm3
  ushort* Al3   = (ushort*)(ws + MiB(73));
  float*  pmax  = (float*)(ws + MiB(68));            // after gemm3
  float*  psum  = (float*)(ws + MiB(68) + 32768);
  float*  pvp   = (float*)(ws + MiB(68) + 65536);
  ushort* Wh3   = (ushort*)(ws + MiB(97));
  ushort* Wl3   = (ushort*)(ws + MiB(97) + 1572864);
  float*  ctx   = Q;   // Q dead after attn; ctx written afterwards

  // zero flags + cnt (contiguous region)
  hipMemsetAsync(flags, 0, 32768 + 4, stream);

  wsplit3_kernel<<<1536, 256, 0, stream>>>(Wq, Wk, Wv, Wh3, Wl3);
  asplit3_kernel<<<12288, 256, 0, stream>>>(query, key, value, Ah3, Al3);
  gemm3_mfma<<<768, 256, 0, stream>>>(Ah3, Al3, Wh3, Wl3, bq, bk, bv, QKV);

  transposeK_kernel<<<512, 256, 0, stream>>>(K, Kt);

  mscore_kernel<<<16384, 256, 0, stream>>>(Q, K, idxs, Mbuf);
  topk_kernel<<<NBH, 256, 0, stream>>>(Mbuf, Mtop);
  selbuild_kernel<<<20, 64, 0, stream>>>(Mtop, flags);
  selcompact_kernel<<<32, 256, 0, stream>>>(flags, rows, cnt);

  meanv_part<<<256, 256, 0, stream>>>(V, vpart);
  meanv_final<<<8, 256, 0, stream>>>(vpart, mnV);

  attn_part<<<NBH * 32, 256, 0, stream>>>(Q, Kt, V, Mtop, pmax, psum, pvp);
  attn_combine<<<NBH * UP, 64, 0, stream>>>(pmax, psum, pvp, upd);

  fillsel_kernel<<<NBH * UP, 128, 0, stream>>>(mnV, rows, cnt, ctx);
  scatter_kernel<<<NBH * UP, 64, 0, stream>>>(upd, Mtop, ctx);

  meanout_kernel<<<4, 256, 0, stream>>>(mnV, Wo, bo, mo);
  fillout_kernel<<<4096, 256, 0, stream>>>(mo, out);
  gemm_rows<<<160, 256, 0, stream>>>(ctx, Wo, bo, rows, cnt, out);
}

// Round 22
// 200.594 us; speedup vs baseline: 1.6926x; 1.1715x over previous
//
#include <hip/hip_runtime.h>
#include <hip/hip_bf16.h>

// Problem constants
#define KN 2048
#define BB 4
#define DM 512
#define NH 8
#define HE 64
#define UP 40
#define NBH 32          // B*H
#define NROWS 8192      // KN*B
#define MiB(x) ((size_t)(x) << 20)

typedef __attribute__((ext_vector_type(8))) short short8;
typedef __attribute__((ext_vector_type(4))) float f32x4;

// bf16 split helpers (RNE)
__device__ __forceinline__ ushort f2bf(float x) {
  unsigned u = __float_as_uint(x);
  unsigned r = (u + 0x7FFFu + ((u >> 16) & 1u)) >> 16;
  return (ushort)r;
}
__device__ __forceinline__ float bf2f(ushort h) {
  return __uint_as_float((unsigned)h << 16);
}

// ---------------------------------------------------------------------------
// Fused split of the 3 weight matrices into hi/lo bf16 planes (stacked).
// ---------------------------------------------------------------------------
__global__ __launch_bounds__(256) void wsplit3_kernel(
    const float* __restrict__ W0, const float* __restrict__ W1,
    const float* __restrict__ W2, ushort* __restrict__ Wh,
    ushort* __restrict__ Wl) {
  const int which = blockIdx.x >> 9;
  const float* W = (which == 0) ? W0 : (which == 1) ? W1 : W2;
  size_t base = (size_t)which * 262144;
  int i = ((blockIdx.x & 511) * 256 + threadIdx.x) * 2;
  float2 v = *(const float2*)(W + i);
  ushort h0 = f2bf(v.x), h1 = f2bf(v.y);
  ushort l0 = f2bf(v.x - bf2f(h0)), l1 = f2bf(v.y - bf2f(h1));
  *(ushort2*)(Wh + base + i) = make_ushort2(h0, h1);
  *(ushort2*)(Wl + base + i) = make_ushort2(l0, l1);
}

// ---------------------------------------------------------------------------
// Fused 3-GEMM, m97-style LDS staging, 64x64 wave tiles (4x4 frags),
// 3-term split (AhWh+AhWl+AlWh). A is read as f32 and split in-register
// during staging (RNE, bitwise-identical to the old asplit3) -> kills the
// 96 MB plane round-trip. W planes preconverted (L2-resident).
// grid 768 = 3 x 256; which = bid>>8; sub-grid XCD decode per R11; the 4
// ot-blocks of one mt share local%64 -> same XCD -> A f32 L2-reused.
// ---------------------------------------------------------------------------
#define APAD 40
__global__ __launch_bounds__(256) void gemm3_mfma(
    const float* __restrict__ A0, const float* __restrict__ A1,
    const float* __restrict__ A2,
    const ushort* __restrict__ Wh3, const ushort* __restrict__ Wl3,
    const float* __restrict__ bq, const float* __restrict__ bk,
    const float* __restrict__ bv, float* __restrict__ QKV) {
  __shared__ ushort AsH[128 * APAD];
  __shared__ ushort AsL[128 * APAD];
  __shared__ ushort WsH[128 * APAD];
  __shared__ ushort WsL[128 * APAD];

  const int which = blockIdx.x >> 8;
  const int local = blockIdx.x & 255;
  const int mt = (local & 7) * 8 + ((local >> 3) & 7);  // 0..63
  const int ot = local >> 6;                            // 0..3
  const int m0 = mt * 128, o0 = ot * 128;

  const float* A = (which == 0) ? A0 : (which == 1) ? A1 : A2;
  const ushort* Wh = Wh3 + (size_t)which * 262144;
  const ushort* Wl = Wl3 + (size_t)which * 262144;
  const float* bias = (which == 0) ? bq : (which == 1) ? bk : bv;
  float* C = QKV + (size_t)which * 8192 * 512;
  const float scale = (which == 0) ? 0.125f : 1.0f;

  const int tid = threadIdx.x;
  const int w = tid >> 6, lane = tid & 63;
  const int wr = w >> 1, wc = w & 1;   // 2x2 wave grid
  const int fr = lane & 15;            // fragment row
  const int kc = lane >> 4;            // k-chunk (8 bf16)

  f32x4 acc[4][4];
#pragma unroll
  for (int i = 0; i < 4; ++i)
#pragma unroll
    for (int j = 0; j < 4; ++j)
#pragma unroll
      for (int r = 0; r < 4; ++r) acc[i][j][r] = 0.f;

  // W staging decode: chunk c in [0,512): row = c>>2, kq = (c&3)*8
  const int r0 = tid >> 2, kq0 = (tid & 3) * 8;
  const int r1 = (tid + 256) >> 2, kq1 = ((tid + 256) & 3) * 8;
  const int lo0 = r0 * APAD + kq0, lo1 = r1 * APAD + kq1;

  for (int k0 = 0; k0 < 512; k0 += 32) {
    // stage A: 128 rows x 32 floats = 1024 float4; 4 chunks/thread,
    // converted to bf16 hi/lo in-register (RNE split).
#pragma unroll
    for (int i = 0; i < 4; ++i) {
      int c = tid + i * 256;           // 0..1023
      int row = c >> 3, q = c & 7;
      float4 v = *(const float4*)(A + (size_t)(m0 + row) * 512 + k0 + q * 4);
      ushort h0 = f2bf(v.x), h1 = f2bf(v.y), h2 = f2bf(v.z), h3 = f2bf(v.w);
      ushort l0 = f2bf(v.x - bf2f(h0)), l1 = f2bf(v.y - bf2f(h1));
      ushort l2 = f2bf(v.z - bf2f(h2)), l3 = f2bf(v.w - bf2f(h3));
      *(ushort4*)(AsH + row * APAD + q * 4) = make_ushort4(h0, h1, h2, h3);
      *(ushort4*)(AsL + row * APAD + q * 4) = make_ushort4(l0, l1, l2, l3);
    }
    // stage W hi/lo planes (2 short8 chunks/thread each)
    {
      size_t gw0 = (size_t)(o0 + r0) * 512 + k0 + kq0;
      size_t gw1 = (size_t)(o0 + r1) * 512 + k0 + kq1;
      *(short8*)(WsH + lo0) = *(const short8*)(Wh + gw0);
      *(short8*)(WsL + lo0) = *(const short8*)(Wl + gw0);
      *(short8*)(WsH + lo1) = *(const short8*)(Wh + gw1);
      *(short8*)(WsL + lo1) = *(const short8*)(Wl + gw1);
    }
    __syncthreads();

    short8 ah[4], al[4], bh[4], bl[4];
#pragma unroll
    for (int i = 0; i < 4; ++i) {
      int off = (wr * 64 + i * 16 + fr) * APAD + kc * 8;
      ah[i] = *(const short8*)(AsH + off);
      al[i] = *(const short8*)(AsL + off);
    }
#pragma unroll
    for (int j = 0; j < 4; ++j) {
      int off = (wc * 64 + j * 16 + fr) * APAD + kc * 8;
      bh[j] = *(const short8*)(WsH + off);
      bl[j] = *(const short8*)(WsL + off);
    }
#pragma unroll
    for (int i = 0; i < 4; ++i)
#pragma unroll
      for (int j = 0; j < 4; ++j) {
        acc[i][j] = __builtin_amdgcn_mfma_f32_16x16x32_bf16(
            ah[i], bh[j], acc[i][j], 0, 0, 0);
        acc[i][j] = __builtin_amdgcn_mfma_f32_16x16x32_bf16(
            ah[i], bl[j], acc[i][j], 0, 0, 0);
        acc[i][j] = __builtin_amdgcn_mfma_f32_16x16x32_bf16(
            al[i], bh[j], acc[i][j], 0, 0, 0);
      }
    __syncthreads();
  }

#pragma unroll
  for (int i = 0; i < 4; ++i)
#pragma unroll
    for (int j = 0; j < 4; ++j)
#pragma unroll
      for (int r = 0; r < 4; ++r) {
        int m = m0 + wr * 64 + i * 16 + (lane >> 4) * 4 + r;
        int o = o0 + wc * 64 + j * 16 + fr;
        C[(size_t)m * 512 + o] = (acc[i][j][r] + bias[o]) * scale;
      }
}

// ---------------------------------------------------------------------------
// Transpose K into Kt[bh][e][n] for coalesced attention score reads.
// ---------------------------------------------------------------------------
__global__ __launch_bounds__(256) void transposeK_kernel(
    const float* __restrict__ K, float* __restrict__ Kt) {
  const int bh = blockIdx.x & 31;
  const int nt = blockIdx.x >> 5;       // 0..15
  const int b = bh >> 3, h = bh & 7;
  const int n0 = nt * 128;
  const int tid = threadIdx.x;
  __shared__ float T[128][65];

#pragma unroll
  for (int i = 0; i < 8; ++i) {
    int flat = tid + i * 256;           // 0..2047
    int r = flat >> 4;                  // 0..127
    int c4 = flat & 15;                 // 0..15
    float4 v = *(const float4*)(K + (((size_t)(n0 + r) * 4 + b) * 8 + h) * 64 + c4 * 4);
    T[r][c4 * 4 + 0] = v.x; T[r][c4 * 4 + 1] = v.y;
    T[r][c4 * 4 + 2] = v.z; T[r][c4 * 4 + 3] = v.w;
  }
  __syncthreads();

  const int nl = tid & 127;             // 0..127
  const int eg = tid >> 7;              // 0..1
#pragma unroll
  for (int e = eg * 32; e < eg * 32 + 32; ++e)
    Kt[((size_t)bh * 64 + e) * 2048 + n0 + nl] = T[nl][e];
}

// ---------------------------------------------------------------------------
// M scores, wave-cooperative gather. One wave per (bh, n).
// ---------------------------------------------------------------------------
__global__ __launch_bounds__(256) void mscore_kernel(
    const float* __restrict__ Q, const float* __restrict__ K,
    const int* __restrict__ idx, float* __restrict__ Mout) {
  const int bh = blockIdx.x & 31;
  const int c  = blockIdx.x >> 5;        // 0..511
  const int wv = threadIdx.x >> 6;       // 0..3
  const int lane = threadIdx.x & 63;
  const int n = c * 4 + wv;
  const int b = bh >> 3, h = bh & 7;
  const int g = lane >> 4;               // sample group 0..3
  const int e16 = lane & 15;             // element chunk within row

  const float4 qv = *(const float4*)(Q + (((size_t)n * 4 + b) * 8 + h) * 64 + e16 * 4);

  float mx = -INFINITY, sm = 0.f;
#pragma unroll
  for (int it = 0; it < 10; ++it) {
    const int s = it * 4 + g;
    const int kn = idx[n * UP + s];
    const float4 kv = *(const float4*)(K + (((size_t)kn * 4 + b) * 8 + h) * 64 + e16 * 4);
    float d = qv.x * kv.x + qv.y * kv.y + qv.z * kv.z + qv.w * kv.w;
    d += __shfl_xor(d, 1);
    d += __shfl_xor(d, 2);
    d += __shfl_xor(d, 4);
    d += __shfl_xor(d, 8);
    mx = fmaxf(mx, d);
    sm += d;
  }
  mx = fmaxf(mx, __shfl_xor(mx, 16));
  mx = fmaxf(mx, __shfl_xor(mx, 32));
  sm += __shfl_xor(sm, 16);
  sm += __shfl_xor(sm, 32);
  if (lane == 0) Mout[(size_t)bh * 2048 + n] = mx - sm * (1.0f / (float)KN);
}

// ---------------------------------------------------------------------------
// top-40 per (b,h) via 4-pass byte radix-select (R14, verified).
// Also sets flags[b*2048+n] for each selected n (replaces selbuild).
// ---------------------------------------------------------------------------
__global__ __launch_bounds__(256) void topk_kernel(
    const float* __restrict__ M, int* __restrict__ Mtop,
    int* __restrict__ flags) {
  const int bh = blockIdx.x;
  __shared__ unsigned keys[2048];
  __shared__ int hist[256];
  __shared__ int suf[256];
  __shared__ int scal[2];
  __shared__ int ties[128];
  __shared__ int cnts[2];

  const int tid = threadIdx.x;
  const int fbase = (bh >> 3) * 2048;
  const float* Mrow = M + (size_t)bh * 2048;
#pragma unroll
  for (int i = 0; i < 8; ++i) {
    int j = tid + i * 256;
    unsigned u = __float_as_uint(Mrow[j]);
    keys[j] = (u & 0x80000000u) ? ~u : (u | 0x80000000u);  // monotone map
  }
  if (tid < 2) cnts[tid] = 0;

  unsigned prefix = 0, prefmask = 0;
  int rank = UP;
#pragma unroll
  for (int shift = 24; shift >= 0; shift -= 8) {
    hist[tid] = 0;
    __syncthreads();
#pragma unroll
    for (int i = 0; i < 8; ++i) {
      unsigned k = keys[tid + i * 256];
      if ((k & prefmask) == prefix)
        atomicAdd(&hist[(k >> shift) & 0xFFu], 1);
    }
    __syncthreads();
    suf[tid] = hist[tid];
    __syncthreads();
#pragma unroll
    for (int off = 1; off < 256; off <<= 1) {
      int add = (tid + off < 256) ? suf[tid + off] : 0;
      __syncthreads();
      suf[tid] += add;
      __syncthreads();
    }
    {
      int above = suf[tid] - hist[tid];
      if (above < rank && rank <= suf[tid]) {
        scal[0] = tid;
        scal[1] = rank - above;
      }
    }
    __syncthreads();
    prefix |= ((unsigned)scal[0]) << shift;
    prefmask |= 0xFFu << shift;
    rank = scal[1];
    __syncthreads();
  }
  const unsigned T = prefix;

#pragma unroll
  for (int i = 0; i < 8; ++i) {
    int j = tid + i * 256;
    unsigned k = keys[j];
    if (k > T) {
      int p = atomicAdd(&cnts[0], 1);
      Mtop[bh * UP + p] = j;
      flags[fbase + j] = 1;
    } else if (k == T) {
      int p = atomicAdd(&cnts[1], 1);
      if (p < 128) ties[p] = j;
    }
  }
  __syncthreads();
  if (tid == 0) {
    int base = cnts[0];
    int need = UP - base;
    int tc = cnts[1] < 128 ? cnts[1] : 128;
    for (int s = 0; s < need; ++s) {
      int best = 1 << 30, bj = 0;
      for (int j = 0; j < tc; ++j) {
        int v = ties[j];
        if (v < best) { best = v; bj = j; }
      }
      Mtop[bh * UP + base + s] = best;
      flags[fbase + best] = 1;
      ties[bj] = 1 << 30;
    }
  }
}

// ---------------------------------------------------------------------------
// mean of V: two-phase coalesced column-sum (V is a [2048][2048] matrix).
// ---------------------------------------------------------------------------
__global__ __launch_bounds__(256) void meanv_part(
    const float* __restrict__ V, float* __restrict__ part) {
  const int rc = blockIdx.x >> 3;      // 0..31
  const int cc = blockIdx.x & 7;       // 0..7
  const int c = cc * 256 + threadIdx.x;
  const float* p = V + (size_t)rc * 64 * 2048 + c;
  float acc = 0.f;
#pragma unroll 8
  for (int i = 0; i < 64; ++i) acc += p[(size_t)i * 2048];
  part[(size_t)rc * 2048 + c] = acc;
}

__global__ __launch_bounds__(256) void meanv_final(
    const float* __restrict__ part, float* __restrict__ mnV) {
  const int c = blockIdx.x * 256 + threadIdx.x;   // 8 blocks
  float acc = 0.f;
#pragma unroll
  for (int r = 0; r < 32; ++r) acc += part[(size_t)r * 2048 + c];
  mnV[c] = acc * (1.0f / (float)KN);
}

// ---------------------------------------------------------------------------
// Compact selected rows (flags -> rows list + count).
// ---------------------------------------------------------------------------
__global__ void selcompact_kernel(const int* __restrict__ flags,
                                  int* __restrict__ rows,
                                  int* __restrict__ cnt) {
  const int i = blockIdx.x * 256 + threadIdx.x;  // 0..8191
  if (flags[i]) {
    int p = atomicAdd(cnt, 1);
    rows[p] = i;                                  // flat row index b*2048+n
  }
}

// ---------------------------------------------------------------------------
// meanout[b][o] = dot(mnV[b*512..], Wo[o]) + bo[o]; 32 blocks, k-split x4
// with fixed-order reduce (deterministic).
// ---------------------------------------------------------------------------
__global__ __launch_bounds__(256) void meanout_kernel(
    const float* __restrict__ mnV, const float* __restrict__ Wo,
    const float* __restrict__ bo, float* __restrict__ mo) {
  const int b = blockIdx.x >> 3;          // 0..3
  const int oc = blockIdx.x & 7;          // 0..7
  const int ol = threadIdx.x & 63;        // o within chunk
  const int kp = threadIdx.x >> 6;        // k-part 0..3
  const int o = oc * 64 + ol;
  __shared__ float red[4][64];

  const float* m = mnV + b * 512;
  const float* w = Wo + (size_t)o * 512;
  float acc = 0.f;
#pragma unroll 8
  for (int k = kp * 128; k < kp * 128 + 128; ++k)
    acc = fmaf(m[k], w[k], acc);
  red[kp][ol] = acc;
  __syncthreads();
  if (threadIdx.x < 64) {
    float s = red[0][ol] + red[1][ol] + red[2][ol] + red[3][ol];
    mo[b * 512 + o] = s + bo[o];
  }
}

// out broadcast fill (float4)
__global__ void fillout_kernel(const float* __restrict__ mo,
                               float* __restrict__ out) {
  size_t i = ((size_t)blockIdx.x * 256 + threadIdx.x) * 4;
  int d = (int)(i & 511);
  int b = (int)(i >> 20);
  float4 v = *(const float4*)(mo + (b << 9) + d);
  *(float4*)(out + i) = v;
}

// ---------------------------------------------------------------------------
// Seed ONLY the selected ctx rows with the per-batch mean row.
// ---------------------------------------------------------------------------
__global__ __launch_bounds__(128) void fillsel_kernel(
    const float* __restrict__ mnV, const int* __restrict__ rows,
    const int* __restrict__ cnt, float* __restrict__ ctx) {
  const int bid = blockIdx.x;          // 0..1279
  if (bid >= *cnt) return;
  const int row = rows[bid];           // b*2048 + n
  const int b = row >> 11;
  float4 v = *(const float4*)(mnV + b * 512 + threadIdx.x * 4);
  *(float4*)(ctx + (size_t)row * 512 + threadIdx.x * 4) = v;
}

// ---------------------------------------------------------------------------
// Sparse output GEMM over selected rows only: 32-row x 64-col tiles,
// grid 320 (40 rt x 8 ot) for better CU utilization.
// ---------------------------------------------------------------------------
__global__ __launch_bounds__(256) void gemm_rows(
    const float* __restrict__ ctx, const float* __restrict__ W,
    const float* __restrict__ bias, const int* __restrict__ rows,
    const int* __restrict__ cnt, float* __restrict__ out) {
  __shared__ float As[32][36];   // [k][row]
  __shared__ float Ws[32][68];   // [k][col]
  __shared__ int rsel[32];
  const int rt = blockIdx.x >> 3;      // 0..39
  const int ot = blockIdx.x & 7;       // 0..7
  const int o0 = ot * 64;
  const int tid = threadIdx.x;
  const int tx = tid & 15;             // col group (4 cols)
  const int ty = tid >> 4;             // row group (2 rows)
  const int n = *cnt;

  if (rt * 32 >= n) return;

  if (tid < 32) {
    int g = rt * 32 + tid;
    rsel[tid] = (g < n) ? rows[g] : rows[0];
  }
  __syncthreads();

  float acc[2][4] = {};
  for (int k0 = 0; k0 < 512; k0 += 32) {
    // A: 32 rows x 32 k = 256 float4, 1/thread
    {
      int row = tid >> 3, q = tid & 7;
      float4 av = *(const float4*)(ctx + (size_t)rsel[row] * 512 + k0 + q * 4);
      As[q * 4 + 0][row] = av.x; As[q * 4 + 1][row] = av.y;
      As[q * 4 + 2][row] = av.z; As[q * 4 + 3][row] = av.w;
    }
    // W: 64 rows x 32 k = 512 float4, 2/thread
#pragma unroll
    for (int i = 0; i < 2; ++i) {
      int flat = tid + i * 256;        // 0..511
      int r = flat >> 3, q = flat & 7;
      float4 wv = *(const float4*)(W + (size_t)(o0 + r) * 512 + k0 + q * 4);
      Ws[q * 4 + 0][r] = wv.x; Ws[q * 4 + 1][r] = wv.y;
      Ws[q * 4 + 2][r] = wv.z; Ws[q * 4 + 3][r] = wv.w;
    }
    __syncthreads();
#pragma unroll
    for (int kk = 0; kk < 32; ++kk) {
      float a_[2], w_[4];
#pragma unroll
      for (int i = 0; i < 2; ++i) a_[i] = As[kk][ty * 2 + i];
#pragma unroll
      for (int j = 0; j < 4; ++j) w_[j] = Ws[kk][tx * 4 + j];
#pragma unroll
      for (int i = 0; i < 2; ++i)
#pragma unroll
        for (int j = 0; j < 4; ++j)
          acc[i][j] = fmaf(a_[i], w_[j], acc[i][j]);
    }
    __syncthreads();
  }

#pragma unroll
  for (int i = 0; i < 2; ++i) {
    int g = rt * 32 + ty * 2 + i;
    if (g < n) {
      int m = rsel[ty * 2 + i];
#pragma unroll
      for (int j = 0; j < 4; ++j) {
        int o = o0 + tx * 4 + j;
        out[(size_t)m * 512 + o] = acc[i][j] + bias[o];
      }
    }
  }
}

// ---------------------------------------------------------------------------
// Flash-split attention (R15, verified): grid 1024, bid%8 == bh%8.
// ---------------------------------------------------------------------------
#define QG 5   // queries per block
#define NC 4   // n-chunks
__global__ __launch_bounds__(256) void attn_part(
    const float* __restrict__ Q, const float* __restrict__ Kt,
    const float* __restrict__ V, const int* __restrict__ Mtop,
    float* __restrict__ pmax, float* __restrict__ psum,
    float* __restrict__ pvp) {
  const int bh = blockIdx.x & 31;
  const int t  = blockIdx.x >> 5;       // 0..31
  const int g  = t & 7;                 // query group
  const int ch = t >> 3;                // n-chunk
  const int b = bh >> 3, h = bh & 7;
  const int tid = threadIdx.x;
  const int wv = tid >> 6, lane = tid & 63;
  const int n0 = ch * 512;

  __shared__ float qs[QG][64];
  __shared__ float p[QG][512];
  __shared__ float redm[QG][4];
  __shared__ float reds[QG][4];
  __shared__ float pvs[4][QG][64];

  for (int i = tid; i < QG * 64; i += 256) {
    int q = i >> 6, e = i & 63;
    int nq = Mtop[bh * UP + g * QG + q];
    qs[q][e] = Q[(((size_t)nq * 4 + b) * 8 + h) * 64 + e];
  }
  __syncthreads();

  const float* ktb = Kt + (size_t)bh * 64 * 2048;
  float d0[QG] = {}, d1[QG] = {};
  const int nb = n0 + tid * 2;
  for (int e = 0; e < 64; ++e) {
    float2 kv = *(const float2*)(ktb + (size_t)e * 2048 + nb);
#pragma unroll
    for (int q = 0; q < QG; ++q) {
      float qe = qs[q][e];
      d0[q] = fmaf(qe, kv.x, d0[q]);
      d1[q] = fmaf(qe, kv.y, d1[q]);
    }
  }

#pragma unroll
  for (int q = 0; q < QG; ++q) {
    float m_ = fmaxf(d0[q], d1[q]);
#pragma unroll
    for (int off = 1; off < 64; off <<= 1)
      m_ = fmaxf(m_, __shfl_xor(m_, off));
    if (lane == 0) redm[q][wv] = m_;
  }
  __syncthreads();
  float gm[QG];
#pragma unroll
  for (int q = 0; q < QG; ++q)
    gm[q] = fmaxf(fmaxf(redm[q][0], redm[q][1]),
                  fmaxf(redm[q][2], redm[q][3]));

  float ls[QG];
#pragma unroll
  for (int q = 0; q < QG; ++q) {
    float e0 = __expf(d0[q] - gm[q]);
    float e1 = __expf(d1[q] - gm[q]);
    p[q][tid * 2] = e0;
    p[q][tid * 2 + 1] = e1;
    ls[q] = e0 + e1;
  }
#pragma unroll
  for (int q = 0; q < QG; ++q) {
    float s_ = ls[q];
#pragma unroll
    for (int off = 1; off < 64; off <<= 1)
      s_ += __shfl_xor(s_, off);
    if (lane == 0) reds[q][wv] = s_;
  }
  __syncthreads();
  float den[QG];
#pragma unroll
  for (int q = 0; q < QG; ++q)
    den[q] = reds[q][0] + reds[q][1] + reds[q][2] + reds[q][3];

  float acc[QG] = {};
  for (int nn = wv * 128; nn < wv * 128 + 128; ++nn) {
    float v = V[(((size_t)(n0 + nn) * 4 + b) * 8 + h) * 64 + lane];
#pragma unroll
    for (int q = 0; q < QG; ++q) acc[q] = fmaf(p[q][nn], v, acc[q]);
  }
#pragma unroll
  for (int q = 0; q < QG; ++q) pvs[wv][q][lane] = acc[q];
  __syncthreads();

  for (int i = tid; i < QG * 64; i += 256) {
    int q = i >> 6, e = i & 63;
    int slot = bh * UP + g * QG + q;
    float pv = pvs[0][q][e] + pvs[1][q][e] + pvs[2][q][e] + pvs[3][q][e];
    pvp[((size_t)slot * NC + ch) * 64 + e] = pv;
    if (e == 0) {
      pmax[slot * NC + ch] = gm[q];
      psum[slot * NC + ch] = den[q];
    }
  }
}

__global__ __launch_bounds__(64) void attn_combine(
    const float* __restrict__ pmax, const float* __restrict__ psum,
    const float* __restrict__ pvp, float* __restrict__ upd) {
  const int slot = blockIdx.x;     // 0..1279
  const int e = threadIdx.x;
  float m = -INFINITY;
#pragma unroll
  for (int ch = 0; ch < NC; ++ch) m = fmaxf(m, pmax[slot * NC + ch]);
  float den = 0.f, num = 0.f;
#pragma unroll
  for (int ch = 0; ch < NC; ++ch) {
    float w = __expf(pmax[slot * NC + ch] - m);
    den = fmaf(w, psum[slot * NC + ch], den);
    num = fmaf(w, pvp[((size_t)slot * NC + ch) * 64 + e], num);
  }
  upd[(size_t)slot * 64 + e] = num / den;
}

// ---------------------------------------------------------------------------
// scatter selected rows
// ---------------------------------------------------------------------------
__global__ void scatter_kernel(const float* __restrict__ upd,
                               const int* __restrict__ Mtop,
                               float* __restrict__ ctx) {
  const int blk = blockIdx.x;   // bh*40 + s
  const int bh = blk / UP;
  const int b = bh >> 3, h = bh & 7;
  const int n = Mtop[blk];
  ctx[((size_t)(b * 2048 + n)) * 512 + h * 64 + threadIdx.x] =
      upd[(size_t)blk * 64 + threadIdx.x];
}

// ---------------------------------------------------------------------------
// Workspace layout (~70 MiB used; ws >= 113 MiB proven in R4):
//   [0, 256K) Mbuf | [256K,576K) upd | [589824,598016) mnV
//   [598016,603136) Mtop | [634880,897024) vpart | [903168,935936) flags
//   [935936,935940) cnt | [936192,941312) rows | [941312,949504) mo
//   [1M,49M) QKV stacked (Q 1-17M = ctx alias, K 17-33M, V 33-49M)
//   [49M,65M) Kt
//   [65M,66.5M) Wh3 | [66.5M,68M) Wl3
//   [68M..68M+64K) pmax/psum | [..~69.4M) pvp
// ---------------------------------------------------------------------------
extern "C" void kernel_launch(void* const* d_in, const int* in_sizes, int n_in,
                              void* d_out, int out_size, void* d_ws,
                              size_t ws_size, hipStream_t stream) {
  const float* query = (const float*)d_in[0];
  const float* key   = (const float*)d_in[1];
  const float* value = (const float*)d_in[2];
  const int*   idxs  = (const int*)d_in[3];
  const float* Wq = (const float*)d_in[4];
  const float* bq = (const float*)d_in[5];
  const float* Wk = (const float*)d_in[6];
  const float* bk = (const float*)d_in[7];
  const float* Wv = (const float*)d_in[8];
  const float* bv = (const float*)d_in[9];
  const float* Wo = (const float*)d_in[10];
  const float* bo = (const float*)d_in[11];
  float* out = (float*)d_out;    // reference output dtype is float32

  char* ws = (char*)d_ws;
  float*  Mbuf  = (float*)(ws + 0);
  float*  upd   = (float*)(ws + 262144);
  float*  mnV   = (float*)(ws + 589824);
  int*    Mtop  = (int*)  (ws + 598016);
  float*  vpart = (float*)(ws + 634880);
  int*    flags = (int*)  (ws + 903168);
  int*    cnt   = (int*)  (ws + 935936);
  int*    rows  = (int*)  (ws + 936192);
  float*  mo    = (float*)(ws + 941312);
  float*  QKV   = (float*)(ws + MiB(1));   // Q | K | V stacked
  float*  Q     = QKV;
  float*  K     = (float*)(ws + MiB(17));
  float*  V     = (float*)(ws + MiB(33));
  float*  Kt    = (float*)(ws + MiB(49));
  ushort* Wh3   = (ushort*)(ws + MiB(65));
  ushort* Wl3   = (ushort*)(ws + MiB(65) + 1572864);
  float*  pmax  = (float*)(ws + MiB(68));
  float*  psum  = (float*)(ws + MiB(68) + 32768);
  float*  pvp   = (float*)(ws + MiB(68) + 65536);
  float*  ctx   = Q;   // Q dead after attn; ctx written afterwards

  // zero flags + cnt (contiguous region)
  hipMemsetAsync(flags, 0, 32768 + 4, stream);

  wsplit3_kernel<<<1536, 256, 0, stream>>>(Wq, Wk, Wv, Wh3, Wl3);
  gemm3_mfma<<<768, 256, 0, stream>>>(query, key, value, Wh3, Wl3,
                                      bq, bk, bv, QKV);

  transposeK_kernel<<<512, 256, 0, stream>>>(K, Kt);

  mscore_kernel<<<16384, 256, 0, stream>>>(Q, K, idxs, Mbuf);
  topk_kernel<<<NBH, 256, 0, stream>>>(Mbuf, Mtop, flags);
  selcompact_kernel<<<32, 256, 0, stream>>>(flags, rows, cnt);

  meanv_part<<<256, 256, 0, stream>>>(V, vpart);
  meanv_final<<<8, 256, 0, stream>>>(vpart, mnV);

  attn_part<<<NBH * 32, 256, 0, stream>>>(Q, Kt, V, Mtop, pmax, psum, pvp);
  attn_combine<<<NBH * UP, 64, 0, stream>>>(pmax, psum, pvp, upd);

  fillsel_kernel<<<NBH * UP, 128, 0, stream>>>(mnV, rows, cnt, ctx);
  scatter_kernel<<<NBH * UP, 64, 0, stream>>>(upd, Mtop, ctx);

  meanout_kernel<<<32, 256, 0, stream>>>(mnV, Wo, bo, mo);
  fillout_kernel<<<4096, 256, 0, stream>>>(mo, out);
  gemm_rows<<<320, 256, 0, stream>>>(ctx, Wo, bo, rows, cnt, out);
}

// Round 23
// 189.060 us; speedup vs baseline: 1.7959x; 1.0610x over previous
//
#include <hip/hip_runtime.h>
#include <hip/hip_bf16.h>

// Problem constants
#define KN 2048
#define BB 4
#define DM 512
#define NH 8
#define HE 64
#define UP 40
#define NBH 32          // B*H
#define NROWS 8192      // KN*B
#define MiB(x) ((size_t)(x) << 20)

typedef __attribute__((ext_vector_type(8))) short short8;
typedef __attribute__((ext_vector_type(4))) float f32x4;

// bf16 split helpers (RNE)
__device__ __forceinline__ ushort f2bf(float x) {
  unsigned u = __float_as_uint(x);
  unsigned r = (u + 0x7FFFu + ((u >> 16) & 1u)) >> 16;
  return (ushort)r;
}
__device__ __forceinline__ float bf2f(ushort h) {
  return __uint_as_float((unsigned)h << 16);
}

// ---------------------------------------------------------------------------
// Fused split of the 3 weight matrices into hi/lo bf16 planes (stacked).
// ---------------------------------------------------------------------------
__global__ __launch_bounds__(256) void wsplit3_kernel(
    const float* __restrict__ W0, const float* __restrict__ W1,
    const float* __restrict__ W2, ushort* __restrict__ Wh,
    ushort* __restrict__ Wl) {
  const int which = blockIdx.x >> 9;
  const float* W = (which == 0) ? W0 : (which == 1) ? W1 : W2;
  size_t base = (size_t)which * 262144;
  int i = ((blockIdx.x & 511) * 256 + threadIdx.x) * 2;
  float2 v = *(const float2*)(W + i);
  ushort h0 = f2bf(v.x), h1 = f2bf(v.y);
  ushort l0 = f2bf(v.x - bf2f(h0)), l1 = f2bf(v.y - bf2f(h1));
  *(ushort2*)(Wh + base + i) = make_ushort2(h0, h1);
  *(ushort2*)(Wl + base + i) = make_ushort2(l0, l1);
}

// ---------------------------------------------------------------------------
// Fused 3-GEMM, LDS staging, BM=64 x BN=256 tiles (conversion redundancy 2x
// instead of 4x), 3-term split (AhWh+AhWl+AlWh). A read as f32, split
// in-register during staging (RNE). W planes preconverted (L2-resident).
// grid 768 = 3 x 256; which = bid>>8. Sub-grid 256 = 8 xcd x 16 mt x 2 ot:
// xcd = local&7 -> per-XCD A slice 2MB (L2-fits). Wave w owns cols
// [w*64,+64) x all 64 rows; acc 4x4 frags; 16 ds_read_b128 : 48 MFMA.
// ---------------------------------------------------------------------------
#define APAD 40
__global__ __launch_bounds__(256) void gemm3_mfma(
    const float* __restrict__ A0, const float* __restrict__ A1,
    const float* __restrict__ A2,
    const ushort* __restrict__ Wh3, const ushort* __restrict__ Wl3,
    const float* __restrict__ bq, const float* __restrict__ bk,
    const float* __restrict__ bv, float* __restrict__ QKV) {
  __shared__ ushort AsH[64 * APAD];
  __shared__ ushort AsL[64 * APAD];
  __shared__ ushort WsH[256 * APAD];
  __shared__ ushort WsL[256 * APAD];

  const int which = blockIdx.x >> 8;
  const int local = blockIdx.x & 255;
  const int xcd = local & 7;
  const int idx = local >> 3;            // 0..31
  const int ot = idx >> 4;               // 0..1
  const int mt = xcd * 16 + (idx & 15);  // 0..127
  const int m0 = mt * 64, o0 = ot * 256;

  const float* A = (which == 0) ? A0 : (which == 1) ? A1 : A2;
  const ushort* Wh = Wh3 + (size_t)which * 262144;
  const ushort* Wl = Wl3 + (size_t)which * 262144;
  const float* bias = (which == 0) ? bq : (which == 1) ? bk : bv;
  float* C = QKV + (size_t)which * 8192 * 512;
  const float scale = (which == 0) ? 0.125f : 1.0f;

  const int tid = threadIdx.x;
  const int w = tid >> 6, lane = tid & 63;
  const int fr = lane & 15;            // fragment row
  const int kc = lane >> 4;            // k-chunk (8 bf16)

  f32x4 acc[4][4];
#pragma unroll
  for (int i = 0; i < 4; ++i)
#pragma unroll
    for (int j = 0; j < 4; ++j)
#pragma unroll
      for (int r = 0; r < 4; ++r) acc[i][j][r] = 0.f;

  for (int k0 = 0; k0 < 512; k0 += 32) {
    // stage A: 64 rows x 32 floats = 512 float4; 2 chunks/thread,
    // converted to bf16 hi/lo in-register (RNE split).
#pragma unroll
    for (int i = 0; i < 2; ++i) {
      int c = tid + i * 256;           // 0..511
      int row = c >> 3, q = c & 7;
      float4 v = *(const float4*)(A + (size_t)(m0 + row) * 512 + k0 + q * 4);
      ushort h0 = f2bf(v.x), h1 = f2bf(v.y), h2 = f2bf(v.z), h3 = f2bf(v.w);
      ushort l0 = f2bf(v.x - bf2f(h0)), l1 = f2bf(v.y - bf2f(h1));
      ushort l2 = f2bf(v.z - bf2f(h2)), l3 = f2bf(v.w - bf2f(h3));
      *(ushort4*)(AsH + row * APAD + q * 4) = make_ushort4(h0, h1, h2, h3);
      *(ushort4*)(AsL + row * APAD + q * 4) = make_ushort4(l0, l1, l2, l3);
    }
    // stage W: 256 rows x 32 k = 1024 short8 chunks per plane; 4/thread each
#pragma unroll
    for (int i = 0; i < 4; ++i) {
      int c = tid + i * 256;           // 0..1023
      int row = c >> 2, kq = (c & 3) * 8;
      size_t gw = (size_t)(o0 + row) * 512 + k0 + kq;
      int lo = row * APAD + kq;
      *(short8*)(WsH + lo) = *(const short8*)(Wh + gw);
      *(short8*)(WsL + lo) = *(const short8*)(Wl + gw);
    }
    __syncthreads();

    short8 ah[4], al[4], bh[4], bl[4];
#pragma unroll
    for (int i = 0; i < 4; ++i) {
      int off = (i * 16 + fr) * APAD + kc * 8;
      ah[i] = *(const short8*)(AsH + off);
      al[i] = *(const short8*)(AsL + off);
    }
#pragma unroll
    for (int j = 0; j < 4; ++j) {
      int off = (w * 64 + j * 16 + fr) * APAD + kc * 8;
      bh[j] = *(const short8*)(WsH + off);
      bl[j] = *(const short8*)(WsL + off);
    }
#pragma unroll
    for (int i = 0; i < 4; ++i)
#pragma unroll
      for (int j = 0; j < 4; ++j) {
        acc[i][j] = __builtin_amdgcn_mfma_f32_16x16x32_bf16(
            ah[i], bh[j], acc[i][j], 0, 0, 0);
        acc[i][j] = __builtin_amdgcn_mfma_f32_16x16x32_bf16(
            ah[i], bl[j], acc[i][j], 0, 0, 0);
        acc[i][j] = __builtin_amdgcn_mfma_f32_16x16x32_bf16(
            al[i], bh[j], acc[i][j], 0, 0, 0);
      }
    __syncthreads();
  }

#pragma unroll
  for (int i = 0; i < 4; ++i)
#pragma unroll
    for (int j = 0; j < 4; ++j)
#pragma unroll
      for (int r = 0; r < 4; ++r) {
        int m = m0 + i * 16 + (lane >> 4) * 4 + r;
        int o = o0 + w * 64 + j * 16 + fr;
        C[(size_t)m * 512 + o] = (acc[i][j][r] + bias[o]) * scale;
      }
}

// ---------------------------------------------------------------------------
// Transpose K into Kt[bh][e][n] for coalesced attention score reads.
// ---------------------------------------------------------------------------
__global__ __launch_bounds__(256) void transposeK_kernel(
    const float* __restrict__ K, float* __restrict__ Kt) {
  const int bh = blockIdx.x & 31;
  const int nt = blockIdx.x >> 5;       // 0..15
  const int b = bh >> 3, h = bh & 7;
  const int n0 = nt * 128;
  const int tid = threadIdx.x;
  __shared__ float T[128][65];

#pragma unroll
  for (int i = 0; i < 8; ++i) {
    int flat = tid + i * 256;           // 0..2047
    int r = flat >> 4;                  // 0..127
    int c4 = flat & 15;                 // 0..15
    float4 v = *(const float4*)(K + (((size_t)(n0 + r) * 4 + b) * 8 + h) * 64 + c4 * 4);
    T[r][c4 * 4 + 0] = v.x; T[r][c4 * 4 + 1] = v.y;
    T[r][c4 * 4 + 2] = v.z; T[r][c4 * 4 + 3] = v.w;
  }
  __syncthreads();

  const int nl = tid & 127;             // 0..127
  const int eg = tid >> 7;              // 0..1
#pragma unroll
  for (int e = eg * 32; e < eg * 32 + 32; ++e)
    Kt[((size_t)bh * 64 + e) * 2048 + n0 + nl] = T[nl][e];
}

// ---------------------------------------------------------------------------
// M scores, wave-cooperative gather. One wave per (bh, n).
// ---------------------------------------------------------------------------
__global__ __launch_bounds__(256) void mscore_kernel(
    const float* __restrict__ Q, const float* __restrict__ K,
    const int* __restrict__ idx, float* __restrict__ Mout) {
  const int bh = blockIdx.x & 31;
  const int c  = blockIdx.x >> 5;        // 0..511
  const int wv = threadIdx.x >> 6;       // 0..3
  const int lane = threadIdx.x & 63;
  const int n = c * 4 + wv;
  const int b = bh >> 3, h = bh & 7;
  const int g = lane >> 4;               // sample group 0..3
  const int e16 = lane & 15;             // element chunk within row

  const float4 qv = *(const float4*)(Q + (((size_t)n * 4 + b) * 8 + h) * 64 + e16 * 4);

  float mx = -INFINITY, sm = 0.f;
#pragma unroll
  for (int it = 0; it < 10; ++it) {
    const int s = it * 4 + g;
    const int kn = idx[n * UP + s];
    const float4 kv = *(const float4*)(K + (((size_t)kn * 4 + b) * 8 + h) * 64 + e16 * 4);
    float d = qv.x * kv.x + qv.y * kv.y + qv.z * kv.z + qv.w * kv.w;
    d += __shfl_xor(d, 1);
    d += __shfl_xor(d, 2);
    d += __shfl_xor(d, 4);
    d += __shfl_xor(d, 8);
    mx = fmaxf(mx, d);
    sm += d;
  }
  mx = fmaxf(mx, __shfl_xor(mx, 16));
  mx = fmaxf(mx, __shfl_xor(mx, 32));
  sm += __shfl_xor(sm, 16);
  sm += __shfl_xor(sm, 32);
  if (lane == 0) Mout[(size_t)bh * 2048 + n] = mx - sm * (1.0f / (float)KN);
}

// ---------------------------------------------------------------------------
// top-40 per (b,h) via 4-pass byte radix-select (R14, verified).
// ---------------------------------------------------------------------------
__global__ __launch_bounds__(256) void topk_kernel(
    const float* __restrict__ M, int* __restrict__ Mtop) {
  const int bh = blockIdx.x;
  __shared__ unsigned keys[2048];
  __shared__ int hist[256];
  __shared__ int suf[256];
  __shared__ int scal[2];
  __shared__ int ties[128];
  __shared__ int cnts[2];

  const int tid = threadIdx.x;
  const float* Mrow = M + (size_t)bh * 2048;
#pragma unroll
  for (int i = 0; i < 8; ++i) {
    int j = tid + i * 256;
    unsigned u = __float_as_uint(Mrow[j]);
    keys[j] = (u & 0x80000000u) ? ~u : (u | 0x80000000u);  // monotone map
  }
  if (tid < 2) cnts[tid] = 0;

  unsigned prefix = 0, prefmask = 0;
  int rank = UP;
#pragma unroll
  for (int shift = 24; shift >= 0; shift -= 8) {
    hist[tid] = 0;
    __syncthreads();
#pragma unroll
    for (int i = 0; i < 8; ++i) {
      unsigned k = keys[tid + i * 256];
      if ((k & prefmask) == prefix)
        atomicAdd(&hist[(k >> shift) & 0xFFu], 1);
    }
    __syncthreads();
    suf[tid] = hist[tid];
    __syncthreads();
#pragma unroll
    for (int off = 1; off < 256; off <<= 1) {
      int add = (tid + off < 256) ? suf[tid + off] : 0;
      __syncthreads();
      suf[tid] += add;
      __syncthreads();
    }
    {
      int above = suf[tid] - hist[tid];
      if (above < rank && rank <= suf[tid]) {
        scal[0] = tid;
        scal[1] = rank - above;
      }
    }
    __syncthreads();
    prefix |= ((unsigned)scal[0]) << shift;
    prefmask |= 0xFFu << shift;
    rank = scal[1];
    __syncthreads();
  }
  const unsigned T = prefix;

#pragma unroll
  for (int i = 0; i < 8; ++i) {
    int j = tid + i * 256;
    unsigned k = keys[j];
    if (k > T) {
      int p = atomicAdd(&cnts[0], 1);
      Mtop[bh * UP + p] = j;
    } else if (k == T) {
      int p = atomicAdd(&cnts[1], 1);
      if (p < 128) ties[p] = j;
    }
  }
  __syncthreads();
  if (tid == 0) {
    int base = cnts[0];
    int need = UP - base;
    int tc = cnts[1] < 128 ? cnts[1] : 128;
    for (int s = 0; s < need; ++s) {
      int best = 1 << 30, bj = 0;
      for (int j = 0; j < tc; ++j) {
        int v = ties[j];
        if (v < best) { best = v; bj = j; }
      }
      Mtop[bh * UP + base + s] = best;
      ties[bj] = 1 << 30;
    }
  }
}

// ---------------------------------------------------------------------------
// mean of V: two-phase coalesced column-sum (V is a [2048][2048] matrix).
// ---------------------------------------------------------------------------
__global__ __launch_bounds__(256) void meanv_part(
    const float* __restrict__ V, float* __restrict__ part) {
  const int rc = blockIdx.x >> 3;      // 0..31
  const int cc = blockIdx.x & 7;       // 0..7
  const int c = cc * 256 + threadIdx.x;
  const float* p = V + (size_t)rc * 64 * 2048 + c;
  float acc = 0.f;
#pragma unroll 8
  for (int i = 0; i < 64; ++i) acc += p[(size_t)i * 2048];
  part[(size_t)rc * 2048 + c] = acc;
}

__global__ __launch_bounds__(256) void meanv_final(
    const float* __restrict__ part, float* __restrict__ mnV) {
  const int c = blockIdx.x * 256 + threadIdx.x;   // 8 blocks
  float acc = 0.f;
#pragma unroll
  for (int r = 0; r < 32; ++r) acc += part[(size_t)r * 2048 + c];
  mnV[c] = acc * (1.0f / (float)KN);
}

// ---------------------------------------------------------------------------
// meanout[b][o] = dot(mnV[b*512..], Wo[o]) + bo[o]; 32 blocks, k-split x4
// with fixed-order reduce (deterministic).
// ---------------------------------------------------------------------------
__global__ __launch_bounds__(256) void meanout_kernel(
    const float* __restrict__ mnV, const float* __restrict__ Wo,
    const float* __restrict__ bo, float* __restrict__ mo) {
  const int b = blockIdx.x >> 3;          // 0..3
  const int oc = blockIdx.x & 7;          // 0..7
  const int ol = threadIdx.x & 63;        // o within chunk
  const int kp = threadIdx.x >> 6;        // k-part 0..3
  const int o = oc * 64 + ol;
  __shared__ float red[4][64];

  const float* m = mnV + b * 512;
  const float* w = Wo + (size_t)o * 512;
  float acc = 0.f;
#pragma unroll 8
  for (int k = kp * 128; k < kp * 128 + 128; ++k)
    acc = fmaf(m[k], w[k], acc);
  red[kp][ol] = acc;
  __syncthreads();
  if (threadIdx.x < 64) {
    float s = red[0][ol] + red[1][ol] + red[2][ol] + red[3][ol];
    mo[b * 512 + o] = s + bo[o];
  }
}

// out broadcast fill (float4)
__global__ void fillout_kernel(const float* __restrict__ mo,
                               float* __restrict__ out) {
  size_t i = ((size_t)blockIdx.x * 256 + threadIdx.x) * 4;
  int d = (int)(i & 511);
  int b = (int)(i >> 20);
  float4 v = *(const float4*)(mo + (b << 9) + d);
  *(float4*)(out + i) = v;
}

// ---------------------------------------------------------------------------
// Seed the selected ctx rows with the per-batch mean row, indexed directly
// from Mtop (duplicates across heads write identical values - benign).
// ---------------------------------------------------------------------------
__global__ __launch_bounds__(128) void fillsel_kernel(
    const int* __restrict__ Mtop, const float* __restrict__ mnV,
    float* __restrict__ ctx) {
  const int i = blockIdx.x;            // 0..1279
  const int b = (i / UP) >> 3;
  const int row = b * 2048 + Mtop[i];
  float4 v = *(const float4*)(mnV + b * 512 + threadIdx.x * 4);
  *(float4*)(ctx + (size_t)row * 512 + threadIdx.x * 4) = v;
}

// ---------------------------------------------------------------------------
// Sparse output GEMM over the 1280 Mtop rows (dups recompute identical
// values - benign). 32-row x 64-col tiles, grid 320 exact.
// ---------------------------------------------------------------------------
__global__ __launch_bounds__(256) void gemm_rows(
    const float* __restrict__ ctx, const float* __restrict__ W,
    const float* __restrict__ bias, const int* __restrict__ Mtop,
    float* __restrict__ out) {
  __shared__ float As[32][36];   // [k][row]
  __shared__ float Ws[32][68];   // [k][col]
  __shared__ int rsel[32];
  const int rt = blockIdx.x >> 3;      // 0..39
  const int ot = blockIdx.x & 7;       // 0..7
  const int o0 = ot * 64;
  const int tid = threadIdx.x;
  const int tx = tid & 15;             // col group (4 cols)
  const int ty = tid >> 4;             // row group (2 rows)

  if (tid < 32) {
    int g = rt * 32 + tid;             // 0..1279
    int b = (g / UP) >> 3;
    rsel[tid] = b * 2048 + Mtop[g];
  }
  __syncthreads();

  float acc[2][4] = {};
  for (int k0 = 0; k0 < 512; k0 += 32) {
    {
      int row = tid >> 3, q = tid & 7;
      float4 av = *(const float4*)(ctx + (size_t)rsel[row] * 512 + k0 + q * 4);
      As[q * 4 + 0][row] = av.x; As[q * 4 + 1][row] = av.y;
      As[q * 4 + 2][row] = av.z; As[q * 4 + 3][row] = av.w;
    }
#pragma unroll
    for (int i = 0; i < 2; ++i) {
      int flat = tid + i * 256;        // 0..511
      int r = flat >> 3, q = flat & 7;
      float4 wv = *(const float4*)(W + (size_t)(o0 + r) * 512 + k0 + q * 4);
      Ws[q * 4 + 0][r] = wv.x; Ws[q * 4 + 1][r] = wv.y;
      Ws[q * 4 + 2][r] = wv.z; Ws[q * 4 + 3][r] = wv.w;
    }
    __syncthreads();
#pragma unroll
    for (int kk = 0; kk < 32; ++kk) {
      float a_[2], w_[4];
#pragma unroll
      for (int i = 0; i < 2; ++i) a_[i] = As[kk][ty * 2 + i];
#pragma unroll
      for (int j = 0; j < 4; ++j) w_[j] = Ws[kk][tx * 4 + j];
#pragma unroll
      for (int i = 0; i < 2; ++i)
#pragma unroll
        for (int j = 0; j < 4; ++j)
          acc[i][j] = fmaf(a_[i], w_[j], acc[i][j]);
    }
    __syncthreads();
  }

#pragma unroll
  for (int i = 0; i < 2; ++i) {
    int m = rsel[ty * 2 + i];
#pragma unroll
    for (int j = 0; j < 4; ++j) {
      int o = o0 + tx * 4 + j;
      out[(size_t)m * 512 + o] = acc[i][j] + bias[o];
    }
  }
}

// ---------------------------------------------------------------------------
// Flash-split attention (R15, verified): grid 1024, bid%8 == bh%8.
// ---------------------------------------------------------------------------
#define QG 5   // queries per block
#define NC 4   // n-chunks
__global__ __launch_bounds__(256) void attn_part(
    const float* __restrict__ Q, const float* __restrict__ Kt,
    const float* __restrict__ V, const int* __restrict__ Mtop,
    float* __restrict__ pmax, float* __restrict__ psum,
    float* __restrict__ pvp) {
  const int bh = blockIdx.x & 31;
  const int t  = blockIdx.x >> 5;       // 0..31
  const int g  = t & 7;                 // query group
  const int ch = t >> 3;                // n-chunk
  const int b = bh >> 3, h = bh & 7;
  const int tid = threadIdx.x;
  const int wv = tid >> 6, lane = tid & 63;
  const int n0 = ch * 512;

  __shared__ float qs[QG][64];
  __shared__ float p[QG][512];
  __shared__ float redm[QG][4];
  __shared__ float reds[QG][4];
  __shared__ float pvs[4][QG][64];

  for (int i = tid; i < QG * 64; i += 256) {
    int q = i >> 6, e = i & 63;
    int nq = Mtop[bh * UP + g * QG + q];
    qs[q][e] = Q[(((size_t)nq * 4 + b) * 8 + h) * 64 + e];
  }
  __syncthreads();

  const float* ktb = Kt + (size_t)bh * 64 * 2048;
  float d0[QG] = {}, d1[QG] = {};
  const int nb = n0 + tid * 2;
  for (int e = 0; e < 64; ++e) {
    float2 kv = *(const float2*)(ktb + (size_t)e * 2048 + nb);
#pragma unroll
    for (int q = 0; q < QG; ++q) {
      float qe = qs[q][e];
      d0[q] = fmaf(qe, kv.x, d0[q]);
      d1[q] = fmaf(qe, kv.y, d1[q]);
    }
  }

#pragma unroll
  for (int q = 0; q < QG; ++q) {
    float m_ = fmaxf(d0[q], d1[q]);
#pragma unroll
    for (int off = 1; off < 64; off <<= 1)
      m_ = fmaxf(m_, __shfl_xor(m_, off));
    if (lane == 0) redm[q][wv] = m_;
  }
  __syncthreads();
  float gm[QG];
#pragma unroll
  for (int q = 0; q < QG; ++q)
    gm[q] = fmaxf(fmaxf(redm[q][0], redm[q][1]),
                  fmaxf(redm[q][2], redm[q][3]));

  float ls[QG];
#pragma unroll
  for (int q = 0; q < QG; ++q) {
    float e0 = __expf(d0[q] - gm[q]);
    float e1 = __expf(d1[q] - gm[q]);
    p[q][tid * 2] = e0;
    p[q][tid * 2 + 1] = e1;
    ls[q] = e0 + e1;
  }
#pragma unroll
  for (int q = 0; q < QG; ++q) {
    float s_ = ls[q];
#pragma unroll
    for (int off = 1; off < 64; off <<= 1)
      s_ += __shfl_xor(s_, off);
    if (lane == 0) reds[q][wv] = s_;
  }
  __syncthreads();
  float den[QG];
#pragma unroll
  for (int q = 0; q < QG; ++q)
    den[q] = reds[q][0] + reds[q][1] + reds[q][2] + reds[q][3];

  float acc[QG] = {};
  for (int nn = wv * 128; nn < wv * 128 + 128; ++nn) {
    float v = V[(((size_t)(n0 + nn) * 4 + b) * 8 + h) * 64 + lane];
#pragma unroll
    for (int q = 0; q < QG; ++q) acc[q] = fmaf(p[q][nn], v, acc[q]);
  }
#pragma unroll
  for (int q = 0; q < QG; ++q) pvs[wv][q][lane] = acc[q];
  __syncthreads();

  for (int i = tid; i < QG * 64; i += 256) {
    int q = i >> 6, e = i & 63;
    int slot = bh * UP + g * QG + q;
    float pv = pvs[0][q][e] + pvs[1][q][e] + pvs[2][q][e] + pvs[3][q][e];
    pvp[((size_t)slot * NC + ch) * 64 + e] = pv;
    if (e == 0) {
      pmax[slot * NC + ch] = gm[q];
      psum[slot * NC + ch] = den[q];
    }
  }
}

__global__ __launch_bounds__(64) void attn_combine(
    const float* __restrict__ pmax, const float* __restrict__ psum,
    const float* __restrict__ pvp, float* __restrict__ upd) {
  const int slot = blockIdx.x;     // 0..1279
  const int e = threadIdx.x;
  float m = -INFINITY;
#pragma unroll
  for (int ch = 0; ch < NC; ++ch) m = fmaxf(m, pmax[slot * NC + ch]);
  float den = 0.f, num = 0.f;
#pragma unroll
  for (int ch = 0; ch < NC; ++ch) {
    float w = __expf(pmax[slot * NC + ch] - m);
    den = fmaf(w, psum[slot * NC + ch], den);
    num = fmaf(w, pvp[((size_t)slot * NC + ch) * 64 + e], num);
  }
  upd[(size_t)slot * 64 + e] = num / den;
}

// ---------------------------------------------------------------------------
// scatter selected rows
// ---------------------------------------------------------------------------
__global__ void scatter_kernel(const float* __restrict__ upd,
                               const int* __restrict__ Mtop,
                               float* __restrict__ ctx) {
  const int blk = blockIdx.x;   // bh*40 + s
  const int bh = blk / UP;
  const int b = bh >> 3, h = bh & 7;
  const int n = Mtop[blk];
  ctx[((size_t)(b * 2048 + n)) * 512 + h * 64 + threadIdx.x] =
      upd[(size_t)blk * 64 + threadIdx.x];
}

// ---------------------------------------------------------------------------
// Workspace layout (~70 MiB used; ws >= 113 MiB proven in R4):
//   [0, 256K) Mbuf | [256K,576K) upd | [589824,598016) mnV
//   [598016,603136) Mtop | [634880,897024) vpart | [941312,949504) mo
//   [1M,49M) QKV stacked (Q 1-17M = ctx alias, K 17-33M, V 33-49M)
//   [49M,65M) Kt
//   [65M,66.5M) Wh3 | [66.5M,68M) Wl3
//   [68M..68M+64K) pmax/psum | [..~69.4M) pvp
// ---------------------------------------------------------------------------
extern "C" void kernel_launch(void* const* d_in, const int* in_sizes, int n_in,
                              void* d_out, int out_size, void* d_ws,
                              size_t ws_size, hipStream_t stream) {
  const float* query = (const float*)d_in[0];
  const float* key   = (const float*)d_in[1];
  const float* value = (const float*)d_in[2];
  const int*   idxs  = (const int*)d_in[3];
  const float* Wq = (const float*)d_in[4];
  const float* bq = (const float*)d_in[5];
  const float* Wk = (const float*)d_in[6];
  const float* bk = (const float*)d_in[7];
  const float* Wv = (const float*)d_in[8];
  const float* bv = (const float*)d_in[9];
  const float* Wo = (const float*)d_in[10];
  const float* bo = (const float*)d_in[11];
  float* out = (float*)d_out;    // reference output dtype is float32

  char* ws = (char*)d_ws;
  float*  Mbuf  = (float*)(ws + 0);
  float*  upd   = (float*)(ws + 262144);
  float*  mnV   = (float*)(ws + 589824);
  int*    Mtop  = (int*)  (ws + 598016);
  float*  vpart = (float*)(ws + 634880);
  float*  mo    = (float*)(ws + 941312);
  float*  QKV   = (float*)(ws + MiB(1));   // Q | K | V stacked
  float*  Q     = QKV;
  float*  K     = (float*)(ws + MiB(17));
  float*  V     = (float*)(ws + MiB(33));
  float*  Kt    = (float*)(ws + MiB(49));
  ushort* Wh3   = (ushort*)(ws + MiB(65));
  ushort* Wl3   = (ushort*)(ws + MiB(65) + 1572864);
  float*  pmax  = (float*)(ws + MiB(68));
  float*  psum  = (float*)(ws + MiB(68) + 32768);
  float*  pvp   = (float*)(ws + MiB(68) + 65536);
  float*  ctx   = Q;   // Q dead after attn; ctx written afterwards

  wsplit3_kernel<<<1536, 256, 0, stream>>>(Wq, Wk, Wv, Wh3, Wl3);
  gemm3_mfma<<<768, 256, 0, stream>>>(query, key, value, Wh3, Wl3,
                                      bq, bk, bv, QKV);

  transposeK_kernel<<<512, 256, 0, stream>>>(K, Kt);

  mscore_kernel<<<16384, 256, 0, stream>>>(Q, K, idxs, Mbuf);
  topk_kernel<<<NBH, 256, 0, stream>>>(Mbuf, Mtop);

  meanv_part<<<256, 256, 0, stream>>>(V, vpart);
  meanv_final<<<8, 256, 0, stream>>>(vpart, mnV);

  attn_part<<<NBH * 32, 256, 0, stream>>>(Q, Kt, V, Mtop, pmax, psum, pvp);
  attn_combine<<<NBH * UP, 64, 0, stream>>>(pmax, psum, pvp, upd);

  fillsel_kernel<<<NBH * UP, 128, 0, stream>>>(Mtop, mnV, ctx);
  scatter_kernel<<<NBH * UP, 64, 0, stream>>>(upd, Mtop, ctx);

  meanout_kernel<<<32, 256, 0, stream>>>(mnV, Wo, bo, mo);
  fillout_kernel<<<4096, 256, 0, stream>>>(mo, out);
  gemm_rows<<<320, 256, 0, stream>>>(ctx, Wo, bo, Mtop, out);
}

// Round 24
// 188.179 us; speedup vs baseline: 1.8043x; 1.0047x over previous
//
#include <hip/hip_runtime.h>
#include <hip/hip_bf16.h>

// Problem constants
#define KN 2048
#define BB 4
#define DM 512
#define NH 8
#define HE 64
#define UP 40
#define NBH 32          // B*H
#define NROWS 8192      // KN*B
#define MiB(x) ((size_t)(x) << 20)

typedef __attribute__((ext_vector_type(8))) short short8;
typedef __attribute__((ext_vector_type(4))) float f32x4;

// bf16 split helpers (RNE)
__device__ __forceinline__ ushort f2bf(float x) {
  unsigned u = __float_as_uint(x);
  unsigned r = (u + 0x7FFFu + ((u >> 16) & 1u)) >> 16;
  return (ushort)r;
}
__device__ __forceinline__ float bf2f(ushort h) {
  return __uint_as_float((unsigned)h << 16);
}

// ---------------------------------------------------------------------------
// Fused split of the 3 weight matrices into hi/lo bf16 planes (stacked).
// ---------------------------------------------------------------------------
__global__ __launch_bounds__(256) void wsplit3_kernel(
    const float* __restrict__ W0, const float* __restrict__ W1,
    const float* __restrict__ W2, ushort* __restrict__ Wh,
    ushort* __restrict__ Wl) {
  const int which = blockIdx.x >> 9;
  const float* W = (which == 0) ? W0 : (which == 1) ? W1 : W2;
  size_t base = (size_t)which * 262144;
  int i = ((blockIdx.x & 511) * 256 + threadIdx.x) * 2;
  float2 v = *(const float2*)(W + i);
  ushort h0 = f2bf(v.x), h1 = f2bf(v.y);
  ushort l0 = f2bf(v.x - bf2f(h0)), l1 = f2bf(v.y - bf2f(h1));
  *(ushort2*)(Wh + base + i) = make_ushort2(h0, h1);
  *(ushort2*)(Wl + base + i) = make_ushort2(l0, l1);
}

// ---------------------------------------------------------------------------
// Fused 3-GEMM: A in double-buffered LDS (hi/lo, converted in-staging),
// W fragments read DIRECTLY from global bf16 planes (L2-resident, R17-proven
// addressing). BM=64 x BN=256 tiles, ONE barrier per k-step:
//   stage(buf^1, k+32) issued BEFORE frag-read/MFMA on buf -> overlap.
// LDS = 2 x (AsH+AsL) = 20.5 KB -> 4+ blocks/CU co-resident.
// 3-term split (AhWh+AhWl+AlWh). grid 768 = 3 x 256; which = bid>>8;
// sub-grid: xcd = local&7 -> per-XCD A slice 2MB (L2-fits).
// ---------------------------------------------------------------------------
#define APAD 40
__global__ __launch_bounds__(256) void gemm3_mfma(
    const float* __restrict__ A0, const float* __restrict__ A1,
    const float* __restrict__ A2,
    const ushort* __restrict__ Wh3, const ushort* __restrict__ Wl3,
    const float* __restrict__ bq, const float* __restrict__ bk,
    const float* __restrict__ bv, float* __restrict__ QKV) {
  __shared__ ushort AsH[2][64 * APAD];
  __shared__ ushort AsL[2][64 * APAD];

  const int which = blockIdx.x >> 8;
  const int local = blockIdx.x & 255;
  const int xcd = local & 7;
  const int idx = local >> 3;            // 0..31
  const int ot = idx >> 4;               // 0..1
  const int mt = xcd * 16 + (idx & 15);  // 0..127
  const int m0 = mt * 64, o0 = ot * 256;

  const float* A = (which == 0) ? A0 : (which == 1) ? A1 : A2;
  const ushort* Wh = Wh3 + (size_t)which * 262144;
  const ushort* Wl = Wl3 + (size_t)which * 262144;
  const float* bias = (which == 0) ? bq : (which == 1) ? bk : bv;
  float* C = QKV + (size_t)which * 8192 * 512;
  const float scale = (which == 0) ? 0.125f : 1.0f;

  const int tid = threadIdx.x;
  const int w = tid >> 6, lane = tid & 63;
  const int fr = lane & 15;            // fragment row
  const int kc = lane >> 4;            // k-chunk (8 bf16)

  f32x4 acc[4][4];
#pragma unroll
  for (int i = 0; i < 4; ++i)
#pragma unroll
    for (int j = 0; j < 4; ++j)
#pragma unroll
      for (int r = 0; r < 4; ++r) acc[i][j][r] = 0.f;

  // staging decode: 512 float4 chunks, 2/thread; row = c>>3, q = c&7
  const int srow0 = tid >> 3, sq0 = tid & 7;
  const int srow1 = (tid + 256) >> 3, sq1 = (tid + 256) & 7;

#define STAGE_A(BUF, K0)                                                    \
  do {                                                                      \
    float4 v0 = *(const float4*)(A + (size_t)(m0 + srow0) * 512 + (K0) + sq0 * 4); \
    float4 v1 = *(const float4*)(A + (size_t)(m0 + srow1) * 512 + (K0) + sq1 * 4); \
    ushort h0 = f2bf(v0.x), h1 = f2bf(v0.y), h2 = f2bf(v0.z), h3 = f2bf(v0.w); \
    *(ushort4*)(&AsH[BUF][srow0 * APAD + sq0 * 4]) = make_ushort4(h0, h1, h2, h3); \
    *(ushort4*)(&AsL[BUF][srow0 * APAD + sq0 * 4]) = make_ushort4(           \
        f2bf(v0.x - bf2f(h0)), f2bf(v0.y - bf2f(h1)),                        \
        f2bf(v0.z - bf2f(h2)), f2bf(v0.w - bf2f(h3)));                       \
    ushort g0 = f2bf(v1.x), g1 = f2bf(v1.y), g2 = f2bf(v1.z), g3 = f2bf(v1.w); \
    *(ushort4*)(&AsH[BUF][srow1 * APAD + sq1 * 4]) = make_ushort4(g0, g1, g2, g3); \
    *(ushort4*)(&AsL[BUF][srow1 * APAD + sq1 * 4]) = make_ushort4(           \
        f2bf(v1.x - bf2f(g0)), f2bf(v1.y - bf2f(g1)),                        \
        f2bf(v1.z - bf2f(g2)), f2bf(v1.w - bf2f(g3)));                       \
  } while (0)

  STAGE_A(0, 0);

#pragma unroll
  for (int it = 0; it < 16; ++it) {
    const int cur = it & 1;
    const int k0 = it * 32;
    __syncthreads();                   // stage of buf[cur] complete
    if (it + 1 < 16) STAGE_A(!cur ? 1 : 0, k0 + 32);  // (it+1)&1

    short8 ah[4], al[4], bh[4], bl[4];
#pragma unroll
    for (int i = 0; i < 4; ++i) {
      int off = (i * 16 + fr) * APAD + kc * 8;
      ah[i] = *(const short8*)(&AsH[cur][off]);
      al[i] = *(const short8*)(&AsL[cur][off]);
    }
#pragma unroll
    for (int j = 0; j < 4; ++j) {
      size_t off = (size_t)(o0 + w * 64 + j * 16 + fr) * 512 + k0 + kc * 8;
      bh[j] = *(const short8*)(Wh + off);
      bl[j] = *(const short8*)(Wl + off);
    }
#pragma unroll
    for (int i = 0; i < 4; ++i)
#pragma unroll
      for (int j = 0; j < 4; ++j) {
        acc[i][j] = __builtin_amdgcn_mfma_f32_16x16x32_bf16(
            ah[i], bh[j], acc[i][j], 0, 0, 0);
        acc[i][j] = __builtin_amdgcn_mfma_f32_16x16x32_bf16(
            ah[i], bl[j], acc[i][j], 0, 0, 0);
        acc[i][j] = __builtin_amdgcn_mfma_f32_16x16x32_bf16(
            al[i], bh[j], acc[i][j], 0, 0, 0);
      }
  }

#pragma unroll
  for (int i = 0; i < 4; ++i)
#pragma unroll
    for (int j = 0; j < 4; ++j)
#pragma unroll
      for (int r = 0; r < 4; ++r) {
        int m = m0 + i * 16 + (lane >> 4) * 4 + r;
        int o = o0 + w * 64 + j * 16 + fr;
        C[(size_t)m * 512 + o] = (acc[i][j][r] + bias[o]) * scale;
      }
}

// ---------------------------------------------------------------------------
// Transpose K into Kt[bh][e][n] for coalesced attention score reads.
// ---------------------------------------------------------------------------
__global__ __launch_bounds__(256) void transposeK_kernel(
    const float* __restrict__ K, float* __restrict__ Kt) {
  const int bh = blockIdx.x & 31;
  const int nt = blockIdx.x >> 5;       // 0..15
  const int b = bh >> 3, h = bh & 7;
  const int n0 = nt * 128;
  const int tid = threadIdx.x;
  __shared__ float T[128][65];

#pragma unroll
  for (int i = 0; i < 8; ++i) {
    int flat = tid + i * 256;           // 0..2047
    int r = flat >> 4;                  // 0..127
    int c4 = flat & 15;                 // 0..15
    float4 v = *(const float4*)(K + (((size_t)(n0 + r) * 4 + b) * 8 + h) * 64 + c4 * 4);
    T[r][c4 * 4 + 0] = v.x; T[r][c4 * 4 + 1] = v.y;
    T[r][c4 * 4 + 2] = v.z; T[r][c4 * 4 + 3] = v.w;
  }
  __syncthreads();

  const int nl = tid & 127;             // 0..127
  const int eg = tid >> 7;              // 0..1
#pragma unroll
  for (int e = eg * 32; e < eg * 32 + 32; ++e)
    Kt[((size_t)bh * 64 + e) * 2048 + n0 + nl] = T[nl][e];
}

// ---------------------------------------------------------------------------
// M scores, wave-cooperative gather. One wave per (bh, n).
// ---------------------------------------------------------------------------
__global__ __launch_bounds__(256) void mscore_kernel(
    const float* __restrict__ Q, const float* __restrict__ K,
    const int* __restrict__ idx, float* __restrict__ Mout) {
  const int bh = blockIdx.x & 31;
  const int c  = blockIdx.x >> 5;        // 0..511
  const int wv = threadIdx.x >> 6;       // 0..3
  const int lane = threadIdx.x & 63;
  const int n = c * 4 + wv;
  const int b = bh >> 3, h = bh & 7;
  const int g = lane >> 4;               // sample group 0..3
  const int e16 = lane & 15;             // element chunk within row

  const float4 qv = *(const float4*)(Q + (((size_t)n * 4 + b) * 8 + h) * 64 + e16 * 4);

  float mx = -INFINITY, sm = 0.f;
#pragma unroll
  for (int it = 0; it < 10; ++it) {
    const int s = it * 4 + g;
    const int kn = idx[n * UP + s];
    const float4 kv = *(const float4*)(K + (((size_t)kn * 4 + b) * 8 + h) * 64 + e16 * 4);
    float d = qv.x * kv.x + qv.y * kv.y + qv.z * kv.z + qv.w * kv.w;
    d += __shfl_xor(d, 1);
    d += __shfl_xor(d, 2);
    d += __shfl_xor(d, 4);
    d += __shfl_xor(d, 8);
    mx = fmaxf(mx, d);
    sm += d;
  }
  mx = fmaxf(mx, __shfl_xor(mx, 16));
  mx = fmaxf(mx, __shfl_xor(mx, 32));
  sm += __shfl_xor(sm, 16);
  sm += __shfl_xor(sm, 32);
  if (lane == 0) Mout[(size_t)bh * 2048 + n] = mx - sm * (1.0f / (float)KN);
}

// ---------------------------------------------------------------------------
// top-40 per (b,h) via 4-pass byte radix-select (R14, verified).
// ---------------------------------------------------------------------------
__global__ __launch_bounds__(256) void topk_kernel(
    const float* __restrict__ M, int* __restrict__ Mtop) {
  const int bh = blockIdx.x;
  __shared__ unsigned keys[2048];
  __shared__ int hist[256];
  __shared__ int suf[256];
  __shared__ int scal[2];
  __shared__ int ties[128];
  __shared__ int cnts[2];

  const int tid = threadIdx.x;
  const float* Mrow = M + (size_t)bh * 2048;
#pragma unroll
  for (int i = 0; i < 8; ++i) {
    int j = tid + i * 256;
    unsigned u = __float_as_uint(Mrow[j]);
    keys[j] = (u & 0x80000000u) ? ~u : (u | 0x80000000u);  // monotone map
  }
  if (tid < 2) cnts[tid] = 0;

  unsigned prefix = 0, prefmask = 0;
  int rank = UP;
#pragma unroll
  for (int shift = 24; shift >= 0; shift -= 8) {
    hist[tid] = 0;
    __syncthreads();
#pragma unroll
    for (int i = 0; i < 8; ++i) {
      unsigned k = keys[tid + i * 256];
      if ((k & prefmask) == prefix)
        atomicAdd(&hist[(k >> shift) & 0xFFu], 1);
    }
    __syncthreads();
    suf[tid] = hist[tid];
    __syncthreads();
#pragma unroll
    for (int off = 1; off < 256; off <<= 1) {
      int add = (tid + off < 256) ? suf[tid + off] : 0;
      __syncthreads();
      suf[tid] += add;
      __syncthreads();
    }
    {
      int above = suf[tid] - hist[tid];
      if (above < rank && rank <= suf[tid]) {
        scal[0] = tid;
        scal[1] = rank - above;
      }
    }
    __syncthreads();
    prefix |= ((unsigned)scal[0]) << shift;
    prefmask |= 0xFFu << shift;
    rank = scal[1];
    __syncthreads();
  }
  const unsigned T = prefix;

#pragma unroll
  for (int i = 0; i < 8; ++i) {
    int j = tid + i * 256;
    unsigned k = keys[j];
    if (k > T) {
      int p = atomicAdd(&cnts[0], 1);
      Mtop[bh * UP + p] = j;
    } else if (k == T) {
      int p = atomicAdd(&cnts[1], 1);
      if (p < 128) ties[p] = j;
    }
  }
  __syncthreads();
  if (tid == 0) {
    int base = cnts[0];
    int need = UP - base;
    int tc = cnts[1] < 128 ? cnts[1] : 128;
    for (int s = 0; s < need; ++s) {
      int best = 1 << 30, bj = 0;
      for (int j = 0; j < tc; ++j) {
        int v = ties[j];
        if (v < best) { best = v; bj = j; }
      }
      Mtop[bh * UP + base + s] = best;
      ties[bj] = 1 << 30;
    }
  }
}

// ---------------------------------------------------------------------------
// mean of V: two-phase coalesced column-sum (V is a [2048][2048] matrix).
// ---------------------------------------------------------------------------
__global__ __launch_bounds__(256) void meanv_part(
    const float* __restrict__ V, float* __restrict__ part) {
  const int rc = blockIdx.x >> 3;      // 0..31
  const int cc = blockIdx.x & 7;       // 0..7
  const int c = cc * 256 + threadIdx.x;
  const float* p = V + (size_t)rc * 64 * 2048 + c;
  float acc = 0.f;
#pragma unroll 8
  for (int i = 0; i < 64; ++i) acc += p[(size_t)i * 2048];
  part[(size_t)rc * 2048 + c] = acc;
}

__global__ __launch_bounds__(256) void meanv_final(
    const float* __restrict__ part, float* __restrict__ mnV) {
  const int c = blockIdx.x * 256 + threadIdx.x;   // 8 blocks
  float acc = 0.f;
#pragma unroll
  for (int r = 0; r < 32; ++r) acc += part[(size_t)r * 2048 + c];
  mnV[c] = acc * (1.0f / (float)KN);
}

// ---------------------------------------------------------------------------
// meanout[b][o] = dot(mnV[b*512..], Wo[o]) + bo[o]; 32 blocks, k-split x4
// with fixed-order reduce (deterministic).
// ---------------------------------------------------------------------------
__global__ __launch_bounds__(256) void meanout_kernel(
    const float* __restrict__ mnV, const float* __restrict__ Wo,
    const float* __restrict__ bo, float* __restrict__ mo) {
  const int b = blockIdx.x >> 3;          // 0..3
  const int oc = blockIdx.x & 7;          // 0..7
  const int ol = threadIdx.x & 63;        // o within chunk
  const int kp = threadIdx.x >> 6;        // k-part 0..3
  const int o = oc * 64 + ol;
  __shared__ float red[4][64];

  const float* m = mnV + b * 512;
  const float* w = Wo + (size_t)o * 512;
  float acc = 0.f;
#pragma unroll 8
  for (int k = kp * 128; k < kp * 128 + 128; ++k)
    acc = fmaf(m[k], w[k], acc);
  red[kp][ol] = acc;
  __syncthreads();
  if (threadIdx.x < 64) {
    float s = red[0][ol] + red[1][ol] + red[2][ol] + red[3][ol];
    mo[b * 512 + o] = s + bo[o];
  }
}

// out broadcast fill (float4)
__global__ void fillout_kernel(const float* __restrict__ mo,
                               float* __restrict__ out) {
  size_t i = ((size_t)blockIdx.x * 256 + threadIdx.x) * 4;
  int d = (int)(i & 511);
  int b = (int)(i >> 20);
  float4 v = *(const float4*)(mo + (b << 9) + d);
  *(float4*)(out + i) = v;
}

// ---------------------------------------------------------------------------
// Seed the selected ctx rows with the per-batch mean row, indexed directly
// from Mtop (duplicates across heads write identical values - benign).
// ---------------------------------------------------------------------------
__global__ __launch_bounds__(128) void fillsel_kernel(
    const int* __restrict__ Mtop, const float* __restrict__ mnV,
    float* __restrict__ ctx) {
  const int i = blockIdx.x;            // 0..1279
  const int b = (i / UP) >> 3;
  const int row = b * 2048 + Mtop[i];
  float4 v = *(const float4*)(mnV + b * 512 + threadIdx.x * 4);
  *(float4*)(ctx + (size_t)row * 512 + threadIdx.x * 4) = v;
}

// ---------------------------------------------------------------------------
// Sparse output GEMM over the 1280 Mtop rows (dups recompute identical
// values - benign). 32-row x 64-col tiles, grid 320 exact.
// ---------------------------------------------------------------------------
__global__ __launch_bounds__(256) void gemm_rows(
    const float* __restrict__ ctx, const float* __restrict__ W,
    const float* __restrict__ bias, const int* __restrict__ Mtop,
    float* __restrict__ out) {
  __shared__ float As[32][36];   // [k][row]
  __shared__ float Ws[32][68];   // [k][col]
  __shared__ int rsel[32];
  const int rt = blockIdx.x >> 3;      // 0..39
  const int ot = blockIdx.x & 7;       // 0..7
  const int o0 = ot * 64;
  const int tid = threadIdx.x;
  const int tx = tid & 15;             // col group (4 cols)
  const int ty = tid >> 4;             // row group (2 rows)

  if (tid < 32) {
    int g = rt * 32 + tid;             // 0..1279
    int b = (g / UP) >> 3;
    rsel[tid] = b * 2048 + Mtop[g];
  }
  __syncthreads();

  float acc[2][4] = {};
  for (int k0 = 0; k0 < 512; k0 += 32) {
    {
      int row = tid >> 3, q = tid & 7;
      float4 av = *(const float4*)(ctx + (size_t)rsel[row] * 512 + k0 + q * 4);
      As[q * 4 + 0][row] = av.x; As[q * 4 + 1][row] = av.y;
      As[q * 4 + 2][row] = av.z; As[q * 4 + 3][row] = av.w;
    }
#pragma unroll
    for (int i = 0; i < 2; ++i) {
      int flat = tid + i * 256;        // 0..511
      int r = flat >> 3, q = flat & 7;
      float4 wv = *(const float4*)(W + (size_t)(o0 + r) * 512 + k0 + q * 4);
      Ws[q * 4 + 0][r] = wv.x; Ws[q * 4 + 1][r] = wv.y;
      Ws[q * 4 + 2][r] = wv.z; Ws[q * 4 + 3][r] = wv.w;
    }
    __syncthreads();
#pragma unroll
    for (int kk = 0; kk < 32; ++kk) {
      float a_[2], w_[4];
#pragma unroll
      for (int i = 0; i < 2; ++i) a_[i] = As[kk][ty * 2 + i];
#pragma unroll
      for (int j = 0; j < 4; ++j) w_[j] = Ws[kk][tx * 4 + j];
#pragma unroll
      for (int i = 0; i < 2; ++i)
#pragma unroll
        for (int j = 0; j < 4; ++j)
          acc[i][j] = fmaf(a_[i], w_[j], acc[i][j]);
    }
    __syncthreads();
  }

#pragma unroll
  for (int i = 0; i < 2; ++i) {
    int m = rsel[ty * 2 + i];
#pragma unroll
    for (int j = 0; j < 4; ++j) {
      int o = o0 + tx * 4 + j;
      out[(size_t)m * 512 + o] = acc[i][j] + bias[o];
    }
  }
}

// ---------------------------------------------------------------------------
// Flash-split attention (R15, verified): grid 1024, bid%8 == bh%8.
// ---------------------------------------------------------------------------
#define QG 5   // queries per block
#define NC 4   // n-chunks
__global__ __launch_bounds__(256) void attn_part(
    const float* __restrict__ Q, const float* __restrict__ Kt,
    const float* __restrict__ V, const int* __restrict__ Mtop,
    float* __restrict__ pmax, float* __restrict__ psum,
    float* __restrict__ pvp) {
  const int bh = blockIdx.x & 31;
  const int t  = blockIdx.x >> 5;       // 0..31
  const int g  = t & 7;                 // query group
  const int ch = t >> 3;                // n-chunk
  const int b = bh >> 3, h = bh & 7;
  const int tid = threadIdx.x;
  const int wv = tid >> 6, lane = tid & 63;
  const int n0 = ch * 512;

  __shared__ float qs[QG][64];
  __shared__ float p[QG][512];
  __shared__ float redm[QG][4];
  __shared__ float reds[QG][4];
  __shared__ float pvs[4][QG][64];

  for (int i = tid; i < QG * 64; i += 256) {
    int q = i >> 6, e = i & 63;
    int nq = Mtop[bh * UP + g * QG + q];
    qs[q][e] = Q[(((size_t)nq * 4 + b) * 8 + h) * 64 + e];
  }
  __syncthreads();

  const float* ktb = Kt + (size_t)bh * 64 * 2048;
  float d0[QG] = {}, d1[QG] = {};
  const int nb = n0 + tid * 2;
  for (int e = 0; e < 64; ++e) {
    float2 kv = *(const float2*)(ktb + (size_t)e * 2048 + nb);
#pragma unroll
    for (int q = 0; q < QG; ++q) {
      float qe = qs[q][e];
      d0[q] = fmaf(qe, kv.x, d0[q]);
      d1[q] = fmaf(qe, kv.y, d1[q]);
    }
  }

#pragma unroll
  for (int q = 0; q < QG; ++q) {
    float m_ = fmaxf(d0[q], d1[q]);
#pragma unroll
    for (int off = 1; off < 64; off <<= 1)
      m_ = fmaxf(m_, __shfl_xor(m_, off));
    if (lane == 0) redm[q][wv] = m_;
  }
  __syncthreads();
  float gm[QG];
#pragma unroll
  for (int q = 0; q < QG; ++q)
    gm[q] = fmaxf(fmaxf(redm[q][0], redm[q][1]),
                  fmaxf(redm[q][2], redm[q][3]));

  float ls[QG];
#pragma unroll
  for (int q = 0; q < QG; ++q) {
    float e0 = __expf(d0[q] - gm[q]);
    float e1 = __expf(d1[q] - gm[q]);
    p[q][tid * 2] = e0;
    p[q][tid * 2 + 1] = e1;
    ls[q] = e0 + e1;
  }
#pragma unroll
  for (int q = 0; q < QG; ++q) {
    float s_ = ls[q];
#pragma unroll
    for (int off = 1; off < 64; off <<= 1)
      s_ += __shfl_xor(s_, off);
    if (lane == 0) reds[q][wv] = s_;
  }
  __syncthreads();
  float den[QG];
#pragma unroll
  for (int q = 0; q < QG; ++q)
    den[q] = reds[q][0] + reds[q][1] + reds[q][2] + reds[q][3];

  float acc[QG] = {};
  for (int nn = wv * 128; nn < wv * 128 + 128; ++nn) {
    float v = V[(((size_t)(n0 + nn) * 4 + b) * 8 + h) * 64 + lane];
#pragma unroll
    for (int q = 0; q < QG; ++q) acc[q] = fmaf(p[q][nn], v, acc[q]);
  }
#pragma unroll
  for (int q = 0; q < QG; ++q) pvs[wv][q][lane] = acc[q];
  __syncthreads();

  for (int i = tid; i < QG * 64; i += 256) {
    int q = i >> 6, e = i & 63;
    int slot = bh * UP + g * QG + q;
    float pv = pvs[0][q][e] + pvs[1][q][e] + pvs[2][q][e] + pvs[3][q][e];
    pvp[((size_t)slot * NC + ch) * 64 + e] = pv;
    if (e == 0) {
      pmax[slot * NC + ch] = gm[q];
      psum[slot * NC + ch] = den[q];
    }
  }
}

__global__ __launch_bounds__(64) void attn_combine(
    const float* __restrict__ pmax, const float* __restrict__ psum,
    const float* __restrict__ pvp, float* __restrict__ upd) {
  const int slot = blockIdx.x;     // 0..1279
  const int e = threadIdx.x;
  float m = -INFINITY;
#pragma unroll
  for (int ch = 0; ch < NC; ++ch) m = fmaxf(m, pmax[slot * NC + ch]);
  float den = 0.f, num = 0.f;
#pragma unroll
  for (int ch = 0; ch < NC; ++ch) {
    float w = __expf(pmax[slot * NC + ch] - m);
    den = fmaf(w, psum[slot * NC + ch], den);
    num = fmaf(w, pvp[((size_t)slot * NC + ch) * 64 + e], num);
  }
  upd[(size_t)slot * 64 + e] = num / den;
}

// ---------------------------------------------------------------------------
// scatter selected rows
// ---------------------------------------------------------------------------
__global__ void scatter_kernel(const float* __restrict__ upd,
                               const int* __restrict__ Mtop,
                               float* __restrict__ ctx) {
  const int blk = blockIdx.x;   // bh*40 + s
  const int bh = blk / UP;
  const int b = bh >> 3, h = bh & 7;
  const int n = Mtop[blk];
  ctx[((size_t)(b * 2048 + n)) * 512 + h * 64 + threadIdx.x] =
      upd[(size_t)blk * 64 + threadIdx.x];
}

// ---------------------------------------------------------------------------
// Workspace layout (~70 MiB used; ws >= 113 MiB proven in R4):
//   [0, 256K) Mbuf | [256K,576K) upd | [589824,598016) mnV
//   [598016,603136) Mtop | [634880,897024) vpart | [941312,949504) mo
//   [1M,49M) QKV stacked (Q 1-17M = ctx alias, K 17-33M, V 33-49M)
//   [49M,65M) Kt
//   [65M,66.5M) Wh3 | [66.5M,68M) Wl3
//   [68M..68M+64K) pmax/psum | [..~69.4M) pvp
// ---------------------------------------------------------------------------
extern "C" void kernel_launch(void* const* d_in, const int* in_sizes, int n_in,
                              void* d_out, int out_size, void* d_ws,
                              size_t ws_size, hipStream_t stream) {
  const float* query = (const float*)d_in[0];
  const float* key   = (const float*)d_in[1];
  const float* value = (const float*)d_in[2];
  const int*   idxs  = (const int*)d_in[3];
  const float* Wq = (const float*)d_in[4];
  const float* bq = (const float*)d_in[5];
  const float* Wk = (const float*)d_in[6];
  const float* bk = (const float*)d_in[7];
  const float* Wv = (const float*)d_in[8];
  const float* bv = (const float*)d_in[9];
  const float* Wo = (const float*)d_in[10];
  const float* bo = (const float*)d_in[11];
  float* out = (float*)d_out;    // reference output dtype is float32

  char* ws = (char*)d_ws;
  float*  Mbuf  = (float*)(ws + 0);
  float*  upd   = (float*)(ws + 262144);
  float*  mnV   = (float*)(ws + 589824);
  int*    Mtop  = (int*)  (ws + 598016);
  float*  vpart = (float*)(ws + 634880);
  float*  mo    = (float*)(ws + 941312);
  float*  QKV   = (float*)(ws + MiB(1));   // Q | K | V stacked
  float*  Q     = QKV;
  float*  K     = (float*)(ws + MiB(17));
  float*  V     = (float*)(ws + MiB(33));
  float*  Kt    = (float*)(ws + MiB(49));
  ushort* Wh3   = (ushort*)(ws + MiB(65));
  ushort* Wl3   = (ushort*)(ws + MiB(65) + 1572864);
  float*  pmax  = (float*)(ws + MiB(68));
  float*  psum  = (float*)(ws + MiB(68) + 32768);
  float*  pvp   = (float*)(ws + MiB(68) + 65536);
  float*  ctx   = Q;   // Q dead after attn; ctx written afterwards

  wsplit3_kernel<<<1536, 256, 0, stream>>>(Wq, Wk, Wv, Wh3, Wl3);
  gemm3_mfma<<<768, 256, 0, stream>>>(query, key, value, Wh3, Wl3,
                                      bq, bk, bv, QKV);

  transposeK_kernel<<<512, 256, 0, stream>>>(K, Kt);

  mscore_kernel<<<16384, 256, 0, stream>>>(Q, K, idxs, Mbuf);
  topk_kernel<<<NBH, 256, 0, stream>>>(Mbuf, Mtop);

  meanv_part<<<256, 256, 0, stream>>>(V, vpart);
  meanv_final<<<8, 256, 0, stream>>>(vpart, mnV);

  attn_part<<<NBH * 32, 256, 0, stream>>>(Q, Kt, V, Mtop, pmax, psum, pvp);
  attn_combine<<<NBH * UP, 64, 0, stream>>>(pmax, psum, pvp, upd);

  fillsel_kernel<<<NBH * UP, 128, 0, stream>>>(Mtop, mnV, ctx);
  scatter_kernel<<<NBH * UP, 64, 0, stream>>>(upd, Mtop, ctx);

  meanout_kernel<<<32, 256, 0, stream>>>(mnV, Wo, bo, mo);
  fillout_kernel<<<4096, 256, 0, stream>>>(mo, out);
  gemm_rows<<<320, 256, 0, stream>>>(ctx, Wo, bo, Mtop, out);
}

// Round 25
// 170.762 us; speedup vs baseline: 1.9883x; 1.1020x over previous
//
#include <hip/hip_runtime.h>
#include <hip/hip_bf16.h>

// Problem constants
#define KN 2048
#define BB 4
#define DM 512
#define NH 8
#define HE 64
#define UP 40
#define NBH 32          // B*H
#define NROWS 8192      // KN*B
#define MiB(x) ((size_t)(x) << 20)

typedef __attribute__((ext_vector_type(8))) short short8;
typedef __attribute__((ext_vector_type(4))) float f32x4;

// bf16 split helpers (RNE)
__device__ __forceinline__ ushort f2bf(float x) {
  unsigned u = __float_as_uint(x);
  unsigned r = (u + 0x7FFFu + ((u >> 16) & 1u)) >> 16;
  return (ushort)r;
}
__device__ __forceinline__ float bf2f(ushort h) {
  return __uint_as_float((unsigned)h << 16);
}

// ---------------------------------------------------------------------------
// Fused split of the 3 weight matrices into hi/lo bf16 planes (stacked).
// ---------------------------------------------------------------------------
__global__ __launch_bounds__(256) void wsplit3_kernel(
    const float* __restrict__ W0, const float* __restrict__ W1,
    const float* __restrict__ W2, ushort* __restrict__ Wh,
    ushort* __restrict__ Wl) {
  const int which = blockIdx.x >> 9;
  const float* W = (which == 0) ? W0 : (which == 1) ? W1 : W2;
  size_t base = (size_t)which * 262144;
  int i = ((blockIdx.x & 511) * 256 + threadIdx.x) * 2;
  float2 v = *(const float2*)(W + i);
  ushort h0 = f2bf(v.x), h1 = f2bf(v.y);
  ushort l0 = f2bf(v.x - bf2f(h0)), l1 = f2bf(v.y - bf2f(h1));
  *(ushort2*)(Wh + base + i) = make_ushort2(h0, h1);
  *(ushort2*)(Wl + base + i) = make_ushort2(l0, l1);
}

// ---------------------------------------------------------------------------
// Fused 3-GEMM (R24, verified): A dbuf LDS w/ in-staging split, W from global.
// ---------------------------------------------------------------------------
#define APAD 40
__global__ __launch_bounds__(256) void gemm3_mfma(
    const float* __restrict__ A0, const float* __restrict__ A1,
    const float* __restrict__ A2,
    const ushort* __restrict__ Wh3, const ushort* __restrict__ Wl3,
    const float* __restrict__ bq, const float* __restrict__ bk,
    const float* __restrict__ bv, float* __restrict__ QKV) {
  __shared__ ushort AsH[2][64 * APAD];
  __shared__ ushort AsL[2][64 * APAD];

  const int which = blockIdx.x >> 8;
  const int local = blockIdx.x & 255;
  const int xcd = local & 7;
  const int idx = local >> 3;            // 0..31
  const int ot = idx >> 4;               // 0..1
  const int mt = xcd * 16 + (idx & 15);  // 0..127
  const int m0 = mt * 64, o0 = ot * 256;

  const float* A = (which == 0) ? A0 : (which == 1) ? A1 : A2;
  const ushort* Wh = Wh3 + (size_t)which * 262144;
  const ushort* Wl = Wl3 + (size_t)which * 262144;
  const float* bias = (which == 0) ? bq : (which == 1) ? bk : bv;
  float* C = QKV + (size_t)which * 8192 * 512;
  const float scale = (which == 0) ? 0.125f : 1.0f;

  const int tid = threadIdx.x;
  const int w = tid >> 6, lane = tid & 63;
  const int fr = lane & 15;            // fragment row
  const int kc = lane >> 4;            // k-chunk (8 bf16)

  f32x4 acc[4][4];
#pragma unroll
  for (int i = 0; i < 4; ++i)
#pragma unroll
    for (int j = 0; j < 4; ++j)
#pragma unroll
      for (int r = 0; r < 4; ++r) acc[i][j][r] = 0.f;

  const int srow0 = tid >> 3, sq0 = tid & 7;
  const int srow1 = (tid + 256) >> 3, sq1 = (tid + 256) & 7;

#define STAGE_A(BUF, K0)                                                    \
  do {                                                                      \
    float4 v0 = *(const float4*)(A + (size_t)(m0 + srow0) * 512 + (K0) + sq0 * 4); \
    float4 v1 = *(const float4*)(A + (size_t)(m0 + srow1) * 512 + (K0) + sq1 * 4); \
    ushort h0 = f2bf(v0.x), h1 = f2bf(v0.y), h2 = f2bf(v0.z), h3 = f2bf(v0.w); \
    *(ushort4*)(&AsH[BUF][srow0 * APAD + sq0 * 4]) = make_ushort4(h0, h1, h2, h3); \
    *(ushort4*)(&AsL[BUF][srow0 * APAD + sq0 * 4]) = make_ushort4(           \
        f2bf(v0.x - bf2f(h0)), f2bf(v0.y - bf2f(h1)),                        \
        f2bf(v0.z - bf2f(h2)), f2bf(v0.w - bf2f(h3)));                       \
    ushort g0 = f2bf(v1.x), g1 = f2bf(v1.y), g2 = f2bf(v1.z), g3 = f2bf(v1.w); \
    *(ushort4*)(&AsH[BUF][srow1 * APAD + sq1 * 4]) = make_ushort4(g0, g1, g2, g3); \
    *(ushort4*)(&AsL[BUF][srow1 * APAD + sq1 * 4]) = make_ushort4(           \
        f2bf(v1.x - bf2f(g0)), f2bf(v1.y - bf2f(g1)),                        \
        f2bf(v1.z - bf2f(g2)), f2bf(v1.w - bf2f(g3)));                       \
  } while (0)

  STAGE_A(0, 0);

#pragma unroll
  for (int it = 0; it < 16; ++it) {
    const int cur = it & 1;
    const int k0 = it * 32;
    __syncthreads();
    if (it + 1 < 16) STAGE_A(!cur ? 1 : 0, k0 + 32);

    short8 ah[4], al[4], bh[4], bl[4];
#pragma unroll
    for (int i = 0; i < 4; ++i) {
      int off = (i * 16 + fr) * APAD + kc * 8;
      ah[i] = *(const short8*)(&AsH[cur][off]);
      al[i] = *(const short8*)(&AsL[cur][off]);
    }
#pragma unroll
    for (int j = 0; j < 4; ++j) {
      size_t off = (size_t)(o0 + w * 64 + j * 16 + fr) * 512 + k0 + kc * 8;
      bh[j] = *(const short8*)(Wh + off);
      bl[j] = *(const short8*)(Wl + off);
    }
#pragma unroll
    for (int i = 0; i < 4; ++i)
#pragma unroll
      for (int j = 0; j < 4; ++j) {
        acc[i][j] = __builtin_amdgcn_mfma_f32_16x16x32_bf16(
            ah[i], bh[j], acc[i][j], 0, 0, 0);
        acc[i][j] = __builtin_amdgcn_mfma_f32_16x16x32_bf16(
            ah[i], bl[j], acc[i][j], 0, 0, 0);
        acc[i][j] = __builtin_amdgcn_mfma_f32_16x16x32_bf16(
            al[i], bh[j], acc[i][j], 0, 0, 0);
      }
  }

#pragma unroll
  for (int i = 0; i < 4; ++i)
#pragma unroll
    for (int j = 0; j < 4; ++j)
#pragma unroll
      for (int r = 0; r < 4; ++r) {
        int m = m0 + i * 16 + (lane >> 4) * 4 + r;
        int o = o0 + w * 64 + j * 16 + fr;
        C[(size_t)m * 512 + o] = (acc[i][j][r] + bias[o]) * scale;
      }
}

// ---------------------------------------------------------------------------
// prep3: horizontal fusion of transposeK(64x64 tiles, 1024) || mscore(16384)
// || meanv_part(256).  All depend only on Q/K/V. grid 17664.
// Offsets are multiples of 32 -> XCD decodes preserved.
// ---------------------------------------------------------------------------
__global__ __launch_bounds__(256) void prep3_kernel(
    const float* __restrict__ K, float* __restrict__ Kt,
    const float* __restrict__ Q, const int* __restrict__ idx,
    float* __restrict__ Mout, const float* __restrict__ V,
    float* __restrict__ vpart) {
  __shared__ float T[64][65];
  const int bid = blockIdx.x;
  const int tid = threadIdx.x;

  if (bid < 1024) {
    // ---- transposeK: 64x64 tile ----
    const int bh = bid & 31;
    const int nt = bid >> 5;            // 0..31
    const int b = bh >> 3, h = bh & 7;
    const int n0 = nt * 64;
#pragma unroll
    for (int i = 0; i < 4; ++i) {
      int flat = tid + i * 256;         // 0..1023
      int r = flat >> 4;                // 0..63
      int c4 = flat & 15;               // 0..15
      float4 v = *(const float4*)(K + (((size_t)(n0 + r) * 4 + b) * 8 + h) * 64 + c4 * 4);
      T[r][c4 * 4 + 0] = v.x; T[r][c4 * 4 + 1] = v.y;
      T[r][c4 * 4 + 2] = v.z; T[r][c4 * 4 + 3] = v.w;
    }
    __syncthreads();
    const int nl = tid & 63;
    const int eg = tid >> 6;            // 0..3
#pragma unroll
    for (int e = eg * 16; e < eg * 16 + 16; ++e)
      Kt[((size_t)bh * 64 + e) * 2048 + n0 + nl] = T[nl][e];
    return;
  }

  if (bid < 1024 + 16384) {
    // ---- mscore (R10 verified body) ----
    const int vb = bid - 1024;
    const int bh = vb & 31;
    const int c  = vb >> 5;              // 0..511
    const int wv = tid >> 6;
    const int lane = tid & 63;
    const int n = c * 4 + wv;
    const int b = bh >> 3, h = bh & 7;
    const int g = lane >> 4;
    const int e16 = lane & 15;

    const float4 qv = *(const float4*)(Q + (((size_t)n * 4 + b) * 8 + h) * 64 + e16 * 4);

    float mx = -INFINITY, sm = 0.f;
#pragma unroll
    for (int it = 0; it < 10; ++it) {
      const int s = it * 4 + g;
      const int kn = idx[n * UP + s];
      const float4 kv = *(const float4*)(K + (((size_t)kn * 4 + b) * 8 + h) * 64 + e16 * 4);
      float d = qv.x * kv.x + qv.y * kv.y + qv.z * kv.z + qv.w * kv.w;
      d += __shfl_xor(d, 1);
      d += __shfl_xor(d, 2);
      d += __shfl_xor(d, 4);
      d += __shfl_xor(d, 8);
      mx = fmaxf(mx, d);
      sm += d;
    }
    mx = fmaxf(mx, __shfl_xor(mx, 16));
    mx = fmaxf(mx, __shfl_xor(mx, 32));
    sm += __shfl_xor(sm, 16);
    sm += __shfl_xor(sm, 32);
    if (lane == 0) Mout[(size_t)bh * 2048 + n] = mx - sm * (1.0f / (float)KN);
    return;
  }

  // ---- meanv_part ----
  {
    const int vb = bid - 17408;          // 0..255
    const int rc = vb >> 3;
    const int cc = vb & 7;
    const int c = cc * 256 + tid;
    const float* p = V + (size_t)rc * 64 * 2048 + c;
    float acc = 0.f;
#pragma unroll 8
    for (int i = 0; i < 64; ++i) acc += p[(size_t)i * 2048];
    vpart[(size_t)rc * 2048 + c] = acc;
  }
}

// ---------------------------------------------------------------------------
// sel2: topk(32) || meanv_final(8). grid 40.
// ---------------------------------------------------------------------------
__global__ __launch_bounds__(256) void sel2_kernel(
    const float* __restrict__ M, int* __restrict__ Mtop,
    const float* __restrict__ part, float* __restrict__ mnV) {
  __shared__ unsigned keys[2048];
  __shared__ int hist[256];
  __shared__ int suf[256];
  __shared__ int scal[2];
  __shared__ int ties[128];
  __shared__ int cnts[2];
  const int tid = threadIdx.x;

  if (blockIdx.x >= 32) {
    // ---- meanv_final ----
    const int c = (blockIdx.x - 32) * 256 + tid;
    float acc = 0.f;
#pragma unroll
    for (int r = 0; r < 32; ++r) acc += part[(size_t)r * 2048 + c];
    mnV[c] = acc * (1.0f / (float)KN);
    return;
  }

  // ---- topk (R14 verified radix-select) ----
  const int bh = blockIdx.x;
  const float* Mrow = M + (size_t)bh * 2048;
#pragma unroll
  for (int i = 0; i < 8; ++i) {
    int j = tid + i * 256;
    unsigned u = __float_as_uint(Mrow[j]);
    keys[j] = (u & 0x80000000u) ? ~u : (u | 0x80000000u);
  }
  if (tid < 2) cnts[tid] = 0;

  unsigned prefix = 0, prefmask = 0;
  int rank = UP;
#pragma unroll
  for (int shift = 24; shift >= 0; shift -= 8) {
    hist[tid] = 0;
    __syncthreads();
#pragma unroll
    for (int i = 0; i < 8; ++i) {
      unsigned k = keys[tid + i * 256];
      if ((k & prefmask) == prefix)
        atomicAdd(&hist[(k >> shift) & 0xFFu], 1);
    }
    __syncthreads();
    suf[tid] = hist[tid];
    __syncthreads();
#pragma unroll
    for (int off = 1; off < 256; off <<= 1) {
      int add = (tid + off < 256) ? suf[tid + off] : 0;
      __syncthreads();
      suf[tid] += add;
      __syncthreads();
    }
    {
      int above = suf[tid] - hist[tid];
      if (above < rank && rank <= suf[tid]) {
        scal[0] = tid;
        scal[1] = rank - above;
      }
    }
    __syncthreads();
    prefix |= ((unsigned)scal[0]) << shift;
    prefmask |= 0xFFu << shift;
    rank = scal[1];
    __syncthreads();
  }
  const unsigned T = prefix;

#pragma unroll
  for (int i = 0; i < 8; ++i) {
    int j = tid + i * 256;
    unsigned k = keys[j];
    if (k > T) {
      int p = atomicAdd(&cnts[0], 1);
      Mtop[bh * UP + p] = j;
    } else if (k == T) {
      int p = atomicAdd(&cnts[1], 1);
      if (p < 128) ties[p] = j;
    }
  }
  __syncthreads();
  if (tid == 0) {
    int base = cnts[0];
    int need = UP - base;
    int tc = cnts[1] < 128 ? cnts[1] : 128;
    for (int s = 0; s < need; ++s) {
      int best = 1 << 30, bj = 0;
      for (int j = 0; j < tc; ++j) {
        int v = ties[j];
        if (v < best) { best = v; bj = j; }
      }
      Mtop[bh * UP + base + s] = best;
      ties[bj] = 1 << 30;
    }
  }
}

// ---------------------------------------------------------------------------
// attnmean: attn_part(1024, R15 verified) || meanout(32). grid 1056.
// ---------------------------------------------------------------------------
#define QG 5   // queries per block
#define NC 4   // n-chunks
__global__ __launch_bounds__(256) void attnmean_kernel(
    const float* __restrict__ Q, const float* __restrict__ Kt,
    const float* __restrict__ V, const int* __restrict__ Mtop,
    float* __restrict__ pmax, float* __restrict__ psum,
    float* __restrict__ pvp, const float* __restrict__ mnV,
    const float* __restrict__ Wo, const float* __restrict__ bo,
    float* __restrict__ mo) {
  __shared__ float qs[QG][64];
  __shared__ float p[QG][512];
  __shared__ float redm[QG][4];
  __shared__ float reds[QG][4];
  __shared__ float pvs[4][QG][64];
  const int tid = threadIdx.x;

  if (blockIdx.x >= 1024) {
    // ---- meanout ----
    const int mb = blockIdx.x - 1024;       // 0..31
    const int b = mb >> 3;
    const int oc = mb & 7;
    const int ol = tid & 63;
    const int kp = tid >> 6;
    const int o = oc * 64 + ol;
    const float* m = mnV + b * 512;
    const float* w = Wo + (size_t)o * 512;
    float acc = 0.f;
#pragma unroll 8
    for (int k = kp * 128; k < kp * 128 + 128; ++k)
      acc = fmaf(m[k], w[k], acc);
    redm[0][0] = redm[0][0];  // keep shared alive (no-op)
    __shared__ float red[4][64];
    red[kp][ol] = acc;
    __syncthreads();
    if (tid < 64) {
      float s = red[0][ol] + red[1][ol] + red[2][ol] + red[3][ol];
      mo[b * 512 + o] = s + bo[o];
    }
    return;
  }

  const int bh = blockIdx.x & 31;
  const int t  = blockIdx.x >> 5;
  const int g  = t & 7;
  const int ch = t >> 3;
  const int b = bh >> 3, h = bh & 7;
  const int wv = tid >> 6, lane = tid & 63;
  const int n0 = ch * 512;

  for (int i = tid; i < QG * 64; i += 256) {
    int q = i >> 6, e = i & 63;
    int nq = Mtop[bh * UP + g * QG + q];
    qs[q][e] = Q[(((size_t)nq * 4 + b) * 8 + h) * 64 + e];
  }
  __syncthreads();

  const float* ktb = Kt + (size_t)bh * 64 * 2048;
  float d0[QG] = {}, d1[QG] = {};
  const int nb = n0 + tid * 2;
  for (int e = 0; e < 64; ++e) {
    float2 kv = *(const float2*)(ktb + (size_t)e * 2048 + nb);
#pragma unroll
    for (int q = 0; q < QG; ++q) {
      float qe = qs[q][e];
      d0[q] = fmaf(qe, kv.x, d0[q]);
      d1[q] = fmaf(qe, kv.y, d1[q]);
    }
  }

#pragma unroll
  for (int q = 0; q < QG; ++q) {
    float m_ = fmaxf(d0[q], d1[q]);
#pragma unroll
    for (int off = 1; off < 64; off <<= 1)
      m_ = fmaxf(m_, __shfl_xor(m_, off));
    if (lane == 0) redm[q][wv] = m_;
  }
  __syncthreads();
  float gm[QG];
#pragma unroll
  for (int q = 0; q < QG; ++q)
    gm[q] = fmaxf(fmaxf(redm[q][0], redm[q][1]),
                  fmaxf(redm[q][2], redm[q][3]));

  float ls[QG];
#pragma unroll
  for (int q = 0; q < QG; ++q) {
    float e0 = __expf(d0[q] - gm[q]);
    float e1 = __expf(d1[q] - gm[q]);
    p[q][tid * 2] = e0;
    p[q][tid * 2 + 1] = e1;
    ls[q] = e0 + e1;
  }
#pragma unroll
  for (int q = 0; q < QG; ++q) {
    float s_ = ls[q];
#pragma unroll
    for (int off = 1; off < 64; off <<= 1)
      s_ += __shfl_xor(s_, off);
    if (lane == 0) reds[q][wv] = s_;
  }
  __syncthreads();
  float den[QG];
#pragma unroll
  for (int q = 0; q < QG; ++q)
    den[q] = reds[q][0] + reds[q][1] + reds[q][2] + reds[q][3];

  float acc[QG] = {};
  for (int nn = wv * 128; nn < wv * 128 + 128; ++nn) {
    float v = V[(((size_t)(n0 + nn) * 4 + b) * 8 + h) * 64 + lane];
#pragma unroll
    for (int q = 0; q < QG; ++q) acc[q] = fmaf(p[q][nn], v, acc[q]);
  }
#pragma unroll
  for (int q = 0; q < QG; ++q) pvs[wv][q][lane] = acc[q];
  __syncthreads();

  for (int i = tid; i < QG * 64; i += 256) {
    int q = i >> 6, e = i & 63;
    int slot = bh * UP + g * QG + q;
    float pv = pvs[0][q][e] + pvs[1][q][e] + pvs[2][q][e] + pvs[3][q][e];
    pvp[((size_t)slot * NC + ch) * 64 + e] = pv;
    if (e == 0) {
      pmax[slot * NC + ch] = gm[q];
      psum[slot * NC + ch] = den[q];
    }
  }
}

// ---------------------------------------------------------------------------
// fill2: fillsel(1280) || fillout(4096). grid 5376. Disjoint outputs.
// ---------------------------------------------------------------------------
__global__ __launch_bounds__(256) void fill2_kernel(
    const int* __restrict__ Mtop, const float* __restrict__ mnV,
    float* __restrict__ ctx, const float* __restrict__ mo,
    float* __restrict__ out) {
  const int tid = threadIdx.x;
  if (blockIdx.x < 1280) {
    if (tid < 128) {
      const int i = blockIdx.x;
      const int b = (i / UP) >> 3;
      const int row = b * 2048 + Mtop[i];
      float4 v = *(const float4*)(mnV + b * 512 + tid * 4);
      *(float4*)(ctx + (size_t)row * 512 + tid * 4) = v;
    }
    return;
  }
  size_t i = ((size_t)(blockIdx.x - 1280) * 256 + tid) * 4;
  int d = (int)(i & 511);
  int b = (int)(i >> 20);
  float4 v = *(const float4*)(mo + (b << 9) + d);
  *(float4*)(out + i) = v;
}

// ---------------------------------------------------------------------------
// combine_scatter: flash-combine the NC chunk partials and write the result
// DIRECTLY into ctx (h-slices disjoint per slot -> deterministic).
// ---------------------------------------------------------------------------
__global__ __launch_bounds__(64) void combine_scatter_kernel(
    const float* __restrict__ pmax, const float* __restrict__ psum,
    const float* __restrict__ pvp, const int* __restrict__ Mtop,
    float* __restrict__ ctx) {
  const int slot = blockIdx.x;     // bh*40 + s
  const int e = threadIdx.x;
  const int bh = slot / UP;
  const int b = bh >> 3, h = bh & 7;
  const int n = Mtop[slot];
  float m = -INFINITY;
#pragma unroll
  for (int ch = 0; ch < NC; ++ch) m = fmaxf(m, pmax[slot * NC + ch]);
  float den = 0.f, num = 0.f;
#pragma unroll
  for (int ch = 0; ch < NC; ++ch) {
    float w = __expf(pmax[slot * NC + ch] - m);
    den = fmaf(w, psum[slot * NC + ch], den);
    num = fmaf(w, pvp[((size_t)slot * NC + ch) * 64 + e], num);
  }
  ctx[((size_t)(b * 2048 + n)) * 512 + h * 64 + e] = num / den;
}

// ---------------------------------------------------------------------------
// Sparse output GEMM over the 1280 Mtop rows (R23, verified).
// ---------------------------------------------------------------------------
__global__ __launch_bounds__(256) void gemm_rows(
    const float* __restrict__ ctx, const float* __restrict__ W,
    const float* __restrict__ bias, const int* __restrict__ Mtop,
    float* __restrict__ out) {
  __shared__ float As[32][36];
  __shared__ float Ws[32][68];
  __shared__ int rsel[32];
  const int rt = blockIdx.x >> 3;
  const int ot = blockIdx.x & 7;
  const int o0 = ot * 64;
  const int tid = threadIdx.x;
  const int tx = tid & 15;
  const int ty = tid >> 4;

  if (tid < 32) {
    int g = rt * 32 + tid;
    int b = (g / UP) >> 3;
    rsel[tid] = b * 2048 + Mtop[g];
  }
  __syncthreads();

  float acc[2][4] = {};
  for (int k0 = 0; k0 < 512; k0 += 32) {
    {
      int row = tid >> 3, q = tid & 7;
      float4 av = *(const float4*)(ctx + (size_t)rsel[row] * 512 + k0 + q * 4);
      As[q * 4 + 0][row] = av.x; As[q * 4 + 1][row] = av.y;
      As[q * 4 + 2][row] = av.z; As[q * 4 + 3][row] = av.w;
    }
#pragma unroll
    for (int i = 0; i < 2; ++i) {
      int flat = tid + i * 256;
      int r = flat >> 3, q = flat & 7;
      float4 wv = *(const float4*)(W + (size_t)(o0 + r) * 512 + k0 + q * 4);
      Ws[q * 4 + 0][r] = wv.x; Ws[q * 4 + 1][r] = wv.y;
      Ws[q * 4 + 2][r] = wv.z; Ws[q * 4 + 3][r] = wv.w;
    }
    __syncthreads();
#pragma unroll
    for (int kk = 0; kk < 32; ++kk) {
      float a_[2], w_[4];
#pragma unroll
      for (int i = 0; i < 2; ++i) a_[i] = As[kk][ty * 2 + i];
#pragma unroll
      for (int j = 0; j < 4; ++j) w_[j] = Ws[kk][tx * 4 + j];
#pragma unroll
      for (int i = 0; i < 2; ++i)
#pragma unroll
        for (int j = 0; j < 4; ++j)
          acc[i][j] = fmaf(a_[i], w_[j], acc[i][j]);
    }
    __syncthreads();
  }

#pragma unroll
  for (int i = 0; i < 2; ++i) {
    int m = rsel[ty * 2 + i];
#pragma unroll
    for (int j = 0; j < 4; ++j) {
      int o = o0 + tx * 4 + j;
      out[(size_t)m * 512 + o] = acc[i][j] + bias[o];
    }
  }
}

// ---------------------------------------------------------------------------
// Workspace layout (~70 MiB used; ws >= 113 MiB proven in R4):
//   [0, 256K) Mbuf | [589824,598016) mnV | [598016,603136) Mtop
//   [634880,897024) vpart | [941312,949504) mo
//   [1M,49M) QKV stacked (Q 1-17M = ctx alias, K 17-33M, V 33-49M)
//   [49M,65M) Kt | [65M,66.5M) Wh3 | [66.5M,68M) Wl3
//   [68M..68M+64K) pmax/psum | [..~69.4M) pvp
// ---------------------------------------------------------------------------
extern "C" void kernel_launch(void* const* d_in, const int* in_sizes, int n_in,
                              void* d_out, int out_size, void* d_ws,
                              size_t ws_size, hipStream_t stream) {
  const float* query = (const float*)d_in[0];
  const float* key   = (const float*)d_in[1];
  const float* value = (const float*)d_in[2];
  const int*   idxs  = (const int*)d_in[3];
  const float* Wq = (const float*)d_in[4];
  const float* bq = (const float*)d_in[5];
  const float* Wk = (const float*)d_in[6];
  const float* bk = (const float*)d_in[7];
  const float* Wv = (const float*)d_in[8];
  const float* bv = (const float*)d_in[9];
  const float* Wo = (const float*)d_in[10];
  const float* bo = (const float*)d_in[11];
  float* out = (float*)d_out;    // reference output dtype is float32

  char* ws = (char*)d_ws;
  float*  Mbuf  = (float*)(ws + 0);
  float*  mnV   = (float*)(ws + 589824);
  int*    Mtop  = (int*)  (ws + 598016);
  float*  vpart = (float*)(ws + 634880);
  float*  mo    = (float*)(ws + 941312);
  float*  QKV   = (float*)(ws + MiB(1));   // Q | K | V stacked
  float*  Q     = QKV;
  float*  K     = (float*)(ws + MiB(17));
  float*  V     = (float*)(ws + MiB(33));
  float*  Kt    = (float*)(ws + MiB(49));
  ushort* Wh3   = (ushort*)(ws + MiB(65));
  ushort* Wl3   = (ushort*)(ws + MiB(65) + 1572864);
  float*  pmax  = (float*)(ws + MiB(68));
  float*  psum  = (float*)(ws + MiB(68) + 32768);
  float*  pvp   = (float*)(ws + MiB(68) + 65536);
  float*  ctx   = Q;   // Q dead after attn; ctx written afterwards

  wsplit3_kernel<<<1536, 256, 0, stream>>>(Wq, Wk, Wv, Wh3, Wl3);
  gemm3_mfma<<<768, 256, 0, stream>>>(query, key, value, Wh3, Wl3,
                                      bq, bk, bv, QKV);

  prep3_kernel<<<17664, 256, 0, stream>>>(K, Kt, Q, idxs, Mbuf, V, vpart);
  sel2_kernel<<<40, 256, 0, stream>>>(Mbuf, Mtop, vpart, mnV);

  attnmean_kernel<<<1056, 256, 0, stream>>>(Q, Kt, V, Mtop, pmax, psum, pvp,
                                            mnV, Wo, bo, mo);
  fill2_kernel<<<5376, 256, 0, stream>>>(Mtop, mnV, ctx, mo, out);
  combine_scatter_kernel<<<NBH * UP, 64, 0, stream>>>(pmax, psum, pvp,
                                                      Mtop, ctx);
  gemm_rows<<<320, 256, 0, stream>>>(ctx, Wo, bo, Mtop, out);
}